// Round 15
// baseline (673.477 us; speedup 1.0000x reference)
//
#include <hip/hip_runtime.h>
#include <hip/hip_bf16.h>
#include <math.h>

#define B_ 128
#define S_ 100
#define W_ 20
#define D_ 192
#define L_ 6
#define H_ 8
#define DFF_ 256
#define DH_ 24
#define BS_ (B_*S_)
#define THREED_ 576

typedef short short8 __attribute__((ext_vector_type(8)));
typedef short short4v __attribute__((ext_vector_type(4)));
typedef float floatx16 __attribute__((ext_vector_type(16)));

__device__ __forceinline__ float posenc(int s, int c) {
  float freq = expf(-logf(10000.f) * (float)(2 * (c >> 1)) / (float)D_);
  float ang = (float)s * freq;
  return (c & 1) ? cosf(ang) : sinf(ang);
}

__device__ __forceinline__ short8 ld_frag8(const __hip_bfloat16* p) {
  short4v lo = *(const short4v*)p;
  short4v hi = *(const short4v*)(p + 4);
  short8 r;
  r[0]=lo[0]; r[1]=lo[1]; r[2]=lo[2]; r[3]=lo[3];
  r[4]=hi[0]; r[5]=hi[1]; r[6]=hi[2]; r[7]=hi[3];
  return r;
}

__device__ __forceinline__ short f2bf_s(float v) {
  __hip_bfloat16 t = __float2bfloat16(v);
  return *reinterpret_cast<short*>(&t);
}

__device__ __forceinline__ float dot4(float4 a, float4 b) {
  return a.x*b.x + a.y*b.y + a.z*b.z + a.w*b.w;
}

// ---------------------------------------------------------------------------
// Merged weight conversion + encoder precompute (R24-validated). 2077 blocks.
// ---------------------------------------------------------------------------
__global__ __launch_bounds__(256)
void convertprep_kernel(
    const float* __restrict__ s0, __hip_bfloat16* __restrict__ d0,
    const float* __restrict__ s1, __hip_bfloat16* __restrict__ d1,
    const float* __restrict__ s2, __hip_bfloat16* __restrict__ d2,
    const float* __restrict__ s3, __hip_bfloat16* __restrict__ d3,
    const float* __restrict__ te, const float* __restrict__ ce,
    const float* __restrict__ pe, const float* __restrict__ wfw,
    const float* __restrict__ wfb, const float* __restrict__ sw2,
    const float* __restrict__ sb2,
    float* __restrict__ TE2, float* __restrict__ CE2,
    float* __restrict__ PE2, __hip_bfloat16* __restrict__ WSPb,
    float* __restrict__ PEtab)
{
  int b = blockIdx.x, tid = threadIdx.x;
  if (b < 720) {
    const float* s; __hip_bfloat16* d; int base;
    if      (b < 324) { s = s0; d = d0; base = b; }
    else if (b < 432) { s = s1; d = d1; base = b - 324; }
    else if (b < 576) { s = s2; d = d2; base = b - 432; }
    else              { s = s3; d = d3; base = b - 576; }
    int i = (base * 256 + tid) * 8;
    float4 v0 = *(const float4*)(s + i);
    float4 v1 = *(const float4*)(s + i + 4);
    __hip_bfloat162* d2p = (__hip_bfloat162*)(d + i);
    d2p[0] = __float22bfloat162_rn(make_float2(v0.x, v0.y));
    d2p[1] = __float22bfloat162_rn(make_float2(v0.z, v0.w));
    d2p[2] = __float22bfloat162_rn(make_float2(v1.x, v1.y));
    d2p[3] = __float22bfloat162_rn(make_float2(v1.z, v1.w));
    return;
  }
  int blk = b - 720;
  if (blk < 1250) {
    int item = blk * 256 + tid;
    int v = item >> 7, o = item & 127;
    const float* src; float* dst; int base, vv;
    float a;
    if (v < 1000) {
      src = te; dst = TE2; base = 0; vv = v;
      a = wfb[o];                                 // fold wfuse bias
      const float4* w4 = (const float4*)(wfw + o * 128 + 96);
      const float4* b4 = (const float4*)sb2;
      #pragma unroll
      for (int k4 = 0; k4 < 8; ++k4) a += dot4(w4[k4], b4[k4]);
    } else if (v < 1500) {
      src = ce; dst = CE2; base = 32; vv = v - 1000; a = 0.f;
    } else {
      src = pe; dst = PE2; base = 64; vv = v - 1500; a = 0.f;
    }
    const float4* s4 = (const float4*)(src + vv * 32);
    const float4* w4 = (const float4*)(wfw + o * 128 + base);
    #pragma unroll
    for (int k4 = 0; k4 < 8; ++k4) a += dot4(s4[k4], w4[k4]);
    int op = ((o & 31) << 2) + (o >> 5);          // R23 permuted placement
    dst[vv * 128 + op] = a;
  } else if (blk < 1282) {
    int item = (blk - 1250) * 256 + tid;
    int j = item >> 7, o = item & 127;           // j = hidden k, o = out col
    float a = 0.f;
    #pragma unroll 8
    for (int k = 0; k < 32; ++k) a += wfw[o * 128 + 96 + k] * sw2[k * 64 + j];
    WSPb[o * 64 + j] = __float2bfloat16(a);      // B operand [col][k]
  } else {
    int idx = (blk - 1282) * 256 + tid;          // [0, 19200)
    int s_ = idx / D_, c = idx - s_ * D_;
    PEtab[idx] = posenc(s_, c);
  }
}

// ---------------------------------------------------------------------------
// Encoder v14 (R30): 16 bs/block, 1024 threads, grid 800 (R29 lever doubled
// again: 8->16). Bls staged once per 16 bs; idx/mask/rect staging <=1 item
// per thread; block prologues per CU halve again. Per-wave MFMA/epilogue/
// tail unchanged; math bit-identical. LDS 33.8KB -> 2 blocks/CU x 16 waves.
// ---------------------------------------------------------------------------
__global__ __launch_bounds__(1024)
void encode8_kernel(
    const int* __restrict__ title_idx, const int* __restrict__ class_idx,
    const int* __restrict__ process_idx, const int* __restrict__ activity_type,
    const float* __restrict__ mouse_pos, const float* __restrict__ rect,
    const float* __restrict__ flags, const float* __restrict__ keyboard_active,
    const float* __restrict__ window_mask,
    const float* __restrict__ sw1, const float* __restrict__ sb1,
    const float* __restrict__ TE2, const float* __restrict__ CE2,
    const float* __restrict__ PE2, const __hip_bfloat16* __restrict__ WSPb,
    const float* __restrict__ PEtab,
    const float* __restrict__ mw1, const float* __restrict__ mb1,
    const float* __restrict__ mw2, const float* __restrict__ mb2,
    const float* __restrict__ act_emb, const float* __restrict__ kbw,
    const float* __restrict__ kbb,
    const float* __restrict__ afw, const float* __restrict__ afb,
    float* __restrict__ x, __hip_bfloat16* __restrict__ xb)
{
  __shared__ __hip_bfloat16 Bls[128][72];             // 18432
  __shared__ int   idxS[16][20][3];                   // 3840
  __shared__ float maskS[16][20];                     // 1280
  __shared__ __align__(16) float rectS[16][20][8];    // 10240 (wave-private after stage)

  int tid = threadIdx.x;
  int w = tid >> 6, lane = tid & 63;
  int m32 = lane & 31, half = lane >> 5;
  int bs0 = blockIdx.x * 16;
  int bs = bs0 + w;

  if (tid < 960) {
    int g2 = tid / 60, rem = tid % 60, which = rem / 20, w_ = rem % 20;
    const int* src = (which == 0) ? title_idx : (which == 1) ? class_idx : process_idx;
    idxS[g2][w_][which] = src[(bs0 + g2) * W_ + w_];
  }
  if (tid < 320) {
    int g2 = tid / 20, w_ = tid % 20;
    maskS[g2][w_] = window_mask[(bs0 + g2) * W_ + w_];
  }
  for (int e = tid; e < 1920; e += 1024) {    // 16*20*6
    int g2 = e / 120, rem = e % 120, w_ = rem / 6, c = rem % 6;
    int rg = (bs0 + g2) * W_ + w_;
    rectS[g2][w_][c] = (c < 4) ? rect[rg * 4 + c] : flags[rg * 2 + (c - 4)];
  }
  if (tid < 1024) {                           // 128 cols x 8 k-groups of 8
    int col = tid >> 3, k8 = tid & 7;
    short8 v = *(const short8*)&WSPb[col * 64 + k8 * 8];
    *(short8*)&Bls[col][k8 * 8] = v;
  }
  __syncthreads();

  short8 afr[4];
  {
    float rc[6];
    bool act = (m32 < W_);
    if (act) {
      #pragma unroll
      for (int c = 0; c < 6; ++c) rc[c] = rectS[w][m32][c];
    }
    #pragma unroll
    for (int s = 0; s < 4; ++s) {
      short8 f;
      #pragma unroll
      for (int jp = 0; jp < 8; ++jp) {
        float a = 0.f;
        if (act) {
          int j = s * 16 + half * 8 + jp;
          const float* w1 = sw1 + j * 6;
          a = sb1[j];
          #pragma unroll
          for (int c = 0; c < 6; ++c) a += w1[c] * rc[c];
          a = fmaxf(a, 0.f);
        }
        f[jp] = f2bf_s(a);
      }
      afr[s] = f;
    }
  }

  floatx16 acc[4];
  #pragma unroll
  for (int nt = 0; nt < 4; ++nt)
    #pragma unroll
    for (int r = 0; r < 16; ++r) acc[nt][r] = 0.f;

  #pragma unroll
  for (int s = 0; s < 4; ++s) {
    int ko = s * 16 + half * 8;
    #pragma unroll
    for (int nt = 0; nt < 4; ++nt) {
      short8 bf = *(const short8*)&Bls[nt * 32 + m32][ko];
      acc[nt] = __builtin_amdgcn_mfma_f32_32x32x16_bf16(afr[s], bf, acc[nt], 0, 0, 0);
    }
  }

  // ---- epilogue: one float4 per (row, table) from permuted tables ----
  float cs[4] = {0.f, 0.f, 0.f, 0.f};
  #pragma unroll
  for (int r = 0; r < 16; ++r) {
    int row = (r & 3) + 8 * (r >> 2) + 4 * half;
    if (row < W_) {
      int t  = idxS[w][row][0];
      int ci = idxS[w][row][1];
      int p  = idxS[w][row][2];
      float mk = maskS[w][row];
      float4 gt = *(const float4*)&TE2[(size_t)t  * 128 + m32 * 4];
      float4 gc = *(const float4*)&CE2[(size_t)ci * 128 + m32 * 4];
      float4 gp = *(const float4*)&PE2[(size_t)p  * 128 + m32 * 4];
      float g0 = gt.x + gc.x + gp.x;
      float g1 = gt.y + gc.y + gp.y;
      float g2v = gt.z + gc.z + gp.z;
      float g3 = gt.w + gc.w + gp.w;
      cs[0] += fmaxf(acc[0][r] + g0, 0.f) * mk;
      cs[1] += fmaxf(acc[1][r] + g1, 0.f) * mk;
      cs[2] += fmaxf(acc[2][r] + g2v, 0.f) * mk;
      cs[3] += fmaxf(acc[3][r] + g3, 0.f) * mk;
    }
  }
  #pragma unroll
  for (int nt = 0; nt < 4; ++nt) cs[nt] += __shfl_xor(cs[nt], 32);
  if (half == 0) {
    int s_ = bs % S_;
    #pragma unroll
    for (int nt = 0; nt < 4; ++nt) {
      int col = nt * 32 + m32;
      float v = cs[nt] * (1.f / (float)W_) + PEtab[s_ * D_ + col];
      x[(size_t)bs * D_ + col] = v;
      xb[(size_t)bs * D_ + col] = __float2bfloat16(v);
    }
  }

  // ---- activity-fuse tail (cols 128..191): wave-local, barrier-free ----
  {
    float* wsc = &rectS[w][0][0];   // 160 floats available, need 96
    if (lane < 32) {
      float mx = mouse_pos[bs * 2 + 0] * (1.f / 1920.f);
      float my = mouse_pos[bs * 2 + 1] * (1.f / 1080.f);
      wsc[64 + lane] = fmaxf(mw1[lane * 2] * mx + mw1[lane * 2 + 1] * my + mb1[lane], 0.f);
    }
    __builtin_amdgcn_wave_barrier();
    float cv;
    if (lane < 32) {
      float a = mb2[lane];
      const float4* wv = (const float4*)(mw2 + lane * 32);
      const float4* hv = (const float4*)(wsc + 64);
      #pragma unroll
      for (int k4 = 0; k4 < 8; ++k4) {
        float4 ww = wv[k4], hh = hv[k4];
        a += ww.x*hh.x + ww.y*hh.y + ww.z*hh.z + ww.w*hh.w;
      }
      cv = a;
    } else if (lane < 48) {
      cv = act_emb[activity_type[bs] * 16 + (lane - 32)];
    } else {
      cv = kbw[lane - 48] * keyboard_active[bs] + kbb[lane - 48];
    }
    wsc[lane] = cv;
    __builtin_amdgcn_wave_barrier();
    {
      float a = afb[lane];
      const float4* w4 = (const float4*)(afw + lane * 64);
      const float4* cp = (const float4*)wsc;
      #pragma unroll
      for (int k4 = 0; k4 < 16; ++k4) {
        float4 ww = w4[k4], c2 = cp[k4];
        a += ww.x*c2.x + ww.y*c2.y + ww.z*c2.z + ww.w*c2.w;
      }
      float v = fmaxf(a, 0.f);
      int cg = 128 + lane;
      float ovv = v + PEtab[(bs % S_) * D_ + cg];
      x[(size_t)bs * D_ + cg] = ovv;
      xb[(size_t)bs * D_ + cg] = __float2bfloat16(ovv);
    }
  }
}

// ---------------------------------------------------------------------------
// Fused qkv + attention (R28-validated BK=64; unchanged).
// ---------------------------------------------------------------------------
__global__ __launch_bounds__(256)
void qkvattn_kernel(const __hip_bfloat16* __restrict__ xb,
                    const __hip_bfloat16* __restrict__ Wq,
                    const float* __restrict__ qb,
                    __hip_bfloat16* __restrict__ o)
{
  __shared__ __align__(16) char smem[40960];
  __hip_bfloat16* Asl = (__hip_bfloat16*)smem;             // 128*72
  __hip_bfloat16* Bsl = (__hip_bfloat16*)(smem + 18432);   // 96*72
  __hip_bfloat16* Qs  = (__hip_bfloat16*)smem;             // 128*40 (post-K)
  __hip_bfloat16* Ks  = (__hip_bfloat16*)(smem + 10240);   // 128*40 (post-K)
  __hip_bfloat16* Ps  = (__hip_bfloat16*)smem;             // 128*132 (post-QK^T)
  __hip_bfloat16* Vt  = (__hip_bfloat16*)(smem + 33792);   // 32*112

  int bh = blockIdx.x;
  int hh = bh & 7, b = bh >> 3;
  int tid = threadIdx.x, lane = tid & 63, w = tid >> 6;
  int m32 = lane & 31, half = lane >> 5;

  for (int e = tid; e < (32 * 112) / 8; e += 256)
    ((float4*)Vt)[e] = make_float4(0.f, 0.f, 0.f, 0.f);

  int rA0 = tid >> 2,          hA0 = tid & 3;
  int rA1 = (tid + 256) >> 2,  hA1 = tid & 3;
  int rrA0 = rA0 < S_ ? rA0 : S_ - 1;
  int rrA1 = rA1 < S_ ? rA1 : S_ - 1;
  size_t baseA0 = (size_t)(b * S_ + rrA0) * D_;
  size_t baseA1 = (size_t)(b * S_ + rrA1) * D_;
  float4* dA0 = (float4*)&Asl[rA0 * 72 + hA0 * 16];
  float4* dA1 = (float4*)&Asl[rA1 * 72 + hA1 * 16];

  int rB0 = tid >> 2, hB0 = tid & 3;
  int tB0 = rB0 >> 5, jB0 = rB0 & 31;
  bool actB0 = (jB0 < DH_);
  bool isB1 = (tid < 128);
  int rB1 = (tid + 256) >> 2, hB1 = tid & 3;
  int tB1 = rB1 >> 5, jB1 = rB1 & 31;
  bool actB1 = isB1 && (jB1 < DH_);
  size_t baseB0 = actB0 ? (size_t)(tB0 * D_ + hh * DH_ + jB0) * D_ : 0;
  size_t baseB1 = actB1 ? (size_t)(tB1 * D_ + hh * DH_ + jB1) * D_ : 0;
  float4* dB0 = (float4*)&Bsl[rB0 * 72 + hB0 * 16];
  float4* dB1 = (float4*)&Bsl[rB1 * 72 + hB1 * 16];

  {
    float4 z = make_float4(0.f, 0.f, 0.f, 0.f);
    if (!actB0) { dB0[0] = z; dB0[1] = z; }
    if (isB1 && !actB1) { dB1[0] = z; dB1[1] = z; }
  }
  {
    const float4* s0 = (const float4*)&xb[baseA0 + hA0 * 16];
    float4 a00 = s0[0], a01 = s0[1];
    const float4* s1 = (const float4*)&xb[baseA1 + hA1 * 16];
    float4 a10 = s1[0], a11 = s1[1];
    if (actB0) {
      const float4* p = (const float4*)&Wq[baseB0 + hB0 * 16];
      dB0[0] = p[0]; dB0[1] = p[1];
    }
    if (actB1) {
      const float4* p = (const float4*)&Wq[baseB1 + hB1 * 16];
      dB1[0] = p[0]; dB1[1] = p[1];
    }
    dA0[0] = a00; dA0[1] = a01;
    dA1[0] = a10; dA1[1] = a11;
  }

  floatx16 acc[3];
  #pragma unroll
  for (int t = 0; t < 3; ++t)
    #pragma unroll
    for (int r = 0; r < 16; ++r) acc[t][r] = 0.f;

  for (int k0 = 0; k0 < D_; k0 += 64) {
    bool more = (k0 + 64 < D_);
    __syncthreads();                  // stage for k0 visible
    float4 a00, a01, a10, a11, b00, b01, b10, b11;
    if (more) {
      const float4* s0 = (const float4*)&xb[baseA0 + k0 + 64 + hA0 * 16];
      a00 = s0[0]; a01 = s0[1];
      const float4* s1 = (const float4*)&xb[baseA1 + k0 + 64 + hA1 * 16];
      a10 = s1[0]; a11 = s1[1];
      if (actB0) {
        const float4* p = (const float4*)&Wq[baseB0 + k0 + 64 + hB0 * 16];
        b00 = p[0]; b01 = p[1];
      }
      if (actB1) {
        const float4* p = (const float4*)&Wq[baseB1 + k0 + 64 + hB1 * 16];
        b10 = p[0]; b11 = p[1];
      }
    }
    #pragma unroll
    for (int kc = 0; kc < 4; ++kc) {
      int ko = kc * 16 + half * 8;
      short8 a = *(const short8*)&Asl[(w * 32 + m32) * 72 + ko];
      #pragma unroll
      for (int t = 0; t < 3; ++t) {
        short8 bf = *(const short8*)&Bsl[(t * 32 + m32) * 72 + ko];
        acc[t] = __builtin_amdgcn_mfma_f32_32x32x16_bf16(a, bf, acc[t], 0, 0, 0);
      }
    }
    __syncthreads();                  // all waves done reading k0 tile
    if (more) {
      dA0[0] = a00; dA0[1] = a01;
      dA1[0] = a10; dA1[1] = a11;
      if (actB0) { dB0[0] = b00; dB0[1] = b01; }
      if (actB1) { dB1[0] = b10; dB1[1] = b11; }
    }
  }
  // after final barrier: Asl/Bsl dead, safe to alias with Qs/Ks.
  {
    bool dv = (m32 < DH_);
    float bq = dv ? qb[0 * D_ + hh * DH_ + m32] : 0.f;
    float bk = dv ? qb[1 * D_ + hh * DH_ + m32] : 0.f;
    float bv = dv ? qb[2 * D_ + hh * DH_ + m32] : 0.f;
    #pragma unroll
    for (int r = 0; r < 16; ++r) {
      int row = w * 32 + (r & 3) + 8 * (r >> 2) + 4 * half;
      Qs[row * 40 + m32] = __float2bfloat16(dv ? acc[0][r] + bq : 0.f);
      Ks[row * 40 + m32] = __float2bfloat16(dv ? acc[1][r] + bk : 0.f);
      if (dv && row < S_) Vt[m32 * 112 + row] = __float2bfloat16(acc[2][r] + bv);
    }
  }
  __syncthreads();

  floatx16 sc[4];
  #pragma unroll
  for (int nt = 0; nt < 4; ++nt)
    #pragma unroll
    for (int r = 0; r < 16; ++r) sc[nt][r] = 0.f;
  #pragma unroll
  for (int kc = 0; kc < 2; ++kc) {
    int ko = kc * 16 + half * 8;
    short8 a = *(const short8*)&Qs[(w * 32 + m32) * 40 + ko];
    #pragma unroll
    for (int nt = 0; nt < 4; ++nt) {
      short8 bf = *(const short8*)&Ks[(nt * 32 + m32) * 40 + ko];
      sc[nt] = __builtin_amdgcn_mfma_f32_32x32x16_bf16(a, bf, sc[nt], 0, 0, 0);
    }
  }
  __syncthreads();   // all waves done reading Qs/Ks before Ps overwrites them

  const float scale = 0.20412414523193154f;  // 1/sqrt(24)
  float rinv[16];
  #pragma unroll
  for (int r = 0; r < 16; ++r) {
    float mx = -1e30f;
    #pragma unroll
    for (int nt = 0; nt < 4; ++nt) {
      float s = sc[nt][r] * scale;
      if (nt == 3 && m32 >= 4) s = -1e30f;   // keys >= 100
      sc[nt][r] = s;
      mx = fmaxf(mx, s);
    }
    #pragma unroll
    for (int off = 1; off < 32; off <<= 1) mx = fmaxf(mx, __shfl_xor(mx, off));
    float sum = 0.f;
    #pragma unroll
    for (int nt = 0; nt < 4; ++nt) {
      float e = expf(sc[nt][r] - mx);
      sc[nt][r] = e;
      sum += e;
    }
    #pragma unroll
    for (int off = 1; off < 32; off <<= 1) sum += __shfl_xor(sum, off);
    rinv[r] = 1.f / sum;
  }
  #pragma unroll
  for (int r = 0; r < 16; ++r) {
    int rowl = (r & 3) + 8 * (r >> 2) + 4 * half;
    #pragma unroll
    for (int nt = 0; nt < 4; ++nt)
      Ps[(w * 32 + rowl) * 132 + nt * 32 + m32] = __float2bfloat16(sc[nt][r]);
  }
  // Ps is wave-private — no barrier.

  floatx16 ov;
  #pragma unroll
  for (int r = 0; r < 16; ++r) ov[r] = 0.f;
  #pragma unroll
  for (int kt = 0; kt < 7; ++kt) {       // 112 keys (100..111: P=0, Vt=0)
    int ko = kt * 16 + half * 8;
    short8 a = ld_frag8(&Ps[(w * 32 + m32) * 132 + ko]);
    short8 bf = *(const short8*)&Vt[m32 * 112 + ko];
    ov = __builtin_amdgcn_mfma_f32_32x32x16_bf16(a, bf, ov, 0, 0, 0);
  }
  #pragma unroll
  for (int r = 0; r < 16; ++r) {
    int rowl = (r & 3) + 8 * (r >> 2) + 4 * half;
    int q = w * 32 + rowl;
    if (m32 < DH_ && q < S_)
      o[((size_t)(b * S_ + q)) * D_ + hh * DH_ + m32] =
          __float2bfloat16(ov[r] * rinv[r]);
  }
}

// ---------------------------------------------------------------------------
// Fused out-proj+LN1 + ff1+ff2+LN2 (R27-validated BK=64; unchanged).
// ---------------------------------------------------------------------------
__global__ __launch_bounds__(256)
void outffln_kernel(const __hip_bfloat16* __restrict__ attb,
                    const __hip_bfloat16* __restrict__ Wo, const float* __restrict__ bo,
                    const float* __restrict__ g1, const float* __restrict__ b1v,
                    const __hip_bfloat16* __restrict__ W1, const float* __restrict__ b1,
                    const __hip_bfloat16* __restrict__ W2, const float* __restrict__ b2,
                    const float* __restrict__ g2, const float* __restrict__ b2v,
                    float* __restrict__ x, __hip_bfloat16* __restrict__ xb)
{
  __shared__ __align__(16) char arena[61952];
  __hip_bfloat16* AslA  = (__hip_bfloat16*)arena;             // 64*72
  __hip_bfloat16* BslA  = (__hip_bfloat16*)(arena + 9216);    // 192*72
  __hip_bfloat16* Afull = (__hip_bfloat16*)arena;             // 64*196 (post-LN1)
  __hip_bfloat16* BslB1 = (__hip_bfloat16*)(arena + 25088);   // 256*72 (W1)
  __hip_bfloat16* C1    = (__hip_bfloat16*)arena;             // 64*260 (post-ff1)
  __hip_bfloat16* BslB2 = (__hip_bfloat16*)(arena + 33280);   // 192*72 (W2)
  float (*psum)[2] = (float(*)[2])(arena + 60928);
  float (*psq)[2]  = (float(*)[2])(arena + 61440);

  int tid = threadIdx.x, lane = tid & 63, w = tid >> 6;
  int m32 = lane & 31, half = lane >> 5;
  int mt = w & 1, ng = w >> 1;
  int bm = blockIdx.x * 64;

  // ========= phase A: out-proj + residual + LN1 (K=192, 3 rounds of 64) ====
  floatx16 accA[3];
  #pragma unroll
  for (int j = 0; j < 3; ++j)
    #pragma unroll
    for (int r = 0; r < 16; ++r) accA[j][r] = 0.f;

  {
    int ra = tid >> 2, ha = tid & 3;
    float4* dA = (float4*)&AslA[ra * 72 + ha * 16];
    int rb0 = tid >> 2,           hb0 = tid & 3;
    int rb1 = (tid + 256) >> 2,   hb1 = tid & 3;
    int rb2 = (tid + 512) >> 2,   hb2 = tid & 3;
    float4* dB0 = (float4*)&BslA[rb0 * 72 + hb0 * 16];
    float4* dB1 = (float4*)&BslA[rb1 * 72 + hb1 * 16];
    float4* dB2 = (float4*)&BslA[rb2 * 72 + hb2 * 16];

    {
      const float4* s = (const float4*)(attb + (size_t)(bm + ra) * D_ + ha * 16);
      dA[0] = s[0]; dA[1] = s[1];
      const float4* p0 = (const float4*)(Wo + (size_t)rb0 * D_ + hb0 * 16);
      dB0[0] = p0[0]; dB0[1] = p0[1];
      const float4* p1 = (const float4*)(Wo + (size_t)rb1 * D_ + hb1 * 16);
      dB1[0] = p1[0]; dB1[1] = p1[1];
      const float4* p2 = (const float4*)(Wo + (size_t)rb2 * D_ + hb2 * 16);
      dB2[0] = p2[0]; dB2[1] = p2[1];
    }
    for (int k0 = 0; k0 < D_; k0 += 64) {
      bool more = (k0 + 64 < D_);
      __syncthreads();
      float4 na0, na1, n00, n01, n10, n11, n20, n21;
      if (more) {
        const float4* s = (const float4*)(attb + (size_t)(bm + ra) * D_ + k0 + 64 + ha * 16);
        na0 = s[0]; na1 = s[1];
        const float4* p0 = (const float4*)(Wo + (size_t)rb0 * D_ + k0 + 64 + hb0 * 16);
        n00 = p0[0]; n01 = p0[1];
        const float4* p1 = (const float4*)(Wo + (size_t)rb1 * D_ + k0 + 64 + hb1 * 16);
        n10 = p1[0]; n11 = p1[1];
        const float4* p2 = (const float4*)(Wo + (size_t)rb2 * D_ + k0 + 64 + hb2 * 16);
        n20 = p2[0]; n21 = p2[1];
      }
      #pragma unroll
      for (int kc = 0; kc < 4; ++kc) {
        int ko = kc * 16 + half * 8;
        short8 a = *(const short8*)&AslA[(mt * 32 + m32) * 72 + ko];
        #pragma unroll
        for (int j = 0; j < 3; ++j) {
          short8 bf = *(const short8*)&BslA[((ng * 3 + j) * 32 + m32) * 72 + ko];
          accA[j] = __builtin_amdgcn_mfma_f32_32x32x16_bf16(a, bf, accA[j], 0, 0, 0);
        }
      }
      __syncthreads();
      if (more) {
        dA[0] = na0; dA[1] = na1;
        dB0[0] = n00; dB0[1] = n01;
        dB1[0] = n10; dB1[1] = n11;
        dB2[0] = n20; dB2[1] = n21;
      }
    }
  }
  {
    int rowb = mt * 32 + 4 * half;
    #pragma unroll
    for (int r = 0; r < 16; ++r) {
      int rl = rowb + (r & 3) + 8 * (r >> 2);
      int row = bm + rl;
      float p = 0.f;
      #pragma unroll
      for (int j = 0; j < 3; ++j) {
        int col = (ng * 3 + j) * 32 + m32;
        float t = accA[j][r] + bo[col] + x[(size_t)row * D_ + col];
        accA[j][r] = t;
        p += t;
      }
      #pragma unroll
      for (int off = 1; off < 32; off <<= 1) p += __shfl_xor(p, off);
      if (m32 == 0) psum[rl][ng] = p;
    }
    __syncthreads();
    float mean[16];
    #pragma unroll
    for (int r = 0; r < 16; ++r) {
      int rl = rowb + (r & 3) + 8 * (r >> 2);
      mean[r] = (psum[rl][0] + psum[rl][1]) * (1.f / (float)D_);
    }
    #pragma unroll
    for (int r = 0; r < 16; ++r) {
      int rl = rowb + (r & 3) + 8 * (r >> 2);
      float s = 0.f;
      #pragma unroll
      for (int j = 0; j < 3; ++j) { float dd = accA[j][r] - mean[r]; s += dd * dd; }
      #pragma unroll
      for (int off = 1; off < 32; off <<= 1) s += __shfl_xor(s, off);
      if (m32 == 0) psq[rl][ng] = s;
    }
    __syncthreads();   // also: last use of AslA/BslA before Afull writes
    #pragma unroll
    for (int r = 0; r < 16; ++r) {
      int rl = rowb + (r & 3) + 8 * (r >> 2);
      int row = bm + rl;
      float inv = rsqrtf((psq[rl][0] + psq[rl][1]) * (1.f / (float)D_) + 1e-5f);
      #pragma unroll
      for (int j = 0; j < 3; ++j) {
        int col = (ng * 3 + j) * 32 + m32;
        float ovv = (accA[j][r] - mean[r]) * inv * g1[col] + b1v[col];
        x[(size_t)row * D_ + col] = ovv;
        __hip_bfloat16 hb = __float2bfloat16(ovv);
        xb[(size_t)row * D_ + col] = hb;
        Afull[rl * 196 + col] = hb;
      }
    }
  }
  __syncthreads();   // Afull complete before ff1 reads

  // ========= ff1 (A from Afull; W1 256x4 = 1024 items, 4/thread) =========
  floatx16 acc1[4];
  #pragma unroll
  for (int j = 0; j < 4; ++j)
    #pragma unroll
    for (int r = 0; r < 16; ++r) acc1[j][r] = 0.f;

  {
    int rb0 = tid >> 2,          hb0 = tid & 3;
    int rb1 = (tid + 256) >> 2,  hb1 = tid & 3;
    int rb2 = (tid + 512) >> 2,  hb2 = tid & 3;
    int rb3 = (tid + 768) >> 2,  hb3 = tid & 3;
    float4* dB0 = (float4*)&BslB1[rb0 * 72 + hb0 * 16];
    float4* dB1 = (float4*)&BslB1[rb1 * 72 + hb1 * 16];
    float4* dB2 = (float4*)&BslB1[rb2 * 72 + hb2 * 16];
    float4* dB3 = (float4*)&BslB1[rb3 * 72 + hb3 * 16];
    {
      const float4* p0 = (const float4*)(W1 + (size_t)rb0 * D_ + hb0 * 16);
      dB0[0] = p0[0]; dB0[1] = p0[1];
      const float4* p1 = (const float4*)(W1 + (size_t)rb1 * D_ + hb1 * 16);
      dB1[0] = p1[0]; dB1[1] = p1[1];
      const float4* p2 = (const float4*)(W1 + (size_t)rb2 * D_ + hb2 * 16);
      dB2[0] = p2[0]; dB2[1] = p2[1];
      const float4* p3 = (const float4*)(W1 + (size_t)rb3 * D_ + hb3 * 16);
      dB3[0] = p3[0]; dB3[1] = p3[1];
    }
    for (int k0 = 0; k0 < D_; k0 += 64) {
      bool more = (k0 + 64 < D_);
      __syncthreads();
      float4 n00, n01, n10, n11, n20, n21, n30, n31;
      if (more) {
        const float4* p0 = (const float4*)(W1 + (size_t)rb0 * D_ + k0 + 64 + hb0 * 16);
        n00 = p0[0]; n01 = p0[1];
        const float4* p1 = (const float4*)(W1 + (size_t)rb1 * D_ + k0 + 64 + hb1 * 16);
        n10 = p1[0]; n11 = p1[1];
        const float4* p2 = (const float4*)(W1 + (size_t)rb2 * D_ + k0 + 64 + hb2 * 16);
        n20 = p2[0]; n21 = p2[1];
        const float4* p3 = (const float4*)(W1 + (size_t)rb3 * D_ + k0 + 64 + hb3 * 16);
        n30 = p3[0]; n31 = p3[1];
      }
      #pragma unroll
      for (int kc = 0; kc < 4; ++kc) {
        int ko = kc * 16 + half * 8;
        short8 a = ld_frag8(&Afull[(mt * 32 + m32) * 196 + k0 + ko]);
        #pragma unroll
        for (int j = 0; j < 4; ++j) {
          short8 bf = *(const short8*)&BslB1[((ng * 4 + j) * 32 + m32) * 72 + ko];
          acc1[j] = __builtin_amdgcn_mfma_f32_32x32x16_bf16(a, bf, acc1[j], 0, 0, 0);
        }
      }
      __syncthreads();
      if (more) {
        dB0[0] = n00; dB0[1] = n01;
        dB1[0] = n10; dB1[1] = n11;
        dB2[0] = n20; dB2[1] = n21;
        dB3[0] = n30; dB3[1] = n31;
      }
    }
  }
  // ff1 epilogue: relu -> C1 (aliases dead Afull + BslB1 head).
  {
    int rowb = mt * 32 + 4 * half;
    #pragma unroll
    for (int j = 0; j < 4; ++j) {
      int col = (ng * 4 + j) * 32 + m32;
      float cb = b1[col];
      #pragma unroll
      for (int r = 0; r < 16; ++r) {
        int row = rowb + (r & 3) + 8 * (r >> 2);
        C1[row * 260 + col] = __float2bfloat16(fmaxf(acc1[j][r] + cb, 0.f));
      }
    }
  }

  // ========= ff2 (A from C1; W2 192x4 = 768 items, 3/thread; K=256) =======
  floatx16 acc2[3];
  #pragma unroll
  for (int j = 0; j < 3; ++j)
    #pragma unroll
    for (int r = 0; r < 16; ++r) acc2[j][r] = 0.f;

  {
    int rb0 = tid >> 2,          hb0 = tid & 3;
    int rb1 = (tid + 256) >> 2,  hb1 = tid & 3;
    int rb2 = (tid + 512) >> 2,  hb2 = tid & 3;
    float4* dB0 = (float4*)&BslB2[rb0 * 72 + hb0 * 16];
    float4* dB1 = (float4*)&BslB2[rb1 * 72 + hb1 * 16];
    float4* dB2 = (float4*)&BslB2[rb2 * 72 + hb2 * 16];
    {
      const float4* p0 = (const float4*)(W2 + (size_t)rb0 * DFF_ + hb0 * 16);
      dB0[0] = p0[0]; dB0[1] = p0[1];
      const float4* p1 = (const float4*)(W2 + (size_t)rb1 * DFF_ + hb1 * 16);
      dB1[0] = p1[0]; dB1[1] = p1[1];
      const float4* p2 = (const float4*)(W2 + (size_t)rb2 * DFF_ + hb2 * 16);
      dB2[0] = p2[0]; dB2[1] = p2[1];
    }
    for (int k0 = 0; k0 < DFF_; k0 += 64) {
      bool more = (k0 + 64 < DFF_);
      __syncthreads();                    // C1 + BslB2 tile visible
      float4 n00, n01, n10, n11, n20, n21;
      if (more) {
        const float4* p0 = (const float4*)(W2 + (size_t)rb0 * DFF_ + k0 + 64 + hb0 * 16);
        n00 = p0[0]; n01 = p0[1];
        const float4* p1 = (const float4*)(W2 + (size_t)rb1 * DFF_ + k0 + 64 + hb1 * 16);
        n10 = p1[0]; n11 = p1[1];
        const float4* p2 = (const float4*)(W2 + (size_t)rb2 * DFF_ + k0 + 64 + hb2 * 16);
        n20 = p2[0]; n21 = p2[1];
      }
      #pragma unroll
      for (int kc = 0; kc < 4; ++kc) {
        int ko = kc * 16 + half * 8;
        short8 a = ld_frag8(&C1[(mt * 32 + m32) * 260 + k0 + ko]);
        #pragma unroll
        for (int j = 0; j < 3; ++j) {
          short8 bf = *(const short8*)&BslB2[((ng * 3 + j) * 32 + m32) * 72 + ko];
          acc2[j] = __builtin_amdgcn_mfma_f32_32x32x16_bf16(a, bf, acc2[j], 0, 0, 0);
        }
      }
      __syncthreads();
      if (more) {
        dB0[0] = n00; dB0[1] = n01;
        dB1[0] = n10; dB1[1] = n11;
        dB2[0] = n20; dB2[1] = n21;
      }
    }
  }

  int rowb = mt * 32 + 4 * half;
  #pragma unroll
  for (int r = 0; r < 16; ++r) {
    int rl = rowb + (r & 3) + 8 * (r >> 2);
    int row = bm + rl;
    float p = 0.f;
    #pragma unroll
    for (int j = 0; j < 3; ++j) {
      int col = (ng * 3 + j) * 32 + m32;
      float t = acc2[j][r] + b2[col] + x[(size_t)row * D_ + col];
      acc2[j][r] = t;
      p += t;
    }
    #pragma unroll
    for (int off = 1; off < 32; off <<= 1) p += __shfl_xor(p, off);
    if (m32 == 0) psum[rl][ng] = p;
  }
  __syncthreads();
  float mean[16];
  #pragma unroll
  for (int r = 0; r < 16; ++r) {
    int rl = rowb + (r & 3) + 8 * (r >> 2);
    mean[r] = (psum[rl][0] + psum[rl][1]) * (1.f / (float)D_);
  }
  #pragma unroll
  for (int r = 0; r < 16; ++r) {
    int rl = rowb + (r & 3) + 8 * (r >> 2);
    float s = 0.f;
    #pragma unroll
    for (int j = 0; j < 3; ++j) { float dd = acc2[j][r] - mean[r]; s += dd * dd; }
    #pragma unroll
    for (int off = 1; off < 32; off <<= 1) s += __shfl_xor(s, off);
    if (m32 == 0) psq[rl][ng] = s;
  }
  __syncthreads();
  #pragma unroll
  for (int r = 0; r < 16; ++r) {
    int rl = rowb + (r & 3) + 8 * (r >> 2);
    int row = bm + rl;
    float inv = rsqrtf((psq[rl][0] + psq[rl][1]) * (1.f / (float)D_) + 1e-5f);
    #pragma unroll
    for (int j = 0; j < 3; ++j) {
      int col = (ng * 3 + j) * 32 + m32;
      float ovv = (acc2[j][r] - mean[r]) * inv * g2[col] + b2v[col];
      x[(size_t)row * D_ + col] = ovv;
      xb[(size_t)row * D_ + col] = __float2bfloat16(ovv);
    }
  }
}

// ---------------------------------------------------------------------------
// Head v3 (R26-validated): grid 640 = b x 5 window-groups of 4.
// ---------------------------------------------------------------------------
__global__ __launch_bounds__(256)
void head3_kernel(const float* __restrict__ x, const float* __restrict__ noise,
                  const float* __restrict__ pw1, const float* __restrict__ pb1,
                  const float* __restrict__ pw2, const float* __restrict__ pb2,
                  const float* __restrict__ ew1, const float* __restrict__ eb1,
                  const float* __restrict__ ew2, const float* __restrict__ eb2,
                  float* __restrict__ out)
{
  __shared__ float slotS[4][192];    // 3072
  __shared__ float phS[4][256];      // 4096
  __shared__ float ehS[4][128];      // 2048
  int blk = blockIdx.x;
  int b = blk / 5, g = blk - b * 5;  // windows g*4 .. g*4+3
  int tid = threadIdx.x;

  const float* lastrow = x + ((size_t)b * S_ + (S_ - 1)) * D_;
  for (int e = tid; e < 4 * 192; e += 256) {
    int wl = e / 192, c = e - wl * 192;
    int wg = g * 4 + wl;
    slotS[wl][c] = lastrow[c] + noise[((size_t)wg * B_ + b) * D_ + c] * 0.1f;
  }
  __syncthreads();

  bool doe = (tid < 128);
  float accp[4], acce[4];
  {
    float bp = pb1[tid];
    float be = doe ? eb1[tid] : 0.f;
    #pragma unroll
    for (int wl = 0; wl < 4; ++wl) { accp[wl] = bp; acce[wl] = be; }
  }
  {
    const float4* wr = (const float4*)(pw1 + (size_t)tid * D_);
    const float4* we = (const float4*)(ew1 + (size_t)(doe ? tid : 0) * D_);
    for (int k4 = 0; k4 < 48; ++k4) {
      float4 wv = wr[k4];
      float4 ev = we[k4];
      #pragma unroll
      for (int wl = 0; wl < 4; ++wl) {
        float4 sv = *(const float4*)&slotS[wl][k4 * 4];
        accp[wl] += wv.x*sv.x + wv.y*sv.y + wv.z*sv.z + wv.w*sv.w;
        if (doe) acce[wl] += ev.x*sv.x + ev.y*sv.y + ev.z*sv.z + ev.w*sv.w;
      }
    }
  }
  #pragma unroll
  for (int wl = 0; wl < 4; ++wl) {
    phS[wl][tid] = fmaxf(accp[wl], 0.f);
    if (doe) ehS[wl][tid] = fmaxf(acce[wl], 0.f);
  }
  __syncthreads();

  if (tid < 16) {
    int wl = tid >> 2, c = tid & 3;
    float a = pb2[c];
    const float4* wr = (const float4*)(pw2 + c * 256);
    const float4* pp = (const float4*)&phS[wl][0];
    for (int k = 0; k < 64; ++k) {
      float4 wv = wr[k], pv = pp[k];
      a += wv.x*pv.x + wv.y*pv.y + wv.z*pv.z + wv.w*pv.w;
    }
    out[((size_t)b * W_ + g * 4 + wl) * 4 + c] = a;
  } else if (tid >= 64 && tid < 68) {
    int wl = tid - 64;
    float a = eb2[0];
    const float4* wr = (const float4*)ew2;
    const float4* pp = (const float4*)&ehS[wl][0];
    for (int k = 0; k < 32; ++k) {
      float4 wv = wr[k], pv = pp[k];
      a += wv.x*pv.x + wv.y*pv.y + wv.z*pv.z + wv.w*pv.w;
    }
    out[(size_t)B_ * W_ * 4 + (size_t)b * W_ + g * 4 + wl] = 1.f / (1.f + expf(-a));
  }
}

// ---------------------------------------------------------------------------
extern "C" void kernel_launch(void* const* d_in, const int* in_sizes, int n_in,
                              void* d_out, int out_size, void* d_ws, size_t ws_size,
                              hipStream_t stream)
{
  const int*   title_idx       = (const int*)  d_in[0];
  const int*   class_idx       = (const int*)  d_in[1];
  const int*   process_idx     = (const int*)  d_in[2];
  const int*   activity_type   = (const int*)  d_in[3];
  const float* mouse_pos       = (const float*)d_in[4];
  const float* rect            = (const float*)d_in[5];
  const float* flags           = (const float*)d_in[6];
  const float* keyboard_active = (const float*)d_in[7];
  const float* window_mask     = (const float*)d_in[8];
  const float* noise           = (const float*)d_in[9];
  const float* title_emb       = (const float*)d_in[10];
  const float* class_emb       = (const float*)d_in[11];
  const float* process_emb     = (const float*)d_in[12];
  const float* spatial_w1      = (const float*)d_in[13];
  const float* spatial_b1      = (const float*)d_in[14];
  const float* spatial_w2      = (const float*)d_in[15];
  const float* spatial_b2      = (const float*)d_in[16];
  const float* wfuse_w         = (const float*)d_in[17];
  const float* wfuse_b         = (const float*)d_in[18];
  const float* mouse_w1        = (const float*)d_in[19];
  const float* mouse_b1        = (const float*)d_in[20];
  const float* mouse_w2        = (const float*)d_in[21];
  const float* mouse_b2        = (const float*)d_in[22];
  const float* act_emb         = (const float*)d_in[23];
  const float* kbd_w           = (const float*)d_in[24];
  const float* kbd_b           = (const float*)d_in[25];
  const float* afuse_w         = (const float*)d_in[26];
  const float* afuse_b         = (const float*)d_in[27];
  const float* qkv_w           = (const float*)d_in[28];
  const float* qkv_b           = (const float*)d_in[29];
  const float* out_w           = (const float*)d_in[30];
  const float* out_b           = (const float*)d_in[31];
  const float* ff1_w           = (const float*)d_in[32];
  const float* ff1_b           = (const float*)d_in[33];
  const float* ff2_w           = (const float*)d_in[34];
  const float* ff2_b           = (const float*)d_in[35];
  const float* ln1_g           = (const float*)d_in[36];
  const float* ln1_b           = (const float*)d_in[37];
  const float* ln2_g           = (const float*)d_in[38];
  const float* ln2_b           = (const float*)d_in[39];
  const float* proj_w1         = (const float*)d_in[40];
  const float* proj_b1         = (const float*)d_in[41];
  const float* proj_w2         = (const float*)d_in[42];
  const float* proj_b2         = (const float*)d_in[43];
  const float* ex_w1           = (const float*)d_in[44];
  const float* ex_b1           = (const float*)d_in[45];
  const float* ex_w2           = (const float*)d_in[46];
  const float* ex_b2           = (const float*)d_in[47];

  float* out = (float*)d_out;

  // workspace layout
  float* x = (float*)d_ws;                                      // BS*192 f32
  __hip_bfloat16* xb   = (__hip_bfloat16*)(x + (size_t)BS_ * D_);
  __hip_bfloat16* attb = xb   + (size_t)BS_ * D_;
  __hip_bfloat16* wqb  = attb + (size_t)BS_ * D_;
  __hip_bfloat16* wob  = wqb  + (size_t)L_ * THREED_ * D_;
  __hip_bfloat16* wf1b = wob  + (size_t)L_ * D_ * D_;
  __hip_bfloat16* wf2b = wf1b + (size_t)L_ * DFF_ * D_;
  float* TE2  = (float*)(wf2b + (size_t)L_ * D_ * DFF_);        // 1000*128 (permuted cols)
  float* CE2  = TE2  + 1000 * 128;                              // 500*128
  float* PE2  = CE2  + 500 * 128;                               // 1000*128
  __hip_bfloat16* WSPb = (__hip_bfloat16*)(PE2 + 1000 * 128);   // 128*64 bf16
  float* PEtab = (float*)(WSPb + 128 * 64);                     // 100*192 f32
  (void)ws_size; (void)n_in; (void)in_sizes; (void)out_size;

  convertprep_kernel<<<2077, 256, 0, stream>>>(
      qkv_w, wqb, out_w, wob, ff1_w, wf1b, ff2_w, wf2b,
      title_emb, class_emb, process_emb, wfuse_w, wfuse_b,
      spatial_w2, spatial_b2, TE2, CE2, PE2, WSPb, PEtab);

  encode8_kernel<<<BS_ / 16, 1024, 0, stream>>>(
      title_idx, class_idx, process_idx, activity_type, mouse_pos, rect, flags,
      keyboard_active, window_mask, spatial_w1, spatial_b1,
      TE2, CE2, PE2, WSPb, PEtab,
      mouse_w1, mouse_b1, mouse_w2, mouse_b2, act_emb, kbd_w, kbd_b,
      afuse_w, afuse_b, x, xb);

  for (int l = 0; l < L_; ++l) {
    qkvattn_kernel<<<B_ * H_, 256, 0, stream>>>(
        xb, wqb + (size_t)l * THREED_ * D_, qkv_b + (size_t)l * THREED_, attb);
    outffln_kernel<<<BS_ / 64, 256, 0, stream>>>(
        attb, wob + (size_t)l * D_ * D_, out_b + (size_t)l * D_,
        ln1_g + (size_t)l * D_, ln1_b + (size_t)l * D_,
        wf1b + (size_t)l * DFF_ * D_, ff1_b + (size_t)l * DFF_,
        wf2b + (size_t)l * D_ * DFF_, ff2_b + (size_t)l * D_,
        ln2_g + (size_t)l * D_, ln2_b + (size_t)l * D_, x, xb);
  }

  head3_kernel<<<B_ * 5, 256, 0, stream>>>(
      x, noise, proj_w1, proj_b1, proj_w2, proj_b2,
      ex_w1, ex_b1, ex_w2, ex_b2, out);
}

// Round 16
// 656.213 us; speedup vs baseline: 1.0263x; 1.0263x over previous
//
#include <hip/hip_runtime.h>
#include <hip/hip_bf16.h>
#include <math.h>

#define B_ 128
#define S_ 100
#define W_ 20
#define D_ 192
#define L_ 6
#define H_ 8
#define DFF_ 256
#define DH_ 24
#define BS_ (B_*S_)
#define THREED_ 576

typedef short short8 __attribute__((ext_vector_type(8)));
typedef short short4v __attribute__((ext_vector_type(4)));
typedef float floatx16 __attribute__((ext_vector_type(16)));

__device__ __forceinline__ float posenc(int s, int c) {
  float freq = expf(-logf(10000.f) * (float)(2 * (c >> 1)) / (float)D_);
  float ang = (float)s * freq;
  return (c & 1) ? cosf(ang) : sinf(ang);
}

__device__ __forceinline__ short8 ld_frag8(const __hip_bfloat16* p) {
  short4v lo = *(const short4v*)p;
  short4v hi = *(const short4v*)(p + 4);
  short8 r;
  r[0]=lo[0]; r[1]=lo[1]; r[2]=lo[2]; r[3]=lo[3];
  r[4]=hi[0]; r[5]=hi[1]; r[6]=hi[2]; r[7]=hi[3];
  return r;
}

__device__ __forceinline__ short f2bf_s(float v) {
  __hip_bfloat16 t = __float2bfloat16(v);
  return *reinterpret_cast<short*>(&t);
}

__device__ __forceinline__ float dot4(float4 a, float4 b) {
  return a.x*b.x + a.y*b.y + a.z*b.z + a.w*b.w;
}

// ---------------------------------------------------------------------------
// Merged weight conversion + encoder precompute (R24-validated). 2077 blocks.
// ---------------------------------------------------------------------------
__global__ __launch_bounds__(256)
void convertprep_kernel(
    const float* __restrict__ s0, __hip_bfloat16* __restrict__ d0,
    const float* __restrict__ s1, __hip_bfloat16* __restrict__ d1,
    const float* __restrict__ s2, __hip_bfloat16* __restrict__ d2,
    const float* __restrict__ s3, __hip_bfloat16* __restrict__ d3,
    const float* __restrict__ te, const float* __restrict__ ce,
    const float* __restrict__ pe, const float* __restrict__ wfw,
    const float* __restrict__ wfb, const float* __restrict__ sw2,
    const float* __restrict__ sb2,
    float* __restrict__ TE2, float* __restrict__ CE2,
    float* __restrict__ PE2, __hip_bfloat16* __restrict__ WSPb,
    float* __restrict__ PEtab)
{
  int b = blockIdx.x, tid = threadIdx.x;
  if (b < 720) {
    const float* s; __hip_bfloat16* d; int base;
    if      (b < 324) { s = s0; d = d0; base = b; }
    else if (b < 432) { s = s1; d = d1; base = b - 324; }
    else if (b < 576) { s = s2; d = d2; base = b - 432; }
    else              { s = s3; d = d3; base = b - 576; }
    int i = (base * 256 + tid) * 8;
    float4 v0 = *(const float4*)(s + i);
    float4 v1 = *(const float4*)(s + i + 4);
    __hip_bfloat162* d2p = (__hip_bfloat162*)(d + i);
    d2p[0] = __float22bfloat162_rn(make_float2(v0.x, v0.y));
    d2p[1] = __float22bfloat162_rn(make_float2(v0.z, v0.w));
    d2p[2] = __float22bfloat162_rn(make_float2(v1.x, v1.y));
    d2p[3] = __float22bfloat162_rn(make_float2(v1.z, v1.w));
    return;
  }
  int blk = b - 720;
  if (blk < 1250) {
    int item = blk * 256 + tid;
    int v = item >> 7, o = item & 127;
    const float* src; float* dst; int base, vv;
    float a;
    if (v < 1000) {
      src = te; dst = TE2; base = 0; vv = v;
      a = wfb[o];                                 // fold wfuse bias
      const float4* w4 = (const float4*)(wfw + o * 128 + 96);
      const float4* b4 = (const float4*)sb2;
      #pragma unroll
      for (int k4 = 0; k4 < 8; ++k4) a += dot4(w4[k4], b4[k4]);
    } else if (v < 1500) {
      src = ce; dst = CE2; base = 32; vv = v - 1000; a = 0.f;
    } else {
      src = pe; dst = PE2; base = 64; vv = v - 1500; a = 0.f;
    }
    const float4* s4 = (const float4*)(src + vv * 32);
    const float4* w4 = (const float4*)(wfw + o * 128 + base);
    #pragma unroll
    for (int k4 = 0; k4 < 8; ++k4) a += dot4(s4[k4], w4[k4]);
    int op = ((o & 31) << 2) + (o >> 5);          // R23 permuted placement
    dst[vv * 128 + op] = a;
  } else if (blk < 1282) {
    int item = (blk - 1250) * 256 + tid;
    int j = item >> 7, o = item & 127;           // j = hidden k, o = out col
    float a = 0.f;
    #pragma unroll 8
    for (int k = 0; k < 32; ++k) a += wfw[o * 128 + 96 + k] * sw2[k * 64 + j];
    WSPb[o * 64 + j] = __float2bfloat16(a);      // B operand [col][k]
  } else {
    int idx = (blk - 1282) * 256 + tid;          // [0, 19200)
    int s_ = idx / D_, c = idx - s_ * D_;
    PEtab[idx] = posenc(s_, c);
  }
}

// ---------------------------------------------------------------------------
// Encoder v13 (R29-measured BEST ~100us; R30's 16-bs variant regressed to
// 113 -- staging-amortization lever saturates at 8 bs/block. Reverted.)
// 8 bs/block, 512 threads, grid 1600. LDS 26.1KB.
// ---------------------------------------------------------------------------
__global__ __launch_bounds__(512)
void encode8_kernel(
    const int* __restrict__ title_idx, const int* __restrict__ class_idx,
    const int* __restrict__ process_idx, const int* __restrict__ activity_type,
    const float* __restrict__ mouse_pos, const float* __restrict__ rect,
    const float* __restrict__ flags, const float* __restrict__ keyboard_active,
    const float* __restrict__ window_mask,
    const float* __restrict__ sw1, const float* __restrict__ sb1,
    const float* __restrict__ TE2, const float* __restrict__ CE2,
    const float* __restrict__ PE2, const __hip_bfloat16* __restrict__ WSPb,
    const float* __restrict__ PEtab,
    const float* __restrict__ mw1, const float* __restrict__ mb1,
    const float* __restrict__ mw2, const float* __restrict__ mb2,
    const float* __restrict__ act_emb, const float* __restrict__ kbw,
    const float* __restrict__ kbb,
    const float* __restrict__ afw, const float* __restrict__ afb,
    float* __restrict__ x, __hip_bfloat16* __restrict__ xb)
{
  __shared__ __hip_bfloat16 Bls[128][72];            // 18432
  __shared__ int   idxS[8][20][3];                   // 1920
  __shared__ float maskS[8][20];                     // 640
  __shared__ __align__(16) float rectS[8][20][8];    // 5120 (wave-private after stage)

  int tid = threadIdx.x;
  int w = tid >> 6, lane = tid & 63;
  int m32 = lane & 31, half = lane >> 5;
  int bs0 = blockIdx.x * 8;
  int bs = bs0 + w;

  if (tid < 480) {
    int g2 = tid / 60, rem = tid % 60, which = rem / 20, w_ = rem % 20;
    const int* src = (which == 0) ? title_idx : (which == 1) ? class_idx : process_idx;
    idxS[g2][w_][which] = src[(bs0 + g2) * W_ + w_];
  }
  if (tid < 160) {
    int g2 = tid / 20, w_ = tid % 20;
    maskS[g2][w_] = window_mask[(bs0 + g2) * W_ + w_];
  }
  for (int e = tid; e < 960; e += 512) {      // 8*20*6
    int g2 = e / 120, rem = e % 120, w_ = rem / 6, c = rem % 6;
    int rg = (bs0 + g2) * W_ + w_;
    rectS[g2][w_][c] = (c < 4) ? rect[rg * 4 + c] : flags[rg * 2 + (c - 4)];
  }
  for (int e = tid; e < 1024; e += 512) {     // 128 cols x 8 k-groups of 8
    int col = e >> 3, k8 = e & 7;
    short8 v = *(const short8*)&WSPb[col * 64 + k8 * 8];
    *(short8*)&Bls[col][k8 * 8] = v;
  }
  __syncthreads();

  short8 afr[4];
  {
    float rc[6];
    bool act = (m32 < W_);
    if (act) {
      #pragma unroll
      for (int c = 0; c < 6; ++c) rc[c] = rectS[w][m32][c];
    }
    #pragma unroll
    for (int s = 0; s < 4; ++s) {
      short8 f;
      #pragma unroll
      for (int jp = 0; jp < 8; ++jp) {
        float a = 0.f;
        if (act) {
          int j = s * 16 + half * 8 + jp;
          const float* w1 = sw1 + j * 6;
          a = sb1[j];
          #pragma unroll
          for (int c = 0; c < 6; ++c) a += w1[c] * rc[c];
          a = fmaxf(a, 0.f);
        }
        f[jp] = f2bf_s(a);
      }
      afr[s] = f;
    }
  }

  floatx16 acc[4];
  #pragma unroll
  for (int nt = 0; nt < 4; ++nt)
    #pragma unroll
    for (int r = 0; r < 16; ++r) acc[nt][r] = 0.f;

  #pragma unroll
  for (int s = 0; s < 4; ++s) {
    int ko = s * 16 + half * 8;
    #pragma unroll
    for (int nt = 0; nt < 4; ++nt) {
      short8 bf = *(const short8*)&Bls[nt * 32 + m32][ko];
      acc[nt] = __builtin_amdgcn_mfma_f32_32x32x16_bf16(afr[s], bf, acc[nt], 0, 0, 0);
    }
  }

  // ---- epilogue: one float4 per (row, table) from permuted tables ----
  float cs[4] = {0.f, 0.f, 0.f, 0.f};
  #pragma unroll
  for (int r = 0; r < 16; ++r) {
    int row = (r & 3) + 8 * (r >> 2) + 4 * half;
    if (row < W_) {
      int t  = idxS[w][row][0];
      int ci = idxS[w][row][1];
      int p  = idxS[w][row][2];
      float mk = maskS[w][row];
      float4 gt = *(const float4*)&TE2[(size_t)t  * 128 + m32 * 4];
      float4 gc = *(const float4*)&CE2[(size_t)ci * 128 + m32 * 4];
      float4 gp = *(const float4*)&PE2[(size_t)p  * 128 + m32 * 4];
      float g0 = gt.x + gc.x + gp.x;
      float g1 = gt.y + gc.y + gp.y;
      float g2v = gt.z + gc.z + gp.z;
      float g3 = gt.w + gc.w + gp.w;
      cs[0] += fmaxf(acc[0][r] + g0, 0.f) * mk;
      cs[1] += fmaxf(acc[1][r] + g1, 0.f) * mk;
      cs[2] += fmaxf(acc[2][r] + g2v, 0.f) * mk;
      cs[3] += fmaxf(acc[3][r] + g3, 0.f) * mk;
    }
  }
  #pragma unroll
  for (int nt = 0; nt < 4; ++nt) cs[nt] += __shfl_xor(cs[nt], 32);
  if (half == 0) {
    int s_ = bs % S_;
    #pragma unroll
    for (int nt = 0; nt < 4; ++nt) {
      int col = nt * 32 + m32;
      float v = cs[nt] * (1.f / (float)W_) + PEtab[s_ * D_ + col];
      x[(size_t)bs * D_ + col] = v;
      xb[(size_t)bs * D_ + col] = __float2bfloat16(v);
    }
  }

  // ---- activity-fuse tail (cols 128..191): wave-local, barrier-free ----
  {
    float* wsc = &rectS[w][0][0];   // 160 floats available, need 96
    if (lane < 32) {
      float mx = mouse_pos[bs * 2 + 0] * (1.f / 1920.f);
      float my = mouse_pos[bs * 2 + 1] * (1.f / 1080.f);
      wsc[64 + lane] = fmaxf(mw1[lane * 2] * mx + mw1[lane * 2 + 1] * my + mb1[lane], 0.f);
    }
    __builtin_amdgcn_wave_barrier();
    float cv;
    if (lane < 32) {
      float a = mb2[lane];
      const float4* wv = (const float4*)(mw2 + lane * 32);
      const float4* hv = (const float4*)(wsc + 64);
      #pragma unroll
      for (int k4 = 0; k4 < 8; ++k4) {
        float4 ww = wv[k4], hh = hv[k4];
        a += ww.x*hh.x + ww.y*hh.y + ww.z*hh.z + ww.w*hh.w;
      }
      cv = a;
    } else if (lane < 48) {
      cv = act_emb[activity_type[bs] * 16 + (lane - 32)];
    } else {
      cv = kbw[lane - 48] * keyboard_active[bs] + kbb[lane - 48];
    }
    wsc[lane] = cv;
    __builtin_amdgcn_wave_barrier();
    {
      float a = afb[lane];
      const float4* w4 = (const float4*)(afw + lane * 64);
      const float4* cp = (const float4*)wsc;
      #pragma unroll
      for (int k4 = 0; k4 < 16; ++k4) {
        float4 ww = w4[k4], c2 = cp[k4];
        a += ww.x*c2.x + ww.y*c2.y + ww.z*c2.z + ww.w*c2.w;
      }
      float v = fmaxf(a, 0.f);
      int cg = 128 + lane;
      float ovv = v + PEtab[(bs % S_) * D_ + cg];
      x[(size_t)bs * D_ + cg] = ovv;
      xb[(size_t)bs * D_ + cg] = __float2bfloat16(ovv);
    }
  }
}

// ---------------------------------------------------------------------------
// Fused qkv + attention (R28-validated BK=64; unchanged).
// ---------------------------------------------------------------------------
__global__ __launch_bounds__(256)
void qkvattn_kernel(const __hip_bfloat16* __restrict__ xb,
                    const __hip_bfloat16* __restrict__ Wq,
                    const float* __restrict__ qb,
                    __hip_bfloat16* __restrict__ o)
{
  __shared__ __align__(16) char smem[40960];
  __hip_bfloat16* Asl = (__hip_bfloat16*)smem;             // 128*72
  __hip_bfloat16* Bsl = (__hip_bfloat16*)(smem + 18432);   // 96*72
  __hip_bfloat16* Qs  = (__hip_bfloat16*)smem;             // 128*40 (post-K)
  __hip_bfloat16* Ks  = (__hip_bfloat16*)(smem + 10240);   // 128*40 (post-K)
  __hip_bfloat16* Ps  = (__hip_bfloat16*)smem;             // 128*132 (post-QK^T)
  __hip_bfloat16* Vt  = (__hip_bfloat16*)(smem + 33792);   // 32*112

  int bh = blockIdx.x;
  int hh = bh & 7, b = bh >> 3;
  int tid = threadIdx.x, lane = tid & 63, w = tid >> 6;
  int m32 = lane & 31, half = lane >> 5;

  for (int e = tid; e < (32 * 112) / 8; e += 256)
    ((float4*)Vt)[e] = make_float4(0.f, 0.f, 0.f, 0.f);

  int rA0 = tid >> 2,          hA0 = tid & 3;
  int rA1 = (tid + 256) >> 2,  hA1 = tid & 3;
  int rrA0 = rA0 < S_ ? rA0 : S_ - 1;
  int rrA1 = rA1 < S_ ? rA1 : S_ - 1;
  size_t baseA0 = (size_t)(b * S_ + rrA0) * D_;
  size_t baseA1 = (size_t)(b * S_ + rrA1) * D_;
  float4* dA0 = (float4*)&Asl[rA0 * 72 + hA0 * 16];
  float4* dA1 = (float4*)&Asl[rA1 * 72 + hA1 * 16];

  int rB0 = tid >> 2, hB0 = tid & 3;
  int tB0 = rB0 >> 5, jB0 = rB0 & 31;
  bool actB0 = (jB0 < DH_);
  bool isB1 = (tid < 128);
  int rB1 = (tid + 256) >> 2, hB1 = tid & 3;
  int tB1 = rB1 >> 5, jB1 = rB1 & 31;
  bool actB1 = isB1 && (jB1 < DH_);
  size_t baseB0 = actB0 ? (size_t)(tB0 * D_ + hh * DH_ + jB0) * D_ : 0;
  size_t baseB1 = actB1 ? (size_t)(tB1 * D_ + hh * DH_ + jB1) * D_ : 0;
  float4* dB0 = (float4*)&Bsl[rB0 * 72 + hB0 * 16];
  float4* dB1 = (float4*)&Bsl[rB1 * 72 + hB1 * 16];

  {
    float4 z = make_float4(0.f, 0.f, 0.f, 0.f);
    if (!actB0) { dB0[0] = z; dB0[1] = z; }
    if (isB1 && !actB1) { dB1[0] = z; dB1[1] = z; }
  }
  {
    const float4* s0 = (const float4*)&xb[baseA0 + hA0 * 16];
    float4 a00 = s0[0], a01 = s0[1];
    const float4* s1 = (const float4*)&xb[baseA1 + hA1 * 16];
    float4 a10 = s1[0], a11 = s1[1];
    if (actB0) {
      const float4* p = (const float4*)&Wq[baseB0 + hB0 * 16];
      dB0[0] = p[0]; dB0[1] = p[1];
    }
    if (actB1) {
      const float4* p = (const float4*)&Wq[baseB1 + hB1 * 16];
      dB1[0] = p[0]; dB1[1] = p[1];
    }
    dA0[0] = a00; dA0[1] = a01;
    dA1[0] = a10; dA1[1] = a11;
  }

  floatx16 acc[3];
  #pragma unroll
  for (int t = 0; t < 3; ++t)
    #pragma unroll
    for (int r = 0; r < 16; ++r) acc[t][r] = 0.f;

  for (int k0 = 0; k0 < D_; k0 += 64) {
    bool more = (k0 + 64 < D_);
    __syncthreads();                  // stage for k0 visible
    float4 a00, a01, a10, a11, b00, b01, b10, b11;
    if (more) {
      const float4* s0 = (const float4*)&xb[baseA0 + k0 + 64 + hA0 * 16];
      a00 = s0[0]; a01 = s0[1];
      const float4* s1 = (const float4*)&xb[baseA1 + k0 + 64 + hA1 * 16];
      a10 = s1[0]; a11 = s1[1];
      if (actB0) {
        const float4* p = (const float4*)&Wq[baseB0 + k0 + 64 + hB0 * 16];
        b00 = p[0]; b01 = p[1];
      }
      if (actB1) {
        const float4* p = (const float4*)&Wq[baseB1 + k0 + 64 + hB1 * 16];
        b10 = p[0]; b11 = p[1];
      }
    }
    #pragma unroll
    for (int kc = 0; kc < 4; ++kc) {
      int ko = kc * 16 + half * 8;
      short8 a = *(const short8*)&Asl[(w * 32 + m32) * 72 + ko];
      #pragma unroll
      for (int t = 0; t < 3; ++t) {
        short8 bf = *(const short8*)&Bsl[(t * 32 + m32) * 72 + ko];
        acc[t] = __builtin_amdgcn_mfma_f32_32x32x16_bf16(a, bf, acc[t], 0, 0, 0);
      }
    }
    __syncthreads();                  // all waves done reading k0 tile
    if (more) {
      dA0[0] = a00; dA0[1] = a01;
      dA1[0] = a10; dA1[1] = a11;
      if (actB0) { dB0[0] = b00; dB0[1] = b01; }
      if (actB1) { dB1[0] = b10; dB1[1] = b11; }
    }
  }
  // after final barrier: Asl/Bsl dead, safe to alias with Qs/Ks.
  {
    bool dv = (m32 < DH_);
    float bq = dv ? qb[0 * D_ + hh * DH_ + m32] : 0.f;
    float bk = dv ? qb[1 * D_ + hh * DH_ + m32] : 0.f;
    float bv = dv ? qb[2 * D_ + hh * DH_ + m32] : 0.f;
    #pragma unroll
    for (int r = 0; r < 16; ++r) {
      int row = w * 32 + (r & 3) + 8 * (r >> 2) + 4 * half;
      Qs[row * 40 + m32] = __float2bfloat16(dv ? acc[0][r] + bq : 0.f);
      Ks[row * 40 + m32] = __float2bfloat16(dv ? acc[1][r] + bk : 0.f);
      if (dv && row < S_) Vt[m32 * 112 + row] = __float2bfloat16(acc[2][r] + bv);
    }
  }
  __syncthreads();

  floatx16 sc[4];
  #pragma unroll
  for (int nt = 0; nt < 4; ++nt)
    #pragma unroll
    for (int r = 0; r < 16; ++r) sc[nt][r] = 0.f;
  #pragma unroll
  for (int kc = 0; kc < 2; ++kc) {
    int ko = kc * 16 + half * 8;
    short8 a = *(const short8*)&Qs[(w * 32 + m32) * 40 + ko];
    #pragma unroll
    for (int nt = 0; nt < 4; ++nt) {
      short8 bf = *(const short8*)&Ks[(nt * 32 + m32) * 40 + ko];
      sc[nt] = __builtin_amdgcn_mfma_f32_32x32x16_bf16(a, bf, sc[nt], 0, 0, 0);
    }
  }
  __syncthreads();   // all waves done reading Qs/Ks before Ps overwrites them

  const float scale = 0.20412414523193154f;  // 1/sqrt(24)
  float rinv[16];
  #pragma unroll
  for (int r = 0; r < 16; ++r) {
    float mx = -1e30f;
    #pragma unroll
    for (int nt = 0; nt < 4; ++nt) {
      float s = sc[nt][r] * scale;
      if (nt == 3 && m32 >= 4) s = -1e30f;   // keys >= 100
      sc[nt][r] = s;
      mx = fmaxf(mx, s);
    }
    #pragma unroll
    for (int off = 1; off < 32; off <<= 1) mx = fmaxf(mx, __shfl_xor(mx, off));
    float sum = 0.f;
    #pragma unroll
    for (int nt = 0; nt < 4; ++nt) {
      float e = expf(sc[nt][r] - mx);
      sc[nt][r] = e;
      sum += e;
    }
    #pragma unroll
    for (int off = 1; off < 32; off <<= 1) sum += __shfl_xor(sum, off);
    rinv[r] = 1.f / sum;
  }
  #pragma unroll
  for (int r = 0; r < 16; ++r) {
    int rowl = (r & 3) + 8 * (r >> 2) + 4 * half;
    #pragma unroll
    for (int nt = 0; nt < 4; ++nt)
      Ps[(w * 32 + rowl) * 132 + nt * 32 + m32] = __float2bfloat16(sc[nt][r]);
  }
  // Ps is wave-private — no barrier.

  floatx16 ov;
  #pragma unroll
  for (int r = 0; r < 16; ++r) ov[r] = 0.f;
  #pragma unroll
  for (int kt = 0; kt < 7; ++kt) {       // 112 keys (100..111: P=0, Vt=0)
    int ko = kt * 16 + half * 8;
    short8 a = ld_frag8(&Ps[(w * 32 + m32) * 132 + ko]);
    short8 bf = *(const short8*)&Vt[m32 * 112 + ko];
    ov = __builtin_amdgcn_mfma_f32_32x32x16_bf16(a, bf, ov, 0, 0, 0);
  }
  #pragma unroll
  for (int r = 0; r < 16; ++r) {
    int rowl = (r & 3) + 8 * (r >> 2) + 4 * half;
    int q = w * 32 + rowl;
    if (m32 < DH_ && q < S_)
      o[((size_t)(b * S_ + q)) * D_ + hh * DH_ + m32] =
          __float2bfloat16(ov[r] * rinv[r]);
  }
}

// ---------------------------------------------------------------------------
// Fused out-proj+LN1 + ff1+ff2+LN2 (R27-validated BK=64; unchanged).
// ---------------------------------------------------------------------------
__global__ __launch_bounds__(256)
void outffln_kernel(const __hip_bfloat16* __restrict__ attb,
                    const __hip_bfloat16* __restrict__ Wo, const float* __restrict__ bo,
                    const float* __restrict__ g1, const float* __restrict__ b1v,
                    const __hip_bfloat16* __restrict__ W1, const float* __restrict__ b1,
                    const __hip_bfloat16* __restrict__ W2, const float* __restrict__ b2,
                    const float* __restrict__ g2, const float* __restrict__ b2v,
                    float* __restrict__ x, __hip_bfloat16* __restrict__ xb)
{
  __shared__ __align__(16) char arena[61952];
  __hip_bfloat16* AslA  = (__hip_bfloat16*)arena;             // 64*72
  __hip_bfloat16* BslA  = (__hip_bfloat16*)(arena + 9216);    // 192*72
  __hip_bfloat16* Afull = (__hip_bfloat16*)arena;             // 64*196 (post-LN1)
  __hip_bfloat16* BslB1 = (__hip_bfloat16*)(arena + 25088);   // 256*72 (W1)
  __hip_bfloat16* C1    = (__hip_bfloat16*)arena;             // 64*260 (post-ff1)
  __hip_bfloat16* BslB2 = (__hip_bfloat16*)(arena + 33280);   // 192*72 (W2)
  float (*psum)[2] = (float(*)[2])(arena + 60928);
  float (*psq)[2]  = (float(*)[2])(arena + 61440);

  int tid = threadIdx.x, lane = tid & 63, w = tid >> 6;
  int m32 = lane & 31, half = lane >> 5;
  int mt = w & 1, ng = w >> 1;
  int bm = blockIdx.x * 64;

  // ========= phase A: out-proj + residual + LN1 (K=192, 3 rounds of 64) ====
  floatx16 accA[3];
  #pragma unroll
  for (int j = 0; j < 3; ++j)
    #pragma unroll
    for (int r = 0; r < 16; ++r) accA[j][r] = 0.f;

  {
    int ra = tid >> 2, ha = tid & 3;
    float4* dA = (float4*)&AslA[ra * 72 + ha * 16];
    int rb0 = tid >> 2,           hb0 = tid & 3;
    int rb1 = (tid + 256) >> 2,   hb1 = tid & 3;
    int rb2 = (tid + 512) >> 2,   hb2 = tid & 3;
    float4* dB0 = (float4*)&BslA[rb0 * 72 + hb0 * 16];
    float4* dB1 = (float4*)&BslA[rb1 * 72 + hb1 * 16];
    float4* dB2 = (float4*)&BslA[rb2 * 72 + hb2 * 16];

    {
      const float4* s = (const float4*)(attb + (size_t)(bm + ra) * D_ + ha * 16);
      dA[0] = s[0]; dA[1] = s[1];
      const float4* p0 = (const float4*)(Wo + (size_t)rb0 * D_ + hb0 * 16);
      dB0[0] = p0[0]; dB0[1] = p0[1];
      const float4* p1 = (const float4*)(Wo + (size_t)rb1 * D_ + hb1 * 16);
      dB1[0] = p1[0]; dB1[1] = p1[1];
      const float4* p2 = (const float4*)(Wo + (size_t)rb2 * D_ + hb2 * 16);
      dB2[0] = p2[0]; dB2[1] = p2[1];
    }
    for (int k0 = 0; k0 < D_; k0 += 64) {
      bool more = (k0 + 64 < D_);
      __syncthreads();
      float4 na0, na1, n00, n01, n10, n11, n20, n21;
      if (more) {
        const float4* s = (const float4*)(attb + (size_t)(bm + ra) * D_ + k0 + 64 + ha * 16);
        na0 = s[0]; na1 = s[1];
        const float4* p0 = (const float4*)(Wo + (size_t)rb0 * D_ + k0 + 64 + hb0 * 16);
        n00 = p0[0]; n01 = p0[1];
        const float4* p1 = (const float4*)(Wo + (size_t)rb1 * D_ + k0 + 64 + hb1 * 16);
        n10 = p1[0]; n11 = p1[1];
        const float4* p2 = (const float4*)(Wo + (size_t)rb2 * D_ + k0 + 64 + hb2 * 16);
        n20 = p2[0]; n21 = p2[1];
      }
      #pragma unroll
      for (int kc = 0; kc < 4; ++kc) {
        int ko = kc * 16 + half * 8;
        short8 a = *(const short8*)&AslA[(mt * 32 + m32) * 72 + ko];
        #pragma unroll
        for (int j = 0; j < 3; ++j) {
          short8 bf = *(const short8*)&BslA[((ng * 3 + j) * 32 + m32) * 72 + ko];
          accA[j] = __builtin_amdgcn_mfma_f32_32x32x16_bf16(a, bf, accA[j], 0, 0, 0);
        }
      }
      __syncthreads();
      if (more) {
        dA[0] = na0; dA[1] = na1;
        dB0[0] = n00; dB0[1] = n01;
        dB1[0] = n10; dB1[1] = n11;
        dB2[0] = n20; dB2[1] = n21;
      }
    }
  }
  {
    int rowb = mt * 32 + 4 * half;
    #pragma unroll
    for (int r = 0; r < 16; ++r) {
      int rl = rowb + (r & 3) + 8 * (r >> 2);
      int row = bm + rl;
      float p = 0.f;
      #pragma unroll
      for (int j = 0; j < 3; ++j) {
        int col = (ng * 3 + j) * 32 + m32;
        float t = accA[j][r] + bo[col] + x[(size_t)row * D_ + col];
        accA[j][r] = t;
        p += t;
      }
      #pragma unroll
      for (int off = 1; off < 32; off <<= 1) p += __shfl_xor(p, off);
      if (m32 == 0) psum[rl][ng] = p;
    }
    __syncthreads();
    float mean[16];
    #pragma unroll
    for (int r = 0; r < 16; ++r) {
      int rl = rowb + (r & 3) + 8 * (r >> 2);
      mean[r] = (psum[rl][0] + psum[rl][1]) * (1.f / (float)D_);
    }
    #pragma unroll
    for (int r = 0; r < 16; ++r) {
      int rl = rowb + (r & 3) + 8 * (r >> 2);
      float s = 0.f;
      #pragma unroll
      for (int j = 0; j < 3; ++j) { float dd = accA[j][r] - mean[r]; s += dd * dd; }
      #pragma unroll
      for (int off = 1; off < 32; off <<= 1) s += __shfl_xor(s, off);
      if (m32 == 0) psq[rl][ng] = s;
    }
    __syncthreads();   // also: last use of AslA/BslA before Afull writes
    #pragma unroll
    for (int r = 0; r < 16; ++r) {
      int rl = rowb + (r & 3) + 8 * (r >> 2);
      int row = bm + rl;
      float inv = rsqrtf((psq[rl][0] + psq[rl][1]) * (1.f / (float)D_) + 1e-5f);
      #pragma unroll
      for (int j = 0; j < 3; ++j) {
        int col = (ng * 3 + j) * 32 + m32;
        float ovv = (accA[j][r] - mean[r]) * inv * g1[col] + b1v[col];
        x[(size_t)row * D_ + col] = ovv;
        __hip_bfloat16 hb = __float2bfloat16(ovv);
        xb[(size_t)row * D_ + col] = hb;
        Afull[rl * 196 + col] = hb;
      }
    }
  }
  __syncthreads();   // Afull complete before ff1 reads

  // ========= ff1 (A from Afull; W1 256x4 = 1024 items, 4/thread) =========
  floatx16 acc1[4];
  #pragma unroll
  for (int j = 0; j < 4; ++j)
    #pragma unroll
    for (int r = 0; r < 16; ++r) acc1[j][r] = 0.f;

  {
    int rb0 = tid >> 2,          hb0 = tid & 3;
    int rb1 = (tid + 256) >> 2,  hb1 = tid & 3;
    int rb2 = (tid + 512) >> 2,  hb2 = tid & 3;
    int rb3 = (tid + 768) >> 2,  hb3 = tid & 3;
    float4* dB0 = (float4*)&BslB1[rb0 * 72 + hb0 * 16];
    float4* dB1 = (float4*)&BslB1[rb1 * 72 + hb1 * 16];
    float4* dB2 = (float4*)&BslB1[rb2 * 72 + hb2 * 16];
    float4* dB3 = (float4*)&BslB1[rb3 * 72 + hb3 * 16];
    {
      const float4* p0 = (const float4*)(W1 + (size_t)rb0 * D_ + hb0 * 16);
      dB0[0] = p0[0]; dB0[1] = p0[1];
      const float4* p1 = (const float4*)(W1 + (size_t)rb1 * D_ + hb1 * 16);
      dB1[0] = p1[0]; dB1[1] = p1[1];
      const float4* p2 = (const float4*)(W1 + (size_t)rb2 * D_ + hb2 * 16);
      dB2[0] = p2[0]; dB2[1] = p2[1];
      const float4* p3 = (const float4*)(W1 + (size_t)rb3 * D_ + hb3 * 16);
      dB3[0] = p3[0]; dB3[1] = p3[1];
    }
    for (int k0 = 0; k0 < D_; k0 += 64) {
      bool more = (k0 + 64 < D_);
      __syncthreads();
      float4 n00, n01, n10, n11, n20, n21, n30, n31;
      if (more) {
        const float4* p0 = (const float4*)(W1 + (size_t)rb0 * D_ + k0 + 64 + hb0 * 16);
        n00 = p0[0]; n01 = p0[1];
        const float4* p1 = (const float4*)(W1 + (size_t)rb1 * D_ + k0 + 64 + hb1 * 16);
        n10 = p1[0]; n11 = p1[1];
        const float4* p2 = (const float4*)(W1 + (size_t)rb2 * D_ + k0 + 64 + hb2 * 16);
        n20 = p2[0]; n21 = p2[1];
        const float4* p3 = (const float4*)(W1 + (size_t)rb3 * D_ + k0 + 64 + hb3 * 16);
        n30 = p3[0]; n31 = p3[1];
      }
      #pragma unroll
      for (int kc = 0; kc < 4; ++kc) {
        int ko = kc * 16 + half * 8;
        short8 a = ld_frag8(&Afull[(mt * 32 + m32) * 196 + k0 + ko]);
        #pragma unroll
        for (int j = 0; j < 4; ++j) {
          short8 bf = *(const short8*)&BslB1[((ng * 4 + j) * 32 + m32) * 72 + ko];
          acc1[j] = __builtin_amdgcn_mfma_f32_32x32x16_bf16(a, bf, acc1[j], 0, 0, 0);
        }
      }
      __syncthreads();
      if (more) {
        dB0[0] = n00; dB0[1] = n01;
        dB1[0] = n10; dB1[1] = n11;
        dB2[0] = n20; dB2[1] = n21;
        dB3[0] = n30; dB3[1] = n31;
      }
    }
  }
  // ff1 epilogue: relu -> C1 (aliases dead Afull + BslB1 head).
  {
    int rowb = mt * 32 + 4 * half;
    #pragma unroll
    for (int j = 0; j < 4; ++j) {
      int col = (ng * 4 + j) * 32 + m32;
      float cb = b1[col];
      #pragma unroll
      for (int r = 0; r < 16; ++r) {
        int row = rowb + (r & 3) + 8 * (r >> 2);
        C1[row * 260 + col] = __float2bfloat16(fmaxf(acc1[j][r] + cb, 0.f));
      }
    }
  }

  // ========= ff2 (A from C1; W2 192x4 = 768 items, 3/thread; K=256) =======
  floatx16 acc2[3];
  #pragma unroll
  for (int j = 0; j < 3; ++j)
    #pragma unroll
    for (int r = 0; r < 16; ++r) acc2[j][r] = 0.f;

  {
    int rb0 = tid >> 2,          hb0 = tid & 3;
    int rb1 = (tid + 256) >> 2,  hb1 = tid & 3;
    int rb2 = (tid + 512) >> 2,  hb2 = tid & 3;
    float4* dB0 = (float4*)&BslB2[rb0 * 72 + hb0 * 16];
    float4* dB1 = (float4*)&BslB2[rb1 * 72 + hb1 * 16];
    float4* dB2 = (float4*)&BslB2[rb2 * 72 + hb2 * 16];
    {
      const float4* p0 = (const float4*)(W2 + (size_t)rb0 * DFF_ + hb0 * 16);
      dB0[0] = p0[0]; dB0[1] = p0[1];
      const float4* p1 = (const float4*)(W2 + (size_t)rb1 * DFF_ + hb1 * 16);
      dB1[0] = p1[0]; dB1[1] = p1[1];
      const float4* p2 = (const float4*)(W2 + (size_t)rb2 * DFF_ + hb2 * 16);
      dB2[0] = p2[0]; dB2[1] = p2[1];
    }
    for (int k0 = 0; k0 < DFF_; k0 += 64) {
      bool more = (k0 + 64 < DFF_);
      __syncthreads();                    // C1 + BslB2 tile visible
      float4 n00, n01, n10, n11, n20, n21;
      if (more) {
        const float4* p0 = (const float4*)(W2 + (size_t)rb0 * DFF_ + k0 + 64 + hb0 * 16);
        n00 = p0[0]; n01 = p0[1];
        const float4* p1 = (const float4*)(W2 + (size_t)rb1 * DFF_ + k0 + 64 + hb1 * 16);
        n10 = p1[0]; n11 = p1[1];
        const float4* p2 = (const float4*)(W2 + (size_t)rb2 * DFF_ + k0 + 64 + hb2 * 16);
        n20 = p2[0]; n21 = p2[1];
      }
      #pragma unroll
      for (int kc = 0; kc < 4; ++kc) {
        int ko = kc * 16 + half * 8;
        short8 a = ld_frag8(&C1[(mt * 32 + m32) * 260 + k0 + ko]);
        #pragma unroll
        for (int j = 0; j < 3; ++j) {
          short8 bf = *(const short8*)&BslB2[((ng * 3 + j) * 32 + m32) * 72 + ko];
          acc2[j] = __builtin_amdgcn_mfma_f32_32x32x16_bf16(a, bf, acc2[j], 0, 0, 0);
        }
      }
      __syncthreads();
      if (more) {
        dB0[0] = n00; dB0[1] = n01;
        dB1[0] = n10; dB1[1] = n11;
        dB2[0] = n20; dB2[1] = n21;
      }
    }
  }

  int rowb = mt * 32 + 4 * half;
  #pragma unroll
  for (int r = 0; r < 16; ++r) {
    int rl = rowb + (r & 3) + 8 * (r >> 2);
    int row = bm + rl;
    float p = 0.f;
    #pragma unroll
    for (int j = 0; j < 3; ++j) {
      int col = (ng * 3 + j) * 32 + m32;
      float t = acc2[j][r] + b2[col] + x[(size_t)row * D_ + col];
      acc2[j][r] = t;
      p += t;
    }
    #pragma unroll
    for (int off = 1; off < 32; off <<= 1) p += __shfl_xor(p, off);
    if (m32 == 0) psum[rl][ng] = p;
  }
  __syncthreads();
  float mean[16];
  #pragma unroll
  for (int r = 0; r < 16; ++r) {
    int rl = rowb + (r & 3) + 8 * (r >> 2);
    mean[r] = (psum[rl][0] + psum[rl][1]) * (1.f / (float)D_);
  }
  #pragma unroll
  for (int r = 0; r < 16; ++r) {
    int rl = rowb + (r & 3) + 8 * (r >> 2);
    float s = 0.f;
    #pragma unroll
    for (int j = 0; j < 3; ++j) { float dd = acc2[j][r] - mean[r]; s += dd * dd; }
    #pragma unroll
    for (int off = 1; off < 32; off <<= 1) s += __shfl_xor(s, off);
    if (m32 == 0) psq[rl][ng] = s;
  }
  __syncthreads();
  #pragma unroll
  for (int r = 0; r < 16; ++r) {
    int rl = rowb + (r & 3) + 8 * (r >> 2);
    int row = bm + rl;
    float inv = rsqrtf((psq[rl][0] + psq[rl][1]) * (1.f / (float)D_) + 1e-5f);
    #pragma unroll
    for (int j = 0; j < 3; ++j) {
      int col = (ng * 3 + j) * 32 + m32;
      float ovv = (acc2[j][r] - mean[r]) * inv * g2[col] + b2v[col];
      x[(size_t)row * D_ + col] = ovv;
      xb[(size_t)row * D_ + col] = __float2bfloat16(ovv);
    }
  }
}

// ---------------------------------------------------------------------------
// Head v3 (R26-validated): grid 640 = b x 5 window-groups of 4.
// ---------------------------------------------------------------------------
__global__ __launch_bounds__(256)
void head3_kernel(const float* __restrict__ x, const float* __restrict__ noise,
                  const float* __restrict__ pw1, const float* __restrict__ pb1,
                  const float* __restrict__ pw2, const float* __restrict__ pb2,
                  const float* __restrict__ ew1, const float* __restrict__ eb1,
                  const float* __restrict__ ew2, const float* __restrict__ eb2,
                  float* __restrict__ out)
{
  __shared__ float slotS[4][192];    // 3072
  __shared__ float phS[4][256];      // 4096
  __shared__ float ehS[4][128];      // 2048
  int blk = blockIdx.x;
  int b = blk / 5, g = blk - b * 5;  // windows g*4 .. g*4+3
  int tid = threadIdx.x;

  const float* lastrow = x + ((size_t)b * S_ + (S_ - 1)) * D_;
  for (int e = tid; e < 4 * 192; e += 256) {
    int wl = e / 192, c = e - wl * 192;
    int wg = g * 4 + wl;
    slotS[wl][c] = lastrow[c] + noise[((size_t)wg * B_ + b) * D_ + c] * 0.1f;
  }
  __syncthreads();

  bool doe = (tid < 128);
  float accp[4], acce[4];
  {
    float bp = pb1[tid];
    float be = doe ? eb1[tid] : 0.f;
    #pragma unroll
    for (int wl = 0; wl < 4; ++wl) { accp[wl] = bp; acce[wl] = be; }
  }
  {
    const float4* wr = (const float4*)(pw1 + (size_t)tid * D_);
    const float4* we = (const float4*)(ew1 + (size_t)(doe ? tid : 0) * D_);
    for (int k4 = 0; k4 < 48; ++k4) {
      float4 wv = wr[k4];
      float4 ev = we[k4];
      #pragma unroll
      for (int wl = 0; wl < 4; ++wl) {
        float4 sv = *(const float4*)&slotS[wl][k4 * 4];
        accp[wl] += wv.x*sv.x + wv.y*sv.y + wv.z*sv.z + wv.w*sv.w;
        if (doe) acce[wl] += ev.x*sv.x + ev.y*sv.y + ev.z*sv.z + ev.w*sv.w;
      }
    }
  }
  #pragma unroll
  for (int wl = 0; wl < 4; ++wl) {
    phS[wl][tid] = fmaxf(accp[wl], 0.f);
    if (doe) ehS[wl][tid] = fmaxf(acce[wl], 0.f);
  }
  __syncthreads();

  if (tid < 16) {
    int wl = tid >> 2, c = tid & 3;
    float a = pb2[c];
    const float4* wr = (const float4*)(pw2 + c * 256);
    const float4* pp = (const float4*)&phS[wl][0];
    for (int k = 0; k < 64; ++k) {
      float4 wv = wr[k], pv = pp[k];
      a += wv.x*pv.x + wv.y*pv.y + wv.z*pv.z + wv.w*pv.w;
    }
    out[((size_t)b * W_ + g * 4 + wl) * 4 + c] = a;
  } else if (tid >= 64 && tid < 68) {
    int wl = tid - 64;
    float a = eb2[0];
    const float4* wr = (const float4*)ew2;
    const float4* pp = (const float4*)&ehS[wl][0];
    for (int k = 0; k < 32; ++k) {
      float4 wv = wr[k], pv = pp[k];
      a += wv.x*pv.x + wv.y*pv.y + wv.z*pv.z + wv.w*pv.w;
    }
    out[(size_t)B_ * W_ * 4 + (size_t)b * W_ + g * 4 + wl] = 1.f / (1.f + expf(-a));
  }
}

// ---------------------------------------------------------------------------
extern "C" void kernel_launch(void* const* d_in, const int* in_sizes, int n_in,
                              void* d_out, int out_size, void* d_ws, size_t ws_size,
                              hipStream_t stream)
{
  const int*   title_idx       = (const int*)  d_in[0];
  const int*   class_idx       = (const int*)  d_in[1];
  const int*   process_idx     = (const int*)  d_in[2];
  const int*   activity_type   = (const int*)  d_in[3];
  const float* mouse_pos       = (const float*)d_in[4];
  const float* rect            = (const float*)d_in[5];
  const float* flags           = (const float*)d_in[6];
  const float* keyboard_active = (const float*)d_in[7];
  const float* window_mask     = (const float*)d_in[8];
  const float* noise           = (const float*)d_in[9];
  const float* title_emb       = (const float*)d_in[10];
  const float* class_emb       = (const float*)d_in[11];
  const float* process_emb     = (const float*)d_in[12];
  const float* spatial_w1      = (const float*)d_in[13];
  const float* spatial_b1      = (const float*)d_in[14];
  const float* spatial_w2      = (const float*)d_in[15];
  const float* spatial_b2      = (const float*)d_in[16];
  const float* wfuse_w         = (const float*)d_in[17];
  const float* wfuse_b         = (const float*)d_in[18];
  const float* mouse_w1        = (const float*)d_in[19];
  const float* mouse_b1        = (const float*)d_in[20];
  const float* mouse_w2        = (const float*)d_in[21];
  const float* mouse_b2        = (const float*)d_in[22];
  const float* act_emb         = (const float*)d_in[23];
  const float* kbd_w           = (const float*)d_in[24];
  const float* kbd_b           = (const float*)d_in[25];
  const float* afuse_w         = (const float*)d_in[26];
  const float* afuse_b         = (const float*)d_in[27];
  const float* qkv_w           = (const float*)d_in[28];
  const float* qkv_b           = (const float*)d_in[29];
  const float* out_w           = (const float*)d_in[30];
  const float* out_b           = (const float*)d_in[31];
  const float* ff1_w           = (const float*)d_in[32];
  const float* ff1_b           = (const float*)d_in[33];
  const float* ff2_w           = (const float*)d_in[34];
  const float* ff2_b           = (const float*)d_in[35];
  const float* ln1_g           = (const float*)d_in[36];
  const float* ln1_b           = (const float*)d_in[37];
  const float* ln2_g           = (const float*)d_in[38];
  const float* ln2_b           = (const float*)d_in[39];
  const float* proj_w1         = (const float*)d_in[40];
  const float* proj_b1         = (const float*)d_in[41];
  const float* proj_w2         = (const float*)d_in[42];
  const float* proj_b2         = (const float*)d_in[43];
  const float* ex_w1           = (const float*)d_in[44];
  const float* ex_b1           = (const float*)d_in[45];
  const float* ex_w2           = (const float*)d_in[46];
  const float* ex_b2           = (const float*)d_in[47];

  float* out = (float*)d_out;

  // workspace layout
  float* x = (float*)d_ws;                                      // BS*192 f32
  __hip_bfloat16* xb   = (__hip_bfloat16*)(x + (size_t)BS_ * D_);
  __hip_bfloat16* attb = xb   + (size_t)BS_ * D_;
  __hip_bfloat16* wqb  = attb + (size_t)BS_ * D_;
  __hip_bfloat16* wob  = wqb  + (size_t)L_ * THREED_ * D_;
  __hip_bfloat16* wf1b = wob  + (size_t)L_ * D_ * D_;
  __hip_bfloat16* wf2b = wf1b + (size_t)L_ * DFF_ * D_;
  float* TE2  = (float*)(wf2b + (size_t)L_ * D_ * DFF_);        // 1000*128 (permuted cols)
  float* CE2  = TE2  + 1000 * 128;                              // 500*128
  float* PE2  = CE2  + 500 * 128;                               // 1000*128
  __hip_bfloat16* WSPb = (__hip_bfloat16*)(PE2 + 1000 * 128);   // 128*64 bf16
  float* PEtab = (float*)(WSPb + 128 * 64);                     // 100*192 f32
  (void)ws_size; (void)n_in; (void)in_sizes; (void)out_size;

  convertprep_kernel<<<2077, 256, 0, stream>>>(
      qkv_w, wqb, out_w, wob, ff1_w, wf1b, ff2_w, wf2b,
      title_emb, class_emb, process_emb, wfuse_w, wfuse_b,
      spatial_w2, spatial_b2, TE2, CE2, PE2, WSPb, PEtab);

  encode8_kernel<<<BS_ / 8, 512, 0, stream>>>(
      title_idx, class_idx, process_idx, activity_type, mouse_pos, rect, flags,
      keyboard_active, window_mask, spatial_w1, spatial_b1,
      TE2, CE2, PE2, WSPb, PEtab,
      mouse_w1, mouse_b1, mouse_w2, mouse_b2, act_emb, kbd_w, kbd_b,
      afuse_w, afuse_b, x, xb);

  for (int l = 0; l < L_; ++l) {
    qkvattn_kernel<<<B_ * H_, 256, 0, stream>>>(
        xb, wqb + (size_t)l * THREED_ * D_, qkv_b + (size_t)l * THREED_, attb);
    outffln_kernel<<<BS_ / 64, 256, 0, stream>>>(
        attb, wob + (size_t)l * D_ * D_, out_b + (size_t)l * D_,
        ln1_g + (size_t)l * D_, ln1_b + (size_t)l * D_,
        wf1b + (size_t)l * DFF_ * D_, ff1_b + (size_t)l * DFF_,
        wf2b + (size_t)l * D_ * DFF_, ff2_b + (size_t)l * D_,
        ln2_g + (size_t)l * D_, ln2_b + (size_t)l * D_, x, xb);
  }

  head3_kernel<<<B_ * 5, 256, 0, stream>>>(
      x, noise, proj_w1, proj_b1, proj_w2, proj_b2,
      ex_w1, ex_b1, ex_w2, ex_b2, out);
}

// Round 17
// 637.547 us; speedup vs baseline: 1.0564x; 1.0293x over previous
//
#include <hip/hip_runtime.h>
#include <hip/hip_bf16.h>
#include <math.h>

#define B_ 128
#define S_ 100
#define W_ 20
#define D_ 192
#define L_ 6
#define H_ 8
#define DFF_ 256
#define DH_ 24
#define BS_ (B_*S_)
#define THREED_ 576

typedef short short8 __attribute__((ext_vector_type(8)));
typedef short short4v __attribute__((ext_vector_type(4)));
typedef float floatx16 __attribute__((ext_vector_type(16)));

__device__ __forceinline__ float posenc(int s, int c) {
  float freq = expf(-logf(10000.f) * (float)(2 * (c >> 1)) / (float)D_);
  float ang = (float)s * freq;
  return (c & 1) ? cosf(ang) : sinf(ang);
}

__device__ __forceinline__ short8 ld_frag8(const __hip_bfloat16* p) {
  short4v lo = *(const short4v*)p;
  short4v hi = *(const short4v*)(p + 4);
  short8 r;
  r[0]=lo[0]; r[1]=lo[1]; r[2]=lo[2]; r[3]=lo[3];
  r[4]=hi[0]; r[5]=hi[1]; r[6]=hi[2]; r[7]=hi[3];
  return r;
}

__device__ __forceinline__ short f2bf_s(float v) {
  __hip_bfloat16 t = __float2bfloat16(v);
  return *reinterpret_cast<short*>(&t);
}

__device__ __forceinline__ float dot4(float4 a, float4 b) {
  return a.x*b.x + a.y*b.y + a.z*b.z + a.w*b.w;
}

// ---------------------------------------------------------------------------
// Merged weight conversion + encoder precompute (R24-validated). 2077 blocks.
// ---------------------------------------------------------------------------
__global__ __launch_bounds__(256)
void convertprep_kernel(
    const float* __restrict__ s0, __hip_bfloat16* __restrict__ d0,
    const float* __restrict__ s1, __hip_bfloat16* __restrict__ d1,
    const float* __restrict__ s2, __hip_bfloat16* __restrict__ d2,
    const float* __restrict__ s3, __hip_bfloat16* __restrict__ d3,
    const float* __restrict__ te, const float* __restrict__ ce,
    const float* __restrict__ pe, const float* __restrict__ wfw,
    const float* __restrict__ wfb, const float* __restrict__ sw2,
    const float* __restrict__ sb2,
    float* __restrict__ TE2, float* __restrict__ CE2,
    float* __restrict__ PE2, __hip_bfloat16* __restrict__ WSPb,
    float* __restrict__ PEtab)
{
  int b = blockIdx.x, tid = threadIdx.x;
  if (b < 720) {
    const float* s; __hip_bfloat16* d; int base;
    if      (b < 324) { s = s0; d = d0; base = b; }
    else if (b < 432) { s = s1; d = d1; base = b - 324; }
    else if (b < 576) { s = s2; d = d2; base = b - 432; }
    else              { s = s3; d = d3; base = b - 576; }
    int i = (base * 256 + tid) * 8;
    float4 v0 = *(const float4*)(s + i);
    float4 v1 = *(const float4*)(s + i + 4);
    __hip_bfloat162* d2p = (__hip_bfloat162*)(d + i);
    d2p[0] = __float22bfloat162_rn(make_float2(v0.x, v0.y));
    d2p[1] = __float22bfloat162_rn(make_float2(v0.z, v0.w));
    d2p[2] = __float22bfloat162_rn(make_float2(v1.x, v1.y));
    d2p[3] = __float22bfloat162_rn(make_float2(v1.z, v1.w));
    return;
  }
  int blk = b - 720;
  if (blk < 1250) {
    int item = blk * 256 + tid;
    int v = item >> 7, o = item & 127;
    const float* src; float* dst; int base, vv;
    float a;
    if (v < 1000) {
      src = te; dst = TE2; base = 0; vv = v;
      a = wfb[o];                                 // fold wfuse bias
      const float4* w4 = (const float4*)(wfw + o * 128 + 96);
      const float4* b4 = (const float4*)sb2;
      #pragma unroll
      for (int k4 = 0; k4 < 8; ++k4) a += dot4(w4[k4], b4[k4]);
    } else if (v < 1500) {
      src = ce; dst = CE2; base = 32; vv = v - 1000; a = 0.f;
    } else {
      src = pe; dst = PE2; base = 64; vv = v - 1500; a = 0.f;
    }
    const float4* s4 = (const float4*)(src + vv * 32);
    const float4* w4 = (const float4*)(wfw + o * 128 + base);
    #pragma unroll
    for (int k4 = 0; k4 < 8; ++k4) a += dot4(s4[k4], w4[k4]);
    int op = ((o & 31) << 2) + (o >> 5);          // R23 permuted placement
    dst[vv * 128 + op] = a;
  } else if (blk < 1282) {
    int item = (blk - 1250) * 256 + tid;
    int j = item >> 7, o = item & 127;           // j = hidden k, o = out col
    float a = 0.f;
    #pragma unroll 8
    for (int k = 0; k < 32; ++k) a += wfw[o * 128 + 96 + k] * sw2[k * 64 + j];
    WSPb[o * 64 + j] = __float2bfloat16(a);      // B operand [col][k]
  } else {
    int idx = (blk - 1282) * 256 + tid;          // [0, 19200)
    int s_ = idx / D_, c = idx - s_ * D_;
    PEtab[idx] = posenc(s_, c);
  }
}

// ---------------------------------------------------------------------------
// Encoder v13 (R29-measured BEST ~100us; unchanged).
// 8 bs/block, 512 threads, grid 1600. LDS 26.1KB.
// ---------------------------------------------------------------------------
__global__ __launch_bounds__(512)
void encode8_kernel(
    const int* __restrict__ title_idx, const int* __restrict__ class_idx,
    const int* __restrict__ process_idx, const int* __restrict__ activity_type,
    const float* __restrict__ mouse_pos, const float* __restrict__ rect,
    const float* __restrict__ flags, const float* __restrict__ keyboard_active,
    const float* __restrict__ window_mask,
    const float* __restrict__ sw1, const float* __restrict__ sb1,
    const float* __restrict__ TE2, const float* __restrict__ CE2,
    const float* __restrict__ PE2, const __hip_bfloat16* __restrict__ WSPb,
    const float* __restrict__ PEtab,
    const float* __restrict__ mw1, const float* __restrict__ mb1,
    const float* __restrict__ mw2, const float* __restrict__ mb2,
    const float* __restrict__ act_emb, const float* __restrict__ kbw,
    const float* __restrict__ kbb,
    const float* __restrict__ afw, const float* __restrict__ afb,
    float* __restrict__ x, __hip_bfloat16* __restrict__ xb)
{
  __shared__ __hip_bfloat16 Bls[128][72];            // 18432
  __shared__ int   idxS[8][20][3];                   // 1920
  __shared__ float maskS[8][20];                     // 640
  __shared__ __align__(16) float rectS[8][20][8];    // 5120 (wave-private after stage)

  int tid = threadIdx.x;
  int w = tid >> 6, lane = tid & 63;
  int m32 = lane & 31, half = lane >> 5;
  int bs0 = blockIdx.x * 8;
  int bs = bs0 + w;

  if (tid < 480) {
    int g2 = tid / 60, rem = tid % 60, which = rem / 20, w_ = rem % 20;
    const int* src = (which == 0) ? title_idx : (which == 1) ? class_idx : process_idx;
    idxS[g2][w_][which] = src[(bs0 + g2) * W_ + w_];
  }
  if (tid < 160) {
    int g2 = tid / 20, w_ = tid % 20;
    maskS[g2][w_] = window_mask[(bs0 + g2) * W_ + w_];
  }
  for (int e = tid; e < 960; e += 512) {      // 8*20*6
    int g2 = e / 120, rem = e % 120, w_ = rem / 6, c = rem % 6;
    int rg = (bs0 + g2) * W_ + w_;
    rectS[g2][w_][c] = (c < 4) ? rect[rg * 4 + c] : flags[rg * 2 + (c - 4)];
  }
  for (int e = tid; e < 1024; e += 512) {     // 128 cols x 8 k-groups of 8
    int col = e >> 3, k8 = e & 7;
    short8 v = *(const short8*)&WSPb[col * 64 + k8 * 8];
    *(short8*)&Bls[col][k8 * 8] = v;
  }
  __syncthreads();

  short8 afr[4];
  {
    float rc[6];
    bool act = (m32 < W_);
    if (act) {
      #pragma unroll
      for (int c = 0; c < 6; ++c) rc[c] = rectS[w][m32][c];
    }
    #pragma unroll
    for (int s = 0; s < 4; ++s) {
      short8 f;
      #pragma unroll
      for (int jp = 0; jp < 8; ++jp) {
        float a = 0.f;
        if (act) {
          int j = s * 16 + half * 8 + jp;
          const float* w1 = sw1 + j * 6;
          a = sb1[j];
          #pragma unroll
          for (int c = 0; c < 6; ++c) a += w1[c] * rc[c];
          a = fmaxf(a, 0.f);
        }
        f[jp] = f2bf_s(a);
      }
      afr[s] = f;
    }
  }

  floatx16 acc[4];
  #pragma unroll
  for (int nt = 0; nt < 4; ++nt)
    #pragma unroll
    for (int r = 0; r < 16; ++r) acc[nt][r] = 0.f;

  #pragma unroll
  for (int s = 0; s < 4; ++s) {
    int ko = s * 16 + half * 8;
    #pragma unroll
    for (int nt = 0; nt < 4; ++nt) {
      short8 bf = *(const short8*)&Bls[nt * 32 + m32][ko];
      acc[nt] = __builtin_amdgcn_mfma_f32_32x32x16_bf16(afr[s], bf, acc[nt], 0, 0, 0);
    }
  }

  // ---- epilogue: one float4 per (row, table) from permuted tables ----
  float cs[4] = {0.f, 0.f, 0.f, 0.f};
  #pragma unroll
  for (int r = 0; r < 16; ++r) {
    int row = (r & 3) + 8 * (r >> 2) + 4 * half;
    if (row < W_) {
      int t  = idxS[w][row][0];
      int ci = idxS[w][row][1];
      int p  = idxS[w][row][2];
      float mk = maskS[w][row];
      float4 gt = *(const float4*)&TE2[(size_t)t  * 128 + m32 * 4];
      float4 gc = *(const float4*)&CE2[(size_t)ci * 128 + m32 * 4];
      float4 gp = *(const float4*)&PE2[(size_t)p  * 128 + m32 * 4];
      float g0 = gt.x + gc.x + gp.x;
      float g1 = gt.y + gc.y + gp.y;
      float g2v = gt.z + gc.z + gp.z;
      float g3 = gt.w + gc.w + gp.w;
      cs[0] += fmaxf(acc[0][r] + g0, 0.f) * mk;
      cs[1] += fmaxf(acc[1][r] + g1, 0.f) * mk;
      cs[2] += fmaxf(acc[2][r] + g2v, 0.f) * mk;
      cs[3] += fmaxf(acc[3][r] + g3, 0.f) * mk;
    }
  }
  #pragma unroll
  for (int nt = 0; nt < 4; ++nt) cs[nt] += __shfl_xor(cs[nt], 32);
  if (half == 0) {
    int s_ = bs % S_;
    #pragma unroll
    for (int nt = 0; nt < 4; ++nt) {
      int col = nt * 32 + m32;
      float v = cs[nt] * (1.f / (float)W_) + PEtab[s_ * D_ + col];
      x[(size_t)bs * D_ + col] = v;
      xb[(size_t)bs * D_ + col] = __float2bfloat16(v);
    }
  }

  // ---- activity-fuse tail (cols 128..191): wave-local, barrier-free ----
  {
    float* wsc = &rectS[w][0][0];   // 160 floats available, need 96
    if (lane < 32) {
      float mx = mouse_pos[bs * 2 + 0] * (1.f / 1920.f);
      float my = mouse_pos[bs * 2 + 1] * (1.f / 1080.f);
      wsc[64 + lane] = fmaxf(mw1[lane * 2] * mx + mw1[lane * 2 + 1] * my + mb1[lane], 0.f);
    }
    __builtin_amdgcn_wave_barrier();
    float cv;
    if (lane < 32) {
      float a = mb2[lane];
      const float4* wv = (const float4*)(mw2 + lane * 32);
      const float4* hv = (const float4*)(wsc + 64);
      #pragma unroll
      for (int k4 = 0; k4 < 8; ++k4) {
        float4 ww = wv[k4], hh = hv[k4];
        a += ww.x*hh.x + ww.y*hh.y + ww.z*hh.z + ww.w*hh.w;
      }
      cv = a;
    } else if (lane < 48) {
      cv = act_emb[activity_type[bs] * 16 + (lane - 32)];
    } else {
      cv = kbw[lane - 48] * keyboard_active[bs] + kbb[lane - 48];
    }
    wsc[lane] = cv;
    __builtin_amdgcn_wave_barrier();
    {
      float a = afb[lane];
      const float4* w4 = (const float4*)(afw + lane * 64);
      const float4* cp = (const float4*)wsc;
      #pragma unroll
      for (int k4 = 0; k4 < 16; ++k4) {
        float4 ww = w4[k4], c2 = cp[k4];
        a += ww.x*c2.x + ww.y*c2.y + ww.z*c2.z + ww.w*c2.w;
      }
      float v = fmaxf(a, 0.f);
      int cg = 128 + lane;
      float ovv = v + PEtab[(bs % S_) * D_ + cg];
      x[(size_t)bs * D_ + cg] = ovv;
      xb[(size_t)bs * D_ + cg] = __float2bfloat16(ovv);
    }
  }
}

// ---------------------------------------------------------------------------
// Fused qkv + attention (R28-validated BK=64; unchanged).
// ---------------------------------------------------------------------------
__global__ __launch_bounds__(256)
void qkvattn_kernel(const __hip_bfloat16* __restrict__ xb,
                    const __hip_bfloat16* __restrict__ Wq,
                    const float* __restrict__ qb,
                    __hip_bfloat16* __restrict__ o)
{
  __shared__ __align__(16) char smem[40960];
  __hip_bfloat16* Asl = (__hip_bfloat16*)smem;             // 128*72
  __hip_bfloat16* Bsl = (__hip_bfloat16*)(smem + 18432);   // 96*72
  __hip_bfloat16* Qs  = (__hip_bfloat16*)smem;             // 128*40 (post-K)
  __hip_bfloat16* Ks  = (__hip_bfloat16*)(smem + 10240);   // 128*40 (post-K)
  __hip_bfloat16* Ps  = (__hip_bfloat16*)smem;             // 128*132 (post-QK^T)
  __hip_bfloat16* Vt  = (__hip_bfloat16*)(smem + 33792);   // 32*112

  int bh = blockIdx.x;
  int hh = bh & 7, b = bh >> 3;
  int tid = threadIdx.x, lane = tid & 63, w = tid >> 6;
  int m32 = lane & 31, half = lane >> 5;

  for (int e = tid; e < (32 * 112) / 8; e += 256)
    ((float4*)Vt)[e] = make_float4(0.f, 0.f, 0.f, 0.f);

  int rA0 = tid >> 2,          hA0 = tid & 3;
  int rA1 = (tid + 256) >> 2,  hA1 = tid & 3;
  int rrA0 = rA0 < S_ ? rA0 : S_ - 1;
  int rrA1 = rA1 < S_ ? rA1 : S_ - 1;
  size_t baseA0 = (size_t)(b * S_ + rrA0) * D_;
  size_t baseA1 = (size_t)(b * S_ + rrA1) * D_;
  float4* dA0 = (float4*)&Asl[rA0 * 72 + hA0 * 16];
  float4* dA1 = (float4*)&Asl[rA1 * 72 + hA1 * 16];

  int rB0 = tid >> 2, hB0 = tid & 3;
  int tB0 = rB0 >> 5, jB0 = rB0 & 31;
  bool actB0 = (jB0 < DH_);
  bool isB1 = (tid < 128);
  int rB1 = (tid + 256) >> 2, hB1 = tid & 3;
  int tB1 = rB1 >> 5, jB1 = rB1 & 31;
  bool actB1 = isB1 && (jB1 < DH_);
  size_t baseB0 = actB0 ? (size_t)(tB0 * D_ + hh * DH_ + jB0) * D_ : 0;
  size_t baseB1 = actB1 ? (size_t)(tB1 * D_ + hh * DH_ + jB1) * D_ : 0;
  float4* dB0 = (float4*)&Bsl[rB0 * 72 + hB0 * 16];
  float4* dB1 = (float4*)&Bsl[rB1 * 72 + hB1 * 16];

  {
    float4 z = make_float4(0.f, 0.f, 0.f, 0.f);
    if (!actB0) { dB0[0] = z; dB0[1] = z; }
    if (isB1 && !actB1) { dB1[0] = z; dB1[1] = z; }
  }
  {
    const float4* s0 = (const float4*)&xb[baseA0 + hA0 * 16];
    float4 a00 = s0[0], a01 = s0[1];
    const float4* s1 = (const float4*)&xb[baseA1 + hA1 * 16];
    float4 a10 = s1[0], a11 = s1[1];
    if (actB0) {
      const float4* p = (const float4*)&Wq[baseB0 + hB0 * 16];
      dB0[0] = p[0]; dB0[1] = p[1];
    }
    if (actB1) {
      const float4* p = (const float4*)&Wq[baseB1 + hB1 * 16];
      dB1[0] = p[0]; dB1[1] = p[1];
    }
    dA0[0] = a00; dA0[1] = a01;
    dA1[0] = a10; dA1[1] = a11;
  }

  floatx16 acc[3];
  #pragma unroll
  for (int t = 0; t < 3; ++t)
    #pragma unroll
    for (int r = 0; r < 16; ++r) acc[t][r] = 0.f;

  for (int k0 = 0; k0 < D_; k0 += 64) {
    bool more = (k0 + 64 < D_);
    __syncthreads();                  // stage for k0 visible
    float4 a00, a01, a10, a11, b00, b01, b10, b11;
    if (more) {
      const float4* s0 = (const float4*)&xb[baseA0 + k0 + 64 + hA0 * 16];
      a00 = s0[0]; a01 = s0[1];
      const float4* s1 = (const float4*)&xb[baseA1 + k0 + 64 + hA1 * 16];
      a10 = s1[0]; a11 = s1[1];
      if (actB0) {
        const float4* p = (const float4*)&Wq[baseB0 + k0 + 64 + hB0 * 16];
        b00 = p[0]; b01 = p[1];
      }
      if (actB1) {
        const float4* p = (const float4*)&Wq[baseB1 + k0 + 64 + hB1 * 16];
        b10 = p[0]; b11 = p[1];
      }
    }
    #pragma unroll
    for (int kc = 0; kc < 4; ++kc) {
      int ko = kc * 16 + half * 8;
      short8 a = *(const short8*)&Asl[(w * 32 + m32) * 72 + ko];
      #pragma unroll
      for (int t = 0; t < 3; ++t) {
        short8 bf = *(const short8*)&Bsl[(t * 32 + m32) * 72 + ko];
        acc[t] = __builtin_amdgcn_mfma_f32_32x32x16_bf16(a, bf, acc[t], 0, 0, 0);
      }
    }
    __syncthreads();                  // all waves done reading k0 tile
    if (more) {
      dA0[0] = a00; dA0[1] = a01;
      dA1[0] = a10; dA1[1] = a11;
      if (actB0) { dB0[0] = b00; dB0[1] = b01; }
      if (actB1) { dB1[0] = b10; dB1[1] = b11; }
    }
  }
  // after final barrier: Asl/Bsl dead, safe to alias with Qs/Ks.
  {
    bool dv = (m32 < DH_);
    float bq = dv ? qb[0 * D_ + hh * DH_ + m32] : 0.f;
    float bk = dv ? qb[1 * D_ + hh * DH_ + m32] : 0.f;
    float bv = dv ? qb[2 * D_ + hh * DH_ + m32] : 0.f;
    #pragma unroll
    for (int r = 0; r < 16; ++r) {
      int row = w * 32 + (r & 3) + 8 * (r >> 2) + 4 * half;
      Qs[row * 40 + m32] = __float2bfloat16(dv ? acc[0][r] + bq : 0.f);
      Ks[row * 40 + m32] = __float2bfloat16(dv ? acc[1][r] + bk : 0.f);
      if (dv && row < S_) Vt[m32 * 112 + row] = __float2bfloat16(acc[2][r] + bv);
    }
  }
  __syncthreads();

  floatx16 sc[4];
  #pragma unroll
  for (int nt = 0; nt < 4; ++nt)
    #pragma unroll
    for (int r = 0; r < 16; ++r) sc[nt][r] = 0.f;
  #pragma unroll
  for (int kc = 0; kc < 2; ++kc) {
    int ko = kc * 16 + half * 8;
    short8 a = *(const short8*)&Qs[(w * 32 + m32) * 40 + ko];
    #pragma unroll
    for (int nt = 0; nt < 4; ++nt) {
      short8 bf = *(const short8*)&Ks[(nt * 32 + m32) * 40 + ko];
      sc[nt] = __builtin_amdgcn_mfma_f32_32x32x16_bf16(a, bf, sc[nt], 0, 0, 0);
    }
  }
  __syncthreads();   // all waves done reading Qs/Ks before Ps overwrites them

  const float scale = 0.20412414523193154f;  // 1/sqrt(24)
  float rinv[16];
  #pragma unroll
  for (int r = 0; r < 16; ++r) {
    float mx = -1e30f;
    #pragma unroll
    for (int nt = 0; nt < 4; ++nt) {
      float s = sc[nt][r] * scale;
      if (nt == 3 && m32 >= 4) s = -1e30f;   // keys >= 100
      sc[nt][r] = s;
      mx = fmaxf(mx, s);
    }
    #pragma unroll
    for (int off = 1; off < 32; off <<= 1) mx = fmaxf(mx, __shfl_xor(mx, off));
    float sum = 0.f;
    #pragma unroll
    for (int nt = 0; nt < 4; ++nt) {
      float e = expf(sc[nt][r] - mx);
      sc[nt][r] = e;
      sum += e;
    }
    #pragma unroll
    for (int off = 1; off < 32; off <<= 1) sum += __shfl_xor(sum, off);
    rinv[r] = 1.f / sum;
  }
  #pragma unroll
  for (int r = 0; r < 16; ++r) {
    int rowl = (r & 3) + 8 * (r >> 2) + 4 * half;
    #pragma unroll
    for (int nt = 0; nt < 4; ++nt)
      Ps[(w * 32 + rowl) * 132 + nt * 32 + m32] = __float2bfloat16(sc[nt][r]);
  }
  // Ps is wave-private — no barrier.

  floatx16 ov;
  #pragma unroll
  for (int r = 0; r < 16; ++r) ov[r] = 0.f;
  #pragma unroll
  for (int kt = 0; kt < 7; ++kt) {       // 112 keys (100..111: P=0, Vt=0)
    int ko = kt * 16 + half * 8;
    short8 a = ld_frag8(&Ps[(w * 32 + m32) * 132 + ko]);
    short8 bf = *(const short8*)&Vt[m32 * 112 + ko];
    ov = __builtin_amdgcn_mfma_f32_32x32x16_bf16(a, bf, ov, 0, 0, 0);
  }
  #pragma unroll
  for (int r = 0; r < 16; ++r) {
    int rowl = (r & 3) + 8 * (r >> 2) + 4 * half;
    int q = w * 32 + rowl;
    if (m32 < DH_ && q < S_)
      o[((size_t)(b * S_ + q)) * D_ + hh * DH_ + m32] =
          __float2bfloat16(ov[r] * rinv[r]);
  }
}

// ---------------------------------------------------------------------------
// Fused out-proj+LN1 + ff1+ff2+LN2. R32: (a) phase A BK=96 (3->2 rounds,
// pitch 104; k-ascending order preserved -> bit-identical); (b) residual x
// reads hoisted to kernel entry (overlap phase-A K-loop); (c) LN1 outputs
// kept in registers (h1v) for the ff2 residual -- each thread re-read
// exactly the values it wrote. Arena layout:
//   phase A: AslA[0,13312) 64x104, BslA[13312,53248) 192x104
//   Afull  [0,25088)      (post-LN1; AslA/BslA dead)
//   BslB1  [25088,61952)  (W1, 256x72)
//   C1     [0,33280)      (post-ff1)
//   BslB2  [33280,60928)  (W2, 192x72)
//   psum/psq [60928,61952) (lifetime-disjoint from BslB1 tail)
// ---------------------------------------------------------------------------
__global__ __launch_bounds__(256)
void outffln_kernel(const __hip_bfloat16* __restrict__ attb,
                    const __hip_bfloat16* __restrict__ Wo, const float* __restrict__ bo,
                    const float* __restrict__ g1, const float* __restrict__ b1v,
                    const __hip_bfloat16* __restrict__ W1, const float* __restrict__ b1,
                    const __hip_bfloat16* __restrict__ W2, const float* __restrict__ b2,
                    const float* __restrict__ g2, const float* __restrict__ b2v,
                    float* __restrict__ x, __hip_bfloat16* __restrict__ xb)
{
  __shared__ __align__(16) char arena[61952];
  __hip_bfloat16* AslA  = (__hip_bfloat16*)arena;             // 64*104
  __hip_bfloat16* BslA  = (__hip_bfloat16*)(arena + 13312);   // 192*104
  __hip_bfloat16* Afull = (__hip_bfloat16*)arena;             // 64*196 (post-LN1)
  __hip_bfloat16* BslB1 = (__hip_bfloat16*)(arena + 25088);   // 256*72 (W1)
  __hip_bfloat16* C1    = (__hip_bfloat16*)arena;             // 64*260 (post-ff1)
  __hip_bfloat16* BslB2 = (__hip_bfloat16*)(arena + 33280);   // 192*72 (W2)
  float (*psum)[2] = (float(*)[2])(arena + 60928);
  float (*psq)[2]  = (float(*)[2])(arena + 61440);

  int tid = threadIdx.x, lane = tid & 63, w = tid >> 6;
  int m32 = lane & 31, half = lane >> 5;
  int mt = w & 1, ng = w >> 1;
  int bm = blockIdx.x * 64;

  // ========= phase A: out-proj + residual + LN1 (K=192, 2 rounds of 96) ====
  floatx16 accA[3];
  #pragma unroll
  for (int j = 0; j < 3; ++j)
    #pragma unroll
    for (int r = 0; r < 16; ++r) accA[j][r] = 0.f;

  // R32(b): hoist residual x reads -- overlap the entire phase-A K-loop.
  float xres[3][16];
  {
    int rowb0 = mt * 32 + 4 * half;
    #pragma unroll
    for (int r = 0; r < 16; ++r) {
      int rl = rowb0 + (r & 3) + 8 * (r >> 2);
      #pragma unroll
      for (int j = 0; j < 3; ++j)
        xres[j][r] = x[(size_t)(bm + rl) * D_ + (ng * 3 + j) * 32 + m32];
    }
  }
  float h1v[3][16];   // R32(c): LN1 outputs carried to ff2 residual

  {
    // staging item = (row, 16-col chunk h in 0..5); e = r*6 + h; pitch 104.
    int eA0 = tid;           int rA0 = eA0 / 6, hA0 = eA0 % 6;
    bool sA1 = (tid < 128);  // A: 384 items, e1 = tid+256 < 384
    int eA1 = tid + 256;     int rA1 = eA1 / 6, hA1 = eA1 % 6;
    float4* dA0 = (float4*)&AslA[rA0 * 104 + hA0 * 16];
    float4* dA1 = (float4*)&AslA[rA1 * 104 + hA1 * 16];

    int eB0 = tid;           int rb0 = eB0 / 6, hb0 = eB0 % 6;
    int eB1 = tid + 256;     int rb1 = eB1 / 6, hb1 = eB1 % 6;
    int eB2 = tid + 512;     int rb2 = eB2 / 6, hb2 = eB2 % 6;
    int eB3 = tid + 768;     int rb3 = eB3 / 6, hb3 = eB3 % 6;
    bool sB4 = (tid < 128);  // Wo: 1152 items, e4 = tid+1024 < 1152
    int eB4 = tid + 1024;    int rb4 = eB4 / 6, hb4 = eB4 % 6;
    float4* dB0 = (float4*)&BslA[rb0 * 104 + hb0 * 16];
    float4* dB1 = (float4*)&BslA[rb1 * 104 + hb1 * 16];
    float4* dB2 = (float4*)&BslA[rb2 * 104 + hb2 * 16];
    float4* dB3 = (float4*)&BslA[rb3 * 104 + hb3 * 16];
    float4* dB4 = (float4*)&BslA[rb4 * 104 + hb4 * 16];

    // prologue k0=0
    {
      const float4* s0 = (const float4*)(attb + (size_t)(bm + rA0) * D_ + hA0 * 16);
      dA0[0] = s0[0]; dA0[1] = s0[1];
      if (sA1) {
        const float4* s1 = (const float4*)(attb + (size_t)(bm + rA1) * D_ + hA1 * 16);
        dA1[0] = s1[0]; dA1[1] = s1[1];
      }
      const float4* p0 = (const float4*)(Wo + (size_t)rb0 * D_ + hb0 * 16);
      dB0[0] = p0[0]; dB0[1] = p0[1];
      const float4* p1 = (const float4*)(Wo + (size_t)rb1 * D_ + hb1 * 16);
      dB1[0] = p1[0]; dB1[1] = p1[1];
      const float4* p2 = (const float4*)(Wo + (size_t)rb2 * D_ + hb2 * 16);
      dB2[0] = p2[0]; dB2[1] = p2[1];
      const float4* p3 = (const float4*)(Wo + (size_t)rb3 * D_ + hb3 * 16);
      dB3[0] = p3[0]; dB3[1] = p3[1];
      if (sB4) {
        const float4* p4 = (const float4*)(Wo + (size_t)rb4 * D_ + hb4 * 16);
        dB4[0] = p4[0]; dB4[1] = p4[1];
      }
    }
    for (int k0 = 0; k0 < D_; k0 += 96) {
      bool more = (k0 + 96 < D_);
      __syncthreads();
      float4 a00, a01, a10, a11;
      float4 n00, n01, n10, n11, n20, n21, n30, n31, n40, n41;
      if (more) {
        const float4* s0 = (const float4*)(attb + (size_t)(bm + rA0) * D_ + k0 + 96 + hA0 * 16);
        a00 = s0[0]; a01 = s0[1];
        if (sA1) {
          const float4* s1 = (const float4*)(attb + (size_t)(bm + rA1) * D_ + k0 + 96 + hA1 * 16);
          a10 = s1[0]; a11 = s1[1];
        }
        const float4* p0 = (const float4*)(Wo + (size_t)rb0 * D_ + k0 + 96 + hb0 * 16);
        n00 = p0[0]; n01 = p0[1];
        const float4* p1 = (const float4*)(Wo + (size_t)rb1 * D_ + k0 + 96 + hb1 * 16);
        n10 = p1[0]; n11 = p1[1];
        const float4* p2 = (const float4*)(Wo + (size_t)rb2 * D_ + k0 + 96 + hb2 * 16);
        n20 = p2[0]; n21 = p2[1];
        const float4* p3 = (const float4*)(Wo + (size_t)rb3 * D_ + k0 + 96 + hb3 * 16);
        n30 = p3[0]; n31 = p3[1];
        if (sB4) {
          const float4* p4 = (const float4*)(Wo + (size_t)rb4 * D_ + k0 + 96 + hb4 * 16);
          n40 = p4[0]; n41 = p4[1];
        }
      }
      #pragma unroll
      for (int kc = 0; kc < 6; ++kc) {
        int ko = kc * 16 + half * 8;
        short8 a = *(const short8*)&AslA[(mt * 32 + m32) * 104 + ko];
        #pragma unroll
        for (int j = 0; j < 3; ++j) {
          short8 bf = *(const short8*)&BslA[((ng * 3 + j) * 32 + m32) * 104 + ko];
          accA[j] = __builtin_amdgcn_mfma_f32_32x32x16_bf16(a, bf, accA[j], 0, 0, 0);
        }
      }
      __syncthreads();
      if (more) {
        dA0[0] = a00; dA0[1] = a01;
        if (sA1) { dA1[0] = a10; dA1[1] = a11; }
        dB0[0] = n00; dB0[1] = n01;
        dB1[0] = n10; dB1[1] = n11;
        dB2[0] = n20; dB2[1] = n21;
        dB3[0] = n30; dB3[1] = n31;
        if (sB4) { dB4[0] = n40; dB4[1] = n41; }
      }
    }
  }
  {
    int rowb = mt * 32 + 4 * half;
    #pragma unroll
    for (int r = 0; r < 16; ++r) {
      int rl = rowb + (r & 3) + 8 * (r >> 2);
      float p = 0.f;
      #pragma unroll
      for (int j = 0; j < 3; ++j) {
        int col = (ng * 3 + j) * 32 + m32;
        float t = accA[j][r] + bo[col] + xres[j][r];
        accA[j][r] = t;
        p += t;
      }
      #pragma unroll
      for (int off = 1; off < 32; off <<= 1) p += __shfl_xor(p, off);
      if (m32 == 0) psum[rl][ng] = p;
    }
    __syncthreads();
    float mean[16];
    #pragma unroll
    for (int r = 0; r < 16; ++r) {
      int rl = rowb + (r & 3) + 8 * (r >> 2);
      mean[r] = (psum[rl][0] + psum[rl][1]) * (1.f / (float)D_);
    }
    #pragma unroll
    for (int r = 0; r < 16; ++r) {
      int rl = rowb + (r & 3) + 8 * (r >> 2);
      float s = 0.f;
      #pragma unroll
      for (int j = 0; j < 3; ++j) { float dd = accA[j][r] - mean[r]; s += dd * dd; }
      #pragma unroll
      for (int off = 1; off < 32; off <<= 1) s += __shfl_xor(s, off);
      if (m32 == 0) psq[rl][ng] = s;
    }
    __syncthreads();   // also: last use of AslA/BslA before Afull writes
    #pragma unroll
    for (int r = 0; r < 16; ++r) {
      int rl = rowb + (r & 3) + 8 * (r >> 2);
      int row = bm + rl;
      float inv = rsqrtf((psq[rl][0] + psq[rl][1]) * (1.f / (float)D_) + 1e-5f);
      #pragma unroll
      for (int j = 0; j < 3; ++j) {
        int col = (ng * 3 + j) * 32 + m32;
        float ovv = (accA[j][r] - mean[r]) * inv * g1[col] + b1v[col];
        h1v[j][r] = ovv;
        x[(size_t)row * D_ + col] = ovv;
        __hip_bfloat16 hb = __float2bfloat16(ovv);
        xb[(size_t)row * D_ + col] = hb;
        Afull[rl * 196 + col] = hb;
      }
    }
  }
  __syncthreads();   // Afull complete before ff1 reads

  // ========= ff1 (A from Afull; W1 256x4 = 1024 items, 4/thread) =========
  floatx16 acc1[4];
  #pragma unroll
  for (int j = 0; j < 4; ++j)
    #pragma unroll
    for (int r = 0; r < 16; ++r) acc1[j][r] = 0.f;

  {
    int rb0 = tid >> 2,          hb0 = tid & 3;
    int rb1 = (tid + 256) >> 2,  hb1 = tid & 3;
    int rb2 = (tid + 512) >> 2,  hb2 = tid & 3;
    int rb3 = (tid + 768) >> 2,  hb3 = tid & 3;
    float4* dB0 = (float4*)&BslB1[rb0 * 72 + hb0 * 16];
    float4* dB1 = (float4*)&BslB1[rb1 * 72 + hb1 * 16];
    float4* dB2 = (float4*)&BslB1[rb2 * 72 + hb2 * 16];
    float4* dB3 = (float4*)&BslB1[rb3 * 72 + hb3 * 16];
    {
      const float4* p0 = (const float4*)(W1 + (size_t)rb0 * D_ + hb0 * 16);
      dB0[0] = p0[0]; dB0[1] = p0[1];
      const float4* p1 = (const float4*)(W1 + (size_t)rb1 * D_ + hb1 * 16);
      dB1[0] = p1[0]; dB1[1] = p1[1];
      const float4* p2 = (const float4*)(W1 + (size_t)rb2 * D_ + hb2 * 16);
      dB2[0] = p2[0]; dB2[1] = p2[1];
      const float4* p3 = (const float4*)(W1 + (size_t)rb3 * D_ + hb3 * 16);
      dB3[0] = p3[0]; dB3[1] = p3[1];
    }
    for (int k0 = 0; k0 < D_; k0 += 64) {
      bool more = (k0 + 64 < D_);
      __syncthreads();
      float4 n00, n01, n10, n11, n20, n21, n30, n31;
      if (more) {
        const float4* p0 = (const float4*)(W1 + (size_t)rb0 * D_ + k0 + 64 + hb0 * 16);
        n00 = p0[0]; n01 = p0[1];
        const float4* p1 = (const float4*)(W1 + (size_t)rb1 * D_ + k0 + 64 + hb1 * 16);
        n10 = p1[0]; n11 = p1[1];
        const float4* p2 = (const float4*)(W1 + (size_t)rb2 * D_ + k0 + 64 + hb2 * 16);
        n20 = p2[0]; n21 = p2[1];
        const float4* p3 = (const float4*)(W1 + (size_t)rb3 * D_ + k0 + 64 + hb3 * 16);
        n30 = p3[0]; n31 = p3[1];
      }
      #pragma unroll
      for (int kc = 0; kc < 4; ++kc) {
        int ko = kc * 16 + half * 8;
        short8 a = ld_frag8(&Afull[(mt * 32 + m32) * 196 + k0 + ko]);
        #pragma unroll
        for (int j = 0; j < 4; ++j) {
          short8 bf = *(const short8*)&BslB1[((ng * 4 + j) * 32 + m32) * 72 + ko];
          acc1[j] = __builtin_amdgcn_mfma_f32_32x32x16_bf16(a, bf, acc1[j], 0, 0, 0);
        }
      }
      __syncthreads();
      if (more) {
        dB0[0] = n00; dB0[1] = n01;
        dB1[0] = n10; dB1[1] = n11;
        dB2[0] = n20; dB2[1] = n21;
        dB3[0] = n30; dB3[1] = n31;
      }
    }
  }
  // ff1 epilogue: relu -> C1 (aliases dead Afull + BslB1 head).
  {
    int rowb = mt * 32 + 4 * half;
    #pragma unroll
    for (int j = 0; j < 4; ++j) {
      int col = (ng * 4 + j) * 32 + m32;
      float cb = b1[col];
      #pragma unroll
      for (int r = 0; r < 16; ++r) {
        int row = rowb + (r & 3) + 8 * (r >> 2);
        C1[row * 260 + col] = __float2bfloat16(fmaxf(acc1[j][r] + cb, 0.f));
      }
    }
  }

  // ========= ff2 (A from C1; W2 192x4 = 768 items, 3/thread; K=256) =======
  floatx16 acc2[3];
  #pragma unroll
  for (int j = 0; j < 3; ++j)
    #pragma unroll
    for (int r = 0; r < 16; ++r) acc2[j][r] = 0.f;

  {
    int rb0 = tid >> 2,          hb0 = tid & 3;
    int rb1 = (tid + 256) >> 2,  hb1 = tid & 3;
    int rb2 = (tid + 512) >> 2,  hb2 = tid & 3;
    float4* dB0 = (float4*)&BslB2[rb0 * 72 + hb0 * 16];
    float4* dB1 = (float4*)&BslB2[rb1 * 72 + hb1 * 16];
    float4* dB2 = (float4*)&BslB2[rb2 * 72 + hb2 * 16];
    {
      const float4* p0 = (const float4*)(W2 + (size_t)rb0 * DFF_ + hb0 * 16);
      dB0[0] = p0[0]; dB0[1] = p0[1];
      const float4* p1 = (const float4*)(W2 + (size_t)rb1 * DFF_ + hb1 * 16);
      dB1[0] = p1[0]; dB1[1] = p1[1];
      const float4* p2 = (const float4*)(W2 + (size_t)rb2 * DFF_ + hb2 * 16);
      dB2[0] = p2[0]; dB2[1] = p2[1];
    }
    for (int k0 = 0; k0 < DFF_; k0 += 64) {
      bool more = (k0 + 64 < DFF_);
      __syncthreads();                    // C1 + BslB2 tile visible
      float4 n00, n01, n10, n11, n20, n21;
      if (more) {
        const float4* p0 = (const float4*)(W2 + (size_t)rb0 * DFF_ + k0 + 64 + hb0 * 16);
        n00 = p0[0]; n01 = p0[1];
        const float4* p1 = (const float4*)(W2 + (size_t)rb1 * DFF_ + k0 + 64 + hb1 * 16);
        n10 = p1[0]; n11 = p1[1];
        const float4* p2 = (const float4*)(W2 + (size_t)rb2 * DFF_ + k0 + 64 + hb2 * 16);
        n20 = p2[0]; n21 = p2[1];
      }
      #pragma unroll
      for (int kc = 0; kc < 4; ++kc) {
        int ko = kc * 16 + half * 8;
        short8 a = ld_frag8(&C1[(mt * 32 + m32) * 260 + k0 + ko]);
        #pragma unroll
        for (int j = 0; j < 3; ++j) {
          short8 bf = *(const short8*)&BslB2[((ng * 3 + j) * 32 + m32) * 72 + ko];
          acc2[j] = __builtin_amdgcn_mfma_f32_32x32x16_bf16(a, bf, acc2[j], 0, 0, 0);
        }
      }
      __syncthreads();
      if (more) {
        dB0[0] = n00; dB0[1] = n01;
        dB1[0] = n10; dB1[1] = n11;
        dB2[0] = n20; dB2[1] = n21;
      }
    }
  }

  int rowb = mt * 32 + 4 * half;
  #pragma unroll
  for (int r = 0; r < 16; ++r) {
    int rl = rowb + (r & 3) + 8 * (r >> 2);
    float p = 0.f;
    #pragma unroll
    for (int j = 0; j < 3; ++j) {
      int col = (ng * 3 + j) * 32 + m32;
      float t = acc2[j][r] + b2[col] + h1v[j][r];
      acc2[j][r] = t;
      p += t;
    }
    #pragma unroll
    for (int off = 1; off < 32; off <<= 1) p += __shfl_xor(p, off);
    if (m32 == 0) psum[rl][ng] = p;
  }
  __syncthreads();
  float mean[16];
  #pragma unroll
  for (int r = 0; r < 16; ++r) {
    int rl = rowb + (r & 3) + 8 * (r >> 2);
    mean[r] = (psum[rl][0] + psum[rl][1]) * (1.f / (float)D_);
  }
  #pragma unroll
  for (int r = 0; r < 16; ++r) {
    int rl = rowb + (r & 3) + 8 * (r >> 2);
    float s = 0.f;
    #pragma unroll
    for (int j = 0; j < 3; ++j) { float dd = acc2[j][r] - mean[r]; s += dd * dd; }
    #pragma unroll
    for (int off = 1; off < 32; off <<= 1) s += __shfl_xor(s, off);
    if (m32 == 0) psq[rl][ng] = s;
  }
  __syncthreads();
  #pragma unroll
  for (int r = 0; r < 16; ++r) {
    int rl = rowb + (r & 3) + 8 * (r >> 2);
    int row = bm + rl;
    float inv = rsqrtf((psq[rl][0] + psq[rl][1]) * (1.f / (float)D_) + 1e-5f);
    #pragma unroll
    for (int j = 0; j < 3; ++j) {
      int col = (ng * 3 + j) * 32 + m32;
      float ovv = (acc2[j][r] - mean[r]) * inv * g2[col] + b2v[col];
      x[(size_t)row * D_ + col] = ovv;
      xb[(size_t)row * D_ + col] = __float2bfloat16(ovv);
    }
  }
}

// ---------------------------------------------------------------------------
// Head v3 (R26-validated): grid 640 = b x 5 window-groups of 4.
// ---------------------------------------------------------------------------
__global__ __launch_bounds__(256)
void head3_kernel(const float* __restrict__ x, const float* __restrict__ noise,
                  const float* __restrict__ pw1, const float* __restrict__ pb1,
                  const float* __restrict__ pw2, const float* __restrict__ pb2,
                  const float* __restrict__ ew1, const float* __restrict__ eb1,
                  const float* __restrict__ ew2, const float* __restrict__ eb2,
                  float* __restrict__ out)
{
  __shared__ float slotS[4][192];    // 3072
  __shared__ float phS[4][256];      // 4096
  __shared__ float ehS[4][128];      // 2048
  int blk = blockIdx.x;
  int b = blk / 5, g = blk - b * 5;  // windows g*4 .. g*4+3
  int tid = threadIdx.x;

  const float* lastrow = x + ((size_t)b * S_ + (S_ - 1)) * D_;
  for (int e = tid; e < 4 * 192; e += 256) {
    int wl = e / 192, c = e - wl * 192;
    int wg = g * 4 + wl;
    slotS[wl][c] = lastrow[c] + noise[((size_t)wg * B_ + b) * D_ + c] * 0.1f;
  }
  __syncthreads();

  bool doe = (tid < 128);
  float accp[4], acce[4];
  {
    float bp = pb1[tid];
    float be = doe ? eb1[tid] : 0.f;
    #pragma unroll
    for (int wl = 0; wl < 4; ++wl) { accp[wl] = bp; acce[wl] = be; }
  }
  {
    const float4* wr = (const float4*)(pw1 + (size_t)tid * D_);
    const float4* we = (const float4*)(ew1 + (size_t)(doe ? tid : 0) * D_);
    for (int k4 = 0; k4 < 48; ++k4) {
      float4 wv = wr[k4];
      float4 ev = we[k4];
      #pragma unroll
      for (int wl = 0; wl < 4; ++wl) {
        float4 sv = *(const float4*)&slotS[wl][k4 * 4];
        accp[wl] += wv.x*sv.x + wv.y*sv.y + wv.z*sv.z + wv.w*sv.w;
        if (doe) acce[wl] += ev.x*sv.x + ev.y*sv.y + ev.z*sv.z + ev.w*sv.w;
      }
    }
  }
  #pragma unroll
  for (int wl = 0; wl < 4; ++wl) {
    phS[wl][tid] = fmaxf(accp[wl], 0.f);
    if (doe) ehS[wl][tid] = fmaxf(acce[wl], 0.f);
  }
  __syncthreads();

  if (tid < 16) {
    int wl = tid >> 2, c = tid & 3;
    float a = pb2[c];
    const float4* wr = (const float4*)(pw2 + c * 256);
    const float4* pp = (const float4*)&phS[wl][0];
    for (int k = 0; k < 64; ++k) {
      float4 wv = wr[k], pv = pp[k];
      a += wv.x*pv.x + wv.y*pv.y + wv.z*pv.z + wv.w*pv.w;
    }
    out[((size_t)b * W_ + g * 4 + wl) * 4 + c] = a;
  } else if (tid >= 64 && tid < 68) {
    int wl = tid - 64;
    float a = eb2[0];
    const float4* wr = (const float4*)ew2;
    const float4* pp = (const float4*)&ehS[wl][0];
    for (int k = 0; k < 32; ++k) {
      float4 wv = wr[k], pv = pp[k];
      a += wv.x*pv.x + wv.y*pv.y + wv.z*pv.z + wv.w*pv.w;
    }
    out[(size_t)B_ * W_ * 4 + (size_t)b * W_ + g * 4 + wl] = 1.f / (1.f + expf(-a));
  }
}

// ---------------------------------------------------------------------------
extern "C" void kernel_launch(void* const* d_in, const int* in_sizes, int n_in,
                              void* d_out, int out_size, void* d_ws, size_t ws_size,
                              hipStream_t stream)
{
  const int*   title_idx       = (const int*)  d_in[0];
  const int*   class_idx       = (const int*)  d_in[1];
  const int*   process_idx     = (const int*)  d_in[2];
  const int*   activity_type   = (const int*)  d_in[3];
  const float* mouse_pos       = (const float*)d_in[4];
  const float* rect            = (const float*)d_in[5];
  const float* flags           = (const float*)d_in[6];
  const float* keyboard_active = (const float*)d_in[7];
  const float* window_mask     = (const float*)d_in[8];
  const float* noise           = (const float*)d_in[9];
  const float* title_emb       = (const float*)d_in[10];
  const float* class_emb       = (const float*)d_in[11];
  const float* process_emb     = (const float*)d_in[12];
  const float* spatial_w1      = (const float*)d_in[13];
  const float* spatial_b1      = (const float*)d_in[14];
  const float* spatial_w2      = (const float*)d_in[15];
  const float* spatial_b2      = (const float*)d_in[16];
  const float* wfuse_w         = (const float*)d_in[17];
  const float* wfuse_b         = (const float*)d_in[18];
  const float* mouse_w1        = (const float*)d_in[19];
  const float* mouse_b1        = (const float*)d_in[20];
  const float* mouse_w2        = (const float*)d_in[21];
  const float* mouse_b2        = (const float*)d_in[22];
  const float* act_emb         = (const float*)d_in[23];
  const float* kbd_w           = (const float*)d_in[24];
  const float* kbd_b           = (const float*)d_in[25];
  const float* afuse_w         = (const float*)d_in[26];
  const float* afuse_b         = (const float*)d_in[27];
  const float* qkv_w           = (const float*)d_in[28];
  const float* qkv_b           = (const float*)d_in[29];
  const float* out_w           = (const float*)d_in[30];
  const float* out_b           = (const float*)d_in[31];
  const float* ff1_w           = (const float*)d_in[32];
  const float* ff1_b           = (const float*)d_in[33];
  const float* ff2_w           = (const float*)d_in[34];
  const float* ff2_b           = (const float*)d_in[35];
  const float* ln1_g           = (const float*)d_in[36];
  const float* ln1_b           = (const float*)d_in[37];
  const float* ln2_g           = (const float*)d_in[38];
  const float* ln2_b           = (const float*)d_in[39];
  const float* proj_w1         = (const float*)d_in[40];
  const float* proj_b1         = (const float*)d_in[41];
  const float* proj_w2         = (const float*)d_in[42];
  const float* proj_b2         = (const float*)d_in[43];
  const float* ex_w1           = (const float*)d_in[44];
  const float* ex_b1           = (const float*)d_in[45];
  const float* ex_w2           = (const float*)d_in[46];
  const float* ex_b2           = (const float*)d_in[47];

  float* out = (float*)d_out;

  // workspace layout
  float* x = (float*)d_ws;                                      // BS*192 f32
  __hip_bfloat16* xb   = (__hip_bfloat16*)(x + (size_t)BS_ * D_);
  __hip_bfloat16* attb = xb   + (size_t)BS_ * D_;
  __hip_bfloat16* wqb  = attb + (size_t)BS_ * D_;
  __hip_bfloat16* wob  = wqb  + (size_t)L_ * THREED_ * D_;
  __hip_bfloat16* wf1b = wob  + (size_t)L_ * D_ * D_;
  __hip_bfloat16* wf2b = wf1b + (size_t)L_ * DFF_ * D_;
  float* TE2  = (float*)(wf2b + (size_t)L_ * D_ * DFF_);        // 1000*128 (permuted cols)
  float* CE2  = TE2  + 1000 * 128;                              // 500*128
  float* PE2  = CE2  + 500 * 128;                               // 1000*128
  __hip_bfloat16* WSPb = (__hip_bfloat16*)(PE2 + 1000 * 128);   // 128*64 bf16
  float* PEtab = (float*)(WSPb + 128 * 64);                     // 100*192 f32
  (void)ws_size; (void)n_in; (void)in_sizes; (void)out_size;

  convertprep_kernel<<<2077, 256, 0, stream>>>(
      qkv_w, wqb, out_w, wob, ff1_w, wf1b, ff2_w, wf2b,
      title_emb, class_emb, process_emb, wfuse_w, wfuse_b,
      spatial_w2, spatial_b2, TE2, CE2, PE2, WSPb, PEtab);

  encode8_kernel<<<BS_ / 8, 512, 0, stream>>>(
      title_idx, class_idx, process_idx, activity_type, mouse_pos, rect, flags,
      keyboard_active, window_mask, spatial_w1, spatial_b1,
      TE2, CE2, PE2, WSPb, PEtab,
      mouse_w1, mouse_b1, mouse_w2, mouse_b2, act_emb, kbd_w, kbd_b,
      afuse_w, afuse_b, x, xb);

  for (int l = 0; l < L_; ++l) {
    qkvattn_kernel<<<B_ * H_, 256, 0, stream>>>(
        xb, wqb + (size_t)l * THREED_ * D_, qkv_b + (size_t)l * THREED_, attb);
    outffln_kernel<<<BS_ / 64, 256, 0, stream>>>(
        attb, wob + (size_t)l * D_ * D_, out_b + (size_t)l * D_,
        ln1_g + (size_t)l * D_, ln1_b + (size_t)l * D_,
        wf1b + (size_t)l * DFF_ * D_, ff1_b + (size_t)l * DFF_,
        wf2b + (size_t)l * D_ * DFF_, ff2_b + (size_t)l * D_,
        ln2_g + (size_t)l * D_, ln2_b + (size_t)l * D_, x, xb);
  }

  head3_kernel<<<B_ * 5, 256, 0, stream>>>(
      x, noise, proj_w1, proj_b1, proj_w2, proj_b2,
      ex_w1, ex_b1, ex_w2, ex_b2, out);
}

// Round 18
// 636.322 us; speedup vs baseline: 1.0584x; 1.0019x over previous
//
#include <hip/hip_runtime.h>
#include <hip/hip_bf16.h>
#include <math.h>

#define B_ 128
#define S_ 100
#define W_ 20
#define D_ 192
#define L_ 6
#define H_ 8
#define DFF_ 256
#define DH_ 24
#define BS_ (B_*S_)
#define THREED_ 576

typedef short short8 __attribute__((ext_vector_type(8)));
typedef short short4v __attribute__((ext_vector_type(4)));
typedef float floatx16 __attribute__((ext_vector_type(16)));

__device__ __forceinline__ float posenc(int s, int c) {
  float freq = expf(-logf(10000.f) * (float)(2 * (c >> 1)) / (float)D_);
  float ang = (float)s * freq;
  return (c & 1) ? cosf(ang) : sinf(ang);
}

__device__ __forceinline__ short8 ld_frag8(const __hip_bfloat16* p) {
  short4v lo = *(const short4v*)p;
  short4v hi = *(const short4v*)(p + 4);
  short8 r;
  r[0]=lo[0]; r[1]=lo[1]; r[2]=lo[2]; r[3]=lo[3];
  r[4]=hi[0]; r[5]=hi[1]; r[6]=hi[2]; r[7]=hi[3];
  return r;
}

__device__ __forceinline__ short f2bf_s(float v) {
  __hip_bfloat16 t = __float2bfloat16(v);
  return *reinterpret_cast<short*>(&t);
}

__device__ __forceinline__ float dot4(float4 a, float4 b) {
  return a.x*b.x + a.y*b.y + a.z*b.z + a.w*b.w;
}

// ---------------------------------------------------------------------------
// Merged weight conversion + encoder precompute (R24-validated). 2077 blocks.
// ---------------------------------------------------------------------------
__global__ __launch_bounds__(256)
void convertprep_kernel(
    const float* __restrict__ s0, __hip_bfloat16* __restrict__ d0,
    const float* __restrict__ s1, __hip_bfloat16* __restrict__ d1,
    const float* __restrict__ s2, __hip_bfloat16* __restrict__ d2,
    const float* __restrict__ s3, __hip_bfloat16* __restrict__ d3,
    const float* __restrict__ te, const float* __restrict__ ce,
    const float* __restrict__ pe, const float* __restrict__ wfw,
    const float* __restrict__ wfb, const float* __restrict__ sw2,
    const float* __restrict__ sb2,
    float* __restrict__ TE2, float* __restrict__ CE2,
    float* __restrict__ PE2, __hip_bfloat16* __restrict__ WSPb,
    float* __restrict__ PEtab)
{
  int b = blockIdx.x, tid = threadIdx.x;
  if (b < 720) {
    const float* s; __hip_bfloat16* d; int base;
    if      (b < 324) { s = s0; d = d0; base = b; }
    else if (b < 432) { s = s1; d = d1; base = b - 324; }
    else if (b < 576) { s = s2; d = d2; base = b - 432; }
    else              { s = s3; d = d3; base = b - 576; }
    int i = (base * 256 + tid) * 8;
    float4 v0 = *(const float4*)(s + i);
    float4 v1 = *(const float4*)(s + i + 4);
    __hip_bfloat162* d2p = (__hip_bfloat162*)(d + i);
    d2p[0] = __float22bfloat162_rn(make_float2(v0.x, v0.y));
    d2p[1] = __float22bfloat162_rn(make_float2(v0.z, v0.w));
    d2p[2] = __float22bfloat162_rn(make_float2(v1.x, v1.y));
    d2p[3] = __float22bfloat162_rn(make_float2(v1.z, v1.w));
    return;
  }
  int blk = b - 720;
  if (blk < 1250) {
    int item = blk * 256 + tid;
    int v = item >> 7, o = item & 127;
    const float* src; float* dst; int base, vv;
    float a;
    if (v < 1000) {
      src = te; dst = TE2; base = 0; vv = v;
      a = wfb[o];                                 // fold wfuse bias
      const float4* w4 = (const float4*)(wfw + o * 128 + 96);
      const float4* b4 = (const float4*)sb2;
      #pragma unroll
      for (int k4 = 0; k4 < 8; ++k4) a += dot4(w4[k4], b4[k4]);
    } else if (v < 1500) {
      src = ce; dst = CE2; base = 32; vv = v - 1000; a = 0.f;
    } else {
      src = pe; dst = PE2; base = 64; vv = v - 1500; a = 0.f;
    }
    const float4* s4 = (const float4*)(src + vv * 32);
    const float4* w4 = (const float4*)(wfw + o * 128 + base);
    #pragma unroll
    for (int k4 = 0; k4 < 8; ++k4) a += dot4(s4[k4], w4[k4]);
    int op = ((o & 31) << 2) + (o >> 5);          // R23 permuted placement
    dst[vv * 128 + op] = a;
  } else if (blk < 1282) {
    int item = (blk - 1250) * 256 + tid;
    int j = item >> 7, o = item & 127;           // j = hidden k, o = out col
    float a = 0.f;
    #pragma unroll 8
    for (int k = 0; k < 32; ++k) a += wfw[o * 128 + 96 + k] * sw2[k * 64 + j];
    WSPb[o * 64 + j] = __float2bfloat16(a);      // B operand [col][k]
  } else {
    int idx = (blk - 1282) * 256 + tid;          // [0, 19200)
    int s_ = idx / D_, c = idx - s_ * D_;
    PEtab[idx] = posenc(s_, c);
  }
}

// ---------------------------------------------------------------------------
// Encoder v13 (R29-measured BEST ~100us; unchanged).
// 8 bs/block, 512 threads, grid 1600. LDS 26.1KB.
// ---------------------------------------------------------------------------
__global__ __launch_bounds__(512)
void encode8_kernel(
    const int* __restrict__ title_idx, const int* __restrict__ class_idx,
    const int* __restrict__ process_idx, const int* __restrict__ activity_type,
    const float* __restrict__ mouse_pos, const float* __restrict__ rect,
    const float* __restrict__ flags, const float* __restrict__ keyboard_active,
    const float* __restrict__ window_mask,
    const float* __restrict__ sw1, const float* __restrict__ sb1,
    const float* __restrict__ TE2, const float* __restrict__ CE2,
    const float* __restrict__ PE2, const __hip_bfloat16* __restrict__ WSPb,
    const float* __restrict__ PEtab,
    const float* __restrict__ mw1, const float* __restrict__ mb1,
    const float* __restrict__ mw2, const float* __restrict__ mb2,
    const float* __restrict__ act_emb, const float* __restrict__ kbw,
    const float* __restrict__ kbb,
    const float* __restrict__ afw, const float* __restrict__ afb,
    float* __restrict__ x, __hip_bfloat16* __restrict__ xb)
{
  __shared__ __hip_bfloat16 Bls[128][72];            // 18432
  __shared__ int   idxS[8][20][3];                   // 1920
  __shared__ float maskS[8][20];                     // 640
  __shared__ __align__(16) float rectS[8][20][8];    // 5120 (wave-private after stage)

  int tid = threadIdx.x;
  int w = tid >> 6, lane = tid & 63;
  int m32 = lane & 31, half = lane >> 5;
  int bs0 = blockIdx.x * 8;
  int bs = bs0 + w;

  if (tid < 480) {
    int g2 = tid / 60, rem = tid % 60, which = rem / 20, w_ = rem % 20;
    const int* src = (which == 0) ? title_idx : (which == 1) ? class_idx : process_idx;
    idxS[g2][w_][which] = src[(bs0 + g2) * W_ + w_];
  }
  if (tid < 160) {
    int g2 = tid / 20, w_ = tid % 20;
    maskS[g2][w_] = window_mask[(bs0 + g2) * W_ + w_];
  }
  for (int e = tid; e < 960; e += 512) {      // 8*20*6
    int g2 = e / 120, rem = e % 120, w_ = rem / 6, c = rem % 6;
    int rg = (bs0 + g2) * W_ + w_;
    rectS[g2][w_][c] = (c < 4) ? rect[rg * 4 + c] : flags[rg * 2 + (c - 4)];
  }
  for (int e = tid; e < 1024; e += 512) {     // 128 cols x 8 k-groups of 8
    int col = e >> 3, k8 = e & 7;
    short8 v = *(const short8*)&WSPb[col * 64 + k8 * 8];
    *(short8*)&Bls[col][k8 * 8] = v;
  }
  __syncthreads();

  short8 afr[4];
  {
    float rc[6];
    bool act = (m32 < W_);
    if (act) {
      #pragma unroll
      for (int c = 0; c < 6; ++c) rc[c] = rectS[w][m32][c];
    }
    #pragma unroll
    for (int s = 0; s < 4; ++s) {
      short8 f;
      #pragma unroll
      for (int jp = 0; jp < 8; ++jp) {
        float a = 0.f;
        if (act) {
          int j = s * 16 + half * 8 + jp;
          const float* w1 = sw1 + j * 6;
          a = sb1[j];
          #pragma unroll
          for (int c = 0; c < 6; ++c) a += w1[c] * rc[c];
          a = fmaxf(a, 0.f);
        }
        f[jp] = f2bf_s(a);
      }
      afr[s] = f;
    }
  }

  floatx16 acc[4];
  #pragma unroll
  for (int nt = 0; nt < 4; ++nt)
    #pragma unroll
    for (int r = 0; r < 16; ++r) acc[nt][r] = 0.f;

  #pragma unroll
  for (int s = 0; s < 4; ++s) {
    int ko = s * 16 + half * 8;
    #pragma unroll
    for (int nt = 0; nt < 4; ++nt) {
      short8 bf = *(const short8*)&Bls[nt * 32 + m32][ko];
      acc[nt] = __builtin_amdgcn_mfma_f32_32x32x16_bf16(afr[s], bf, acc[nt], 0, 0, 0);
    }
  }

  // ---- epilogue: one float4 per (row, table) from permuted tables ----
  float cs[4] = {0.f, 0.f, 0.f, 0.f};
  #pragma unroll
  for (int r = 0; r < 16; ++r) {
    int row = (r & 3) + 8 * (r >> 2) + 4 * half;
    if (row < W_) {
      int t  = idxS[w][row][0];
      int ci = idxS[w][row][1];
      int p  = idxS[w][row][2];
      float mk = maskS[w][row];
      float4 gt = *(const float4*)&TE2[(size_t)t  * 128 + m32 * 4];
      float4 gc = *(const float4*)&CE2[(size_t)ci * 128 + m32 * 4];
      float4 gp = *(const float4*)&PE2[(size_t)p  * 128 + m32 * 4];
      float g0 = gt.x + gc.x + gp.x;
      float g1 = gt.y + gc.y + gp.y;
      float g2v = gt.z + gc.z + gp.z;
      float g3 = gt.w + gc.w + gp.w;
      cs[0] += fmaxf(acc[0][r] + g0, 0.f) * mk;
      cs[1] += fmaxf(acc[1][r] + g1, 0.f) * mk;
      cs[2] += fmaxf(acc[2][r] + g2v, 0.f) * mk;
      cs[3] += fmaxf(acc[3][r] + g3, 0.f) * mk;
    }
  }
  #pragma unroll
  for (int nt = 0; nt < 4; ++nt) cs[nt] += __shfl_xor(cs[nt], 32);
  if (half == 0) {
    int s_ = bs % S_;
    #pragma unroll
    for (int nt = 0; nt < 4; ++nt) {
      int col = nt * 32 + m32;
      float v = cs[nt] * (1.f / (float)W_) + PEtab[s_ * D_ + col];
      x[(size_t)bs * D_ + col] = v;
      xb[(size_t)bs * D_ + col] = __float2bfloat16(v);
    }
  }

  // ---- activity-fuse tail (cols 128..191): wave-local, barrier-free ----
  {
    float* wsc = &rectS[w][0][0];   // 160 floats available, need 96
    if (lane < 32) {
      float mx = mouse_pos[bs * 2 + 0] * (1.f / 1920.f);
      float my = mouse_pos[bs * 2 + 1] * (1.f / 1080.f);
      wsc[64 + lane] = fmaxf(mw1[lane * 2] * mx + mw1[lane * 2 + 1] * my + mb1[lane], 0.f);
    }
    __builtin_amdgcn_wave_barrier();
    float cv;
    if (lane < 32) {
      float a = mb2[lane];
      const float4* wv = (const float4*)(mw2 + lane * 32);
      const float4* hv = (const float4*)(wsc + 64);
      #pragma unroll
      for (int k4 = 0; k4 < 8; ++k4) {
        float4 ww = wv[k4], hh = hv[k4];
        a += ww.x*hh.x + ww.y*hh.y + ww.z*hh.z + ww.w*hh.w;
      }
      cv = a;
    } else if (lane < 48) {
      cv = act_emb[activity_type[bs] * 16 + (lane - 32)];
    } else {
      cv = kbw[lane - 48] * keyboard_active[bs] + kbb[lane - 48];
    }
    wsc[lane] = cv;
    __builtin_amdgcn_wave_barrier();
    {
      float a = afb[lane];
      const float4* w4 = (const float4*)(afw + lane * 64);
      const float4* cp = (const float4*)wsc;
      #pragma unroll
      for (int k4 = 0; k4 < 16; ++k4) {
        float4 ww = w4[k4], c2 = cp[k4];
        a += ww.x*c2.x + ww.y*c2.y + ww.z*c2.z + ww.w*c2.w;
      }
      float v = fmaxf(a, 0.f);
      int cg = 128 + lane;
      float ovv = v + PEtab[(bs % S_) * D_ + cg];
      x[(size_t)bs * D_ + cg] = ovv;
      xb[(size_t)bs * D_ + cg] = __float2bfloat16(ovv);
    }
  }
}

// ---------------------------------------------------------------------------
// Fused qkv + attention (R28-validated BK=64; unchanged).
// ---------------------------------------------------------------------------
__global__ __launch_bounds__(256)
void qkvattn_kernel(const __hip_bfloat16* __restrict__ xb,
                    const __hip_bfloat16* __restrict__ Wq,
                    const float* __restrict__ qb,
                    __hip_bfloat16* __restrict__ o)
{
  __shared__ __align__(16) char smem[40960];
  __hip_bfloat16* Asl = (__hip_bfloat16*)smem;             // 128*72
  __hip_bfloat16* Bsl = (__hip_bfloat16*)(smem + 18432);   // 96*72
  __hip_bfloat16* Qs  = (__hip_bfloat16*)smem;             // 128*40 (post-K)
  __hip_bfloat16* Ks  = (__hip_bfloat16*)(smem + 10240);   // 128*40 (post-K)
  __hip_bfloat16* Ps  = (__hip_bfloat16*)smem;             // 128*132 (post-QK^T)
  __hip_bfloat16* Vt  = (__hip_bfloat16*)(smem + 33792);   // 32*112

  int bh = blockIdx.x;
  int hh = bh & 7, b = bh >> 3;
  int tid = threadIdx.x, lane = tid & 63, w = tid >> 6;
  int m32 = lane & 31, half = lane >> 5;

  for (int e = tid; e < (32 * 112) / 8; e += 256)
    ((float4*)Vt)[e] = make_float4(0.f, 0.f, 0.f, 0.f);

  int rA0 = tid >> 2,          hA0 = tid & 3;
  int rA1 = (tid + 256) >> 2,  hA1 = tid & 3;
  int rrA0 = rA0 < S_ ? rA0 : S_ - 1;
  int rrA1 = rA1 < S_ ? rA1 : S_ - 1;
  size_t baseA0 = (size_t)(b * S_ + rrA0) * D_;
  size_t baseA1 = (size_t)(b * S_ + rrA1) * D_;
  float4* dA0 = (float4*)&Asl[rA0 * 72 + hA0 * 16];
  float4* dA1 = (float4*)&Asl[rA1 * 72 + hA1 * 16];

  int rB0 = tid >> 2, hB0 = tid & 3;
  int tB0 = rB0 >> 5, jB0 = rB0 & 31;
  bool actB0 = (jB0 < DH_);
  bool isB1 = (tid < 128);
  int rB1 = (tid + 256) >> 2, hB1 = tid & 3;
  int tB1 = rB1 >> 5, jB1 = rB1 & 31;
  bool actB1 = isB1 && (jB1 < DH_);
  size_t baseB0 = actB0 ? (size_t)(tB0 * D_ + hh * DH_ + jB0) * D_ : 0;
  size_t baseB1 = actB1 ? (size_t)(tB1 * D_ + hh * DH_ + jB1) * D_ : 0;
  float4* dB0 = (float4*)&Bsl[rB0 * 72 + hB0 * 16];
  float4* dB1 = (float4*)&Bsl[rB1 * 72 + hB1 * 16];

  {
    float4 z = make_float4(0.f, 0.f, 0.f, 0.f);
    if (!actB0) { dB0[0] = z; dB0[1] = z; }
    if (isB1 && !actB1) { dB1[0] = z; dB1[1] = z; }
  }
  {
    const float4* s0 = (const float4*)&xb[baseA0 + hA0 * 16];
    float4 a00 = s0[0], a01 = s0[1];
    const float4* s1 = (const float4*)&xb[baseA1 + hA1 * 16];
    float4 a10 = s1[0], a11 = s1[1];
    if (actB0) {
      const float4* p = (const float4*)&Wq[baseB0 + hB0 * 16];
      dB0[0] = p[0]; dB0[1] = p[1];
    }
    if (actB1) {
      const float4* p = (const float4*)&Wq[baseB1 + hB1 * 16];
      dB1[0] = p[0]; dB1[1] = p[1];
    }
    dA0[0] = a00; dA0[1] = a01;
    dA1[0] = a10; dA1[1] = a11;
  }

  floatx16 acc[3];
  #pragma unroll
  for (int t = 0; t < 3; ++t)
    #pragma unroll
    for (int r = 0; r < 16; ++r) acc[t][r] = 0.f;

  for (int k0 = 0; k0 < D_; k0 += 64) {
    bool more = (k0 + 64 < D_);
    __syncthreads();                  // stage for k0 visible
    float4 a00, a01, a10, a11, b00, b01, b10, b11;
    if (more) {
      const float4* s0 = (const float4*)&xb[baseA0 + k0 + 64 + hA0 * 16];
      a00 = s0[0]; a01 = s0[1];
      const float4* s1 = (const float4*)&xb[baseA1 + k0 + 64 + hA1 * 16];
      a10 = s1[0]; a11 = s1[1];
      if (actB0) {
        const float4* p = (const float4*)&Wq[baseB0 + k0 + 64 + hB0 * 16];
        b00 = p[0]; b01 = p[1];
      }
      if (actB1) {
        const float4* p = (const float4*)&Wq[baseB1 + k0 + 64 + hB1 * 16];
        b10 = p[0]; b11 = p[1];
      }
    }
    #pragma unroll
    for (int kc = 0; kc < 4; ++kc) {
      int ko = kc * 16 + half * 8;
      short8 a = *(const short8*)&Asl[(w * 32 + m32) * 72 + ko];
      #pragma unroll
      for (int t = 0; t < 3; ++t) {
        short8 bf = *(const short8*)&Bsl[(t * 32 + m32) * 72 + ko];
        acc[t] = __builtin_amdgcn_mfma_f32_32x32x16_bf16(a, bf, acc[t], 0, 0, 0);
      }
    }
    __syncthreads();                  // all waves done reading k0 tile
    if (more) {
      dA0[0] = a00; dA0[1] = a01;
      dA1[0] = a10; dA1[1] = a11;
      if (actB0) { dB0[0] = b00; dB0[1] = b01; }
      if (actB1) { dB1[0] = b10; dB1[1] = b11; }
    }
  }
  // after final barrier: Asl/Bsl dead, safe to alias with Qs/Ks.
  {
    bool dv = (m32 < DH_);
    float bq = dv ? qb[0 * D_ + hh * DH_ + m32] : 0.f;
    float bk = dv ? qb[1 * D_ + hh * DH_ + m32] : 0.f;
    float bv = dv ? qb[2 * D_ + hh * DH_ + m32] : 0.f;
    #pragma unroll
    for (int r = 0; r < 16; ++r) {
      int row = w * 32 + (r & 3) + 8 * (r >> 2) + 4 * half;
      Qs[row * 40 + m32] = __float2bfloat16(dv ? acc[0][r] + bq : 0.f);
      Ks[row * 40 + m32] = __float2bfloat16(dv ? acc[1][r] + bk : 0.f);
      if (dv && row < S_) Vt[m32 * 112 + row] = __float2bfloat16(acc[2][r] + bv);
    }
  }
  __syncthreads();

  floatx16 sc[4];
  #pragma unroll
  for (int nt = 0; nt < 4; ++nt)
    #pragma unroll
    for (int r = 0; r < 16; ++r) sc[nt][r] = 0.f;
  #pragma unroll
  for (int kc = 0; kc < 2; ++kc) {
    int ko = kc * 16 + half * 8;
    short8 a = *(const short8*)&Qs[(w * 32 + m32) * 40 + ko];
    #pragma unroll
    for (int nt = 0; nt < 4; ++nt) {
      short8 bf = *(const short8*)&Ks[(nt * 32 + m32) * 40 + ko];
      sc[nt] = __builtin_amdgcn_mfma_f32_32x32x16_bf16(a, bf, sc[nt], 0, 0, 0);
    }
  }
  __syncthreads();   // all waves done reading Qs/Ks before Ps overwrites them

  const float scale = 0.20412414523193154f;  // 1/sqrt(24)
  float rinv[16];
  #pragma unroll
  for (int r = 0; r < 16; ++r) {
    float mx = -1e30f;
    #pragma unroll
    for (int nt = 0; nt < 4; ++nt) {
      float s = sc[nt][r] * scale;
      if (nt == 3 && m32 >= 4) s = -1e30f;   // keys >= 100
      sc[nt][r] = s;
      mx = fmaxf(mx, s);
    }
    #pragma unroll
    for (int off = 1; off < 32; off <<= 1) mx = fmaxf(mx, __shfl_xor(mx, off));
    float sum = 0.f;
    #pragma unroll
    for (int nt = 0; nt < 4; ++nt) {
      float e = expf(sc[nt][r] - mx);
      sc[nt][r] = e;
      sum += e;
    }
    #pragma unroll
    for (int off = 1; off < 32; off <<= 1) sum += __shfl_xor(sum, off);
    rinv[r] = 1.f / sum;
  }
  #pragma unroll
  for (int r = 0; r < 16; ++r) {
    int rowl = (r & 3) + 8 * (r >> 2) + 4 * half;
    #pragma unroll
    for (int nt = 0; nt < 4; ++nt)
      Ps[(w * 32 + rowl) * 132 + nt * 32 + m32] = __float2bfloat16(sc[nt][r]);
  }
  // Ps is wave-private — no barrier.

  floatx16 ov;
  #pragma unroll
  for (int r = 0; r < 16; ++r) ov[r] = 0.f;
  #pragma unroll
  for (int kt = 0; kt < 7; ++kt) {       // 112 keys (100..111: P=0, Vt=0)
    int ko = kt * 16 + half * 8;
    short8 a = ld_frag8(&Ps[(w * 32 + m32) * 132 + ko]);
    short8 bf = *(const short8*)&Vt[m32 * 112 + ko];
    ov = __builtin_amdgcn_mfma_f32_32x32x16_bf16(a, bf, ov, 0, 0, 0);
  }
  #pragma unroll
  for (int r = 0; r < 16; ++r) {
    int rowl = (r & 3) + 8 * (r >> 2) + 4 * half;
    int q = w * 32 + rowl;
    if (m32 < DH_ && q < S_)
      o[((size_t)(b * S_ + q)) * D_ + hh * DH_ + m32] =
          __float2bfloat16(ov[r] * rinv[r]);
  }
}

// ---------------------------------------------------------------------------
// Fused out-proj+LN1 + ff1+ff2+LN2. R32-validated (BK=96 phase A, xres
// hoist, h1v carry). R33: LN1's global x/xb stores DELETED -- dataflow-dead
// since R25 (ff1 reads Afull) + R32 (ff2 residual reads h1v); LN2 overwrites
// the same locations before any other reader. ~14.7MB dead stores/dispatch.
// ---------------------------------------------------------------------------
__global__ __launch_bounds__(256)
void outffln_kernel(const __hip_bfloat16* __restrict__ attb,
                    const __hip_bfloat16* __restrict__ Wo, const float* __restrict__ bo,
                    const float* __restrict__ g1, const float* __restrict__ b1v,
                    const __hip_bfloat16* __restrict__ W1, const float* __restrict__ b1,
                    const __hip_bfloat16* __restrict__ W2, const float* __restrict__ b2,
                    const float* __restrict__ g2, const float* __restrict__ b2v,
                    float* __restrict__ x, __hip_bfloat16* __restrict__ xb)
{
  __shared__ __align__(16) char arena[61952];
  __hip_bfloat16* AslA  = (__hip_bfloat16*)arena;             // 64*104
  __hip_bfloat16* BslA  = (__hip_bfloat16*)(arena + 13312);   // 192*104
  __hip_bfloat16* Afull = (__hip_bfloat16*)arena;             // 64*196 (post-LN1)
  __hip_bfloat16* BslB1 = (__hip_bfloat16*)(arena + 25088);   // 256*72 (W1)
  __hip_bfloat16* C1    = (__hip_bfloat16*)arena;             // 64*260 (post-ff1)
  __hip_bfloat16* BslB2 = (__hip_bfloat16*)(arena + 33280);   // 192*72 (W2)
  float (*psum)[2] = (float(*)[2])(arena + 60928);
  float (*psq)[2]  = (float(*)[2])(arena + 61440);

  int tid = threadIdx.x, lane = tid & 63, w = tid >> 6;
  int m32 = lane & 31, half = lane >> 5;
  int mt = w & 1, ng = w >> 1;
  int bm = blockIdx.x * 64;

  // ========= phase A: out-proj + residual + LN1 (K=192, 2 rounds of 96) ====
  floatx16 accA[3];
  #pragma unroll
  for (int j = 0; j < 3; ++j)
    #pragma unroll
    for (int r = 0; r < 16; ++r) accA[j][r] = 0.f;

  // hoist residual x reads -- overlap the entire phase-A K-loop.
  float xres[3][16];
  {
    int rowb0 = mt * 32 + 4 * half;
    #pragma unroll
    for (int r = 0; r < 16; ++r) {
      int rl = rowb0 + (r & 3) + 8 * (r >> 2);
      #pragma unroll
      for (int j = 0; j < 3; ++j)
        xres[j][r] = x[(size_t)(bm + rl) * D_ + (ng * 3 + j) * 32 + m32];
    }
  }
  float h1v[3][16];   // LN1 outputs carried to ff2 residual

  {
    // staging item = (row, 16-col chunk h in 0..5); e = r*6 + h; pitch 104.
    int eA0 = tid;           int rA0 = eA0 / 6, hA0 = eA0 % 6;
    bool sA1 = (tid < 128);  // A: 384 items, e1 = tid+256 < 384
    int eA1 = tid + 256;     int rA1 = eA1 / 6, hA1 = eA1 % 6;
    float4* dA0 = (float4*)&AslA[rA0 * 104 + hA0 * 16];
    float4* dA1 = (float4*)&AslA[rA1 * 104 + hA1 * 16];

    int eB0 = tid;           int rb0 = eB0 / 6, hb0 = eB0 % 6;
    int eB1 = tid + 256;     int rb1 = eB1 / 6, hb1 = eB1 % 6;
    int eB2 = tid + 512;     int rb2 = eB2 / 6, hb2 = eB2 % 6;
    int eB3 = tid + 768;     int rb3 = eB3 / 6, hb3 = eB3 % 6;
    bool sB4 = (tid < 128);  // Wo: 1152 items, e4 = tid+1024 < 1152
    int eB4 = tid + 1024;    int rb4 = eB4 / 6, hb4 = eB4 % 6;
    float4* dB0 = (float4*)&BslA[rb0 * 104 + hb0 * 16];
    float4* dB1 = (float4*)&BslA[rb1 * 104 + hb1 * 16];
    float4* dB2 = (float4*)&BslA[rb2 * 104 + hb2 * 16];
    float4* dB3 = (float4*)&BslA[rb3 * 104 + hb3 * 16];
    float4* dB4 = (float4*)&BslA[rb4 * 104 + hb4 * 16];

    // prologue k0=0
    {
      const float4* s0 = (const float4*)(attb + (size_t)(bm + rA0) * D_ + hA0 * 16);
      dA0[0] = s0[0]; dA0[1] = s0[1];
      if (sA1) {
        const float4* s1 = (const float4*)(attb + (size_t)(bm + rA1) * D_ + hA1 * 16);
        dA1[0] = s1[0]; dA1[1] = s1[1];
      }
      const float4* p0 = (const float4*)(Wo + (size_t)rb0 * D_ + hb0 * 16);
      dB0[0] = p0[0]; dB0[1] = p0[1];
      const float4* p1 = (const float4*)(Wo + (size_t)rb1 * D_ + hb1 * 16);
      dB1[0] = p1[0]; dB1[1] = p1[1];
      const float4* p2 = (const float4*)(Wo + (size_t)rb2 * D_ + hb2 * 16);
      dB2[0] = p2[0]; dB2[1] = p2[1];
      const float4* p3 = (const float4*)(Wo + (size_t)rb3 * D_ + hb3 * 16);
      dB3[0] = p3[0]; dB3[1] = p3[1];
      if (sB4) {
        const float4* p4 = (const float4*)(Wo + (size_t)rb4 * D_ + hb4 * 16);
        dB4[0] = p4[0]; dB4[1] = p4[1];
      }
    }
    for (int k0 = 0; k0 < D_; k0 += 96) {
      bool more = (k0 + 96 < D_);
      __syncthreads();
      float4 a00, a01, a10, a11;
      float4 n00, n01, n10, n11, n20, n21, n30, n31, n40, n41;
      if (more) {
        const float4* s0 = (const float4*)(attb + (size_t)(bm + rA0) * D_ + k0 + 96 + hA0 * 16);
        a00 = s0[0]; a01 = s0[1];
        if (sA1) {
          const float4* s1 = (const float4*)(attb + (size_t)(bm + rA1) * D_ + k0 + 96 + hA1 * 16);
          a10 = s1[0]; a11 = s1[1];
        }
        const float4* p0 = (const float4*)(Wo + (size_t)rb0 * D_ + k0 + 96 + hb0 * 16);
        n00 = p0[0]; n01 = p0[1];
        const float4* p1 = (const float4*)(Wo + (size_t)rb1 * D_ + k0 + 96 + hb1 * 16);
        n10 = p1[0]; n11 = p1[1];
        const float4* p2 = (const float4*)(Wo + (size_t)rb2 * D_ + k0 + 96 + hb2 * 16);
        n20 = p2[0]; n21 = p2[1];
        const float4* p3 = (const float4*)(Wo + (size_t)rb3 * D_ + k0 + 96 + hb3 * 16);
        n30 = p3[0]; n31 = p3[1];
        if (sB4) {
          const float4* p4 = (const float4*)(Wo + (size_t)rb4 * D_ + k0 + 96 + hb4 * 16);
          n40 = p4[0]; n41 = p4[1];
        }
      }
      #pragma unroll
      for (int kc = 0; kc < 6; ++kc) {
        int ko = kc * 16 + half * 8;
        short8 a = *(const short8*)&AslA[(mt * 32 + m32) * 104 + ko];
        #pragma unroll
        for (int j = 0; j < 3; ++j) {
          short8 bf = *(const short8*)&BslA[((ng * 3 + j) * 32 + m32) * 104 + ko];
          accA[j] = __builtin_amdgcn_mfma_f32_32x32x16_bf16(a, bf, accA[j], 0, 0, 0);
        }
      }
      __syncthreads();
      if (more) {
        dA0[0] = a00; dA0[1] = a01;
        if (sA1) { dA1[0] = a10; dA1[1] = a11; }
        dB0[0] = n00; dB0[1] = n01;
        dB1[0] = n10; dB1[1] = n11;
        dB2[0] = n20; dB2[1] = n21;
        dB3[0] = n30; dB3[1] = n31;
        if (sB4) { dB4[0] = n40; dB4[1] = n41; }
      }
    }
  }
  {
    int rowb = mt * 32 + 4 * half;
    #pragma unroll
    for (int r = 0; r < 16; ++r) {
      int rl = rowb + (r & 3) + 8 * (r >> 2);
      float p = 0.f;
      #pragma unroll
      for (int j = 0; j < 3; ++j) {
        int col = (ng * 3 + j) * 32 + m32;
        float t = accA[j][r] + bo[col] + xres[j][r];
        accA[j][r] = t;
        p += t;
      }
      #pragma unroll
      for (int off = 1; off < 32; off <<= 1) p += __shfl_xor(p, off);
      if (m32 == 0) psum[rl][ng] = p;
    }
    __syncthreads();
    float mean[16];
    #pragma unroll
    for (int r = 0; r < 16; ++r) {
      int rl = rowb + (r & 3) + 8 * (r >> 2);
      mean[r] = (psum[rl][0] + psum[rl][1]) * (1.f / (float)D_);
    }
    #pragma unroll
    for (int r = 0; r < 16; ++r) {
      int rl = rowb + (r & 3) + 8 * (r >> 2);
      float s = 0.f;
      #pragma unroll
      for (int j = 0; j < 3; ++j) { float dd = accA[j][r] - mean[r]; s += dd * dd; }
      #pragma unroll
      for (int off = 1; off < 32; off <<= 1) s += __shfl_xor(s, off);
      if (m32 == 0) psq[rl][ng] = s;
    }
    __syncthreads();   // also: last use of AslA/BslA before Afull writes
    #pragma unroll
    for (int r = 0; r < 16; ++r) {
      int rl = rowb + (r & 3) + 8 * (r >> 2);
      float inv = rsqrtf((psq[rl][0] + psq[rl][1]) * (1.f / (float)D_) + 1e-5f);
      #pragma unroll
      for (int j = 0; j < 3; ++j) {
        int col = (ng * 3 + j) * 32 + m32;
        float ovv = (accA[j][r] - mean[r]) * inv * g1[col] + b1v[col];
        h1v[j][r] = ovv;
        // R33: global x/xb stores removed (dead -- LN2 overwrites before any read)
        Afull[rl * 196 + col] = __float2bfloat16(ovv);
      }
    }
  }
  __syncthreads();   // Afull complete before ff1 reads

  // ========= ff1 (A from Afull; W1 256x4 = 1024 items, 4/thread) =========
  floatx16 acc1[4];
  #pragma unroll
  for (int j = 0; j < 4; ++j)
    #pragma unroll
    for (int r = 0; r < 16; ++r) acc1[j][r] = 0.f;

  {
    int rb0 = tid >> 2,          hb0 = tid & 3;
    int rb1 = (tid + 256) >> 2,  hb1 = tid & 3;
    int rb2 = (tid + 512) >> 2,  hb2 = tid & 3;
    int rb3 = (tid + 768) >> 2,  hb3 = tid & 3;
    float4* dB0 = (float4*)&BslB1[rb0 * 72 + hb0 * 16];
    float4* dB1 = (float4*)&BslB1[rb1 * 72 + hb1 * 16];
    float4* dB2 = (float4*)&BslB1[rb2 * 72 + hb2 * 16];
    float4* dB3 = (float4*)&BslB1[rb3 * 72 + hb3 * 16];
    {
      const float4* p0 = (const float4*)(W1 + (size_t)rb0 * D_ + hb0 * 16);
      dB0[0] = p0[0]; dB0[1] = p0[1];
      const float4* p1 = (const float4*)(W1 + (size_t)rb1 * D_ + hb1 * 16);
      dB1[0] = p1[0]; dB1[1] = p1[1];
      const float4* p2 = (const float4*)(W1 + (size_t)rb2 * D_ + hb2 * 16);
      dB2[0] = p2[0]; dB2[1] = p2[1];
      const float4* p3 = (const float4*)(W1 + (size_t)rb3 * D_ + hb3 * 16);
      dB3[0] = p3[0]; dB3[1] = p3[1];
    }
    for (int k0 = 0; k0 < D_; k0 += 64) {
      bool more = (k0 + 64 < D_);
      __syncthreads();
      float4 n00, n01, n10, n11, n20, n21, n30, n31;
      if (more) {
        const float4* p0 = (const float4*)(W1 + (size_t)rb0 * D_ + k0 + 64 + hb0 * 16);
        n00 = p0[0]; n01 = p0[1];
        const float4* p1 = (const float4*)(W1 + (size_t)rb1 * D_ + k0 + 64 + hb1 * 16);
        n10 = p1[0]; n11 = p1[1];
        const float4* p2 = (const float4*)(W1 + (size_t)rb2 * D_ + k0 + 64 + hb2 * 16);
        n20 = p2[0]; n21 = p2[1];
        const float4* p3 = (const float4*)(W1 + (size_t)rb3 * D_ + k0 + 64 + hb3 * 16);
        n30 = p3[0]; n31 = p3[1];
      }
      #pragma unroll
      for (int kc = 0; kc < 4; ++kc) {
        int ko = kc * 16 + half * 8;
        short8 a = ld_frag8(&Afull[(mt * 32 + m32) * 196 + k0 + ko]);
        #pragma unroll
        for (int j = 0; j < 4; ++j) {
          short8 bf = *(const short8*)&BslB1[((ng * 4 + j) * 32 + m32) * 72 + ko];
          acc1[j] = __builtin_amdgcn_mfma_f32_32x32x16_bf16(a, bf, acc1[j], 0, 0, 0);
        }
      }
      __syncthreads();
      if (more) {
        dB0[0] = n00; dB0[1] = n01;
        dB1[0] = n10; dB1[1] = n11;
        dB2[0] = n20; dB2[1] = n21;
        dB3[0] = n30; dB3[1] = n31;
      }
    }
  }
  // ff1 epilogue: relu -> C1 (aliases dead Afull + BslB1 head).
  {
    int rowb = mt * 32 + 4 * half;
    #pragma unroll
    for (int j = 0; j < 4; ++j) {
      int col = (ng * 4 + j) * 32 + m32;
      float cb = b1[col];
      #pragma unroll
      for (int r = 0; r < 16; ++r) {
        int row = rowb + (r & 3) + 8 * (r >> 2);
        C1[row * 260 + col] = __float2bfloat16(fmaxf(acc1[j][r] + cb, 0.f));
      }
    }
  }

  // ========= ff2 (A from C1; W2 192x4 = 768 items, 3/thread; K=256) =======
  floatx16 acc2[3];
  #pragma unroll
  for (int j = 0; j < 3; ++j)
    #pragma unroll
    for (int r = 0; r < 16; ++r) acc2[j][r] = 0.f;

  {
    int rb0 = tid >> 2,          hb0 = tid & 3;
    int rb1 = (tid + 256) >> 2,  hb1 = tid & 3;
    int rb2 = (tid + 512) >> 2,  hb2 = tid & 3;
    float4* dB0 = (float4*)&BslB2[rb0 * 72 + hb0 * 16];
    float4* dB1 = (float4*)&BslB2[rb1 * 72 + hb1 * 16];
    float4* dB2 = (float4*)&BslB2[rb2 * 72 + hb2 * 16];
    {
      const float4* p0 = (const float4*)(W2 + (size_t)rb0 * DFF_ + hb0 * 16);
      dB0[0] = p0[0]; dB0[1] = p0[1];
      const float4* p1 = (const float4*)(W2 + (size_t)rb1 * DFF_ + hb1 * 16);
      dB1[0] = p1[0]; dB1[1] = p1[1];
      const float4* p2 = (const float4*)(W2 + (size_t)rb2 * DFF_ + hb2 * 16);
      dB2[0] = p2[0]; dB2[1] = p2[1];
    }
    for (int k0 = 0; k0 < DFF_; k0 += 64) {
      bool more = (k0 + 64 < DFF_);
      __syncthreads();                    // C1 + BslB2 tile visible
      float4 n00, n01, n10, n11, n20, n21;
      if (more) {
        const float4* p0 = (const float4*)(W2 + (size_t)rb0 * DFF_ + k0 + 64 + hb0 * 16);
        n00 = p0[0]; n01 = p0[1];
        const float4* p1 = (const float4*)(W2 + (size_t)rb1 * DFF_ + k0 + 64 + hb1 * 16);
        n10 = p1[0]; n11 = p1[1];
        const float4* p2 = (const float4*)(W2 + (size_t)rb2 * DFF_ + k0 + 64 + hb2 * 16);
        n20 = p2[0]; n21 = p2[1];
      }
      #pragma unroll
      for (int kc = 0; kc < 4; ++kc) {
        int ko = kc * 16 + half * 8;
        short8 a = ld_frag8(&C1[(mt * 32 + m32) * 260 + k0 + ko]);
        #pragma unroll
        for (int j = 0; j < 3; ++j) {
          short8 bf = *(const short8*)&BslB2[((ng * 3 + j) * 32 + m32) * 72 + ko];
          acc2[j] = __builtin_amdgcn_mfma_f32_32x32x16_bf16(a, bf, acc2[j], 0, 0, 0);
        }
      }
      __syncthreads();
      if (more) {
        dB0[0] = n00; dB0[1] = n01;
        dB1[0] = n10; dB1[1] = n11;
        dB2[0] = n20; dB2[1] = n21;
      }
    }
  }

  int rowb = mt * 32 + 4 * half;
  #pragma unroll
  for (int r = 0; r < 16; ++r) {
    int rl = rowb + (r & 3) + 8 * (r >> 2);
    float p = 0.f;
    #pragma unroll
    for (int j = 0; j < 3; ++j) {
      int col = (ng * 3 + j) * 32 + m32;
      float t = acc2[j][r] + b2[col] + h1v[j][r];
      acc2[j][r] = t;
      p += t;
    }
    #pragma unroll
    for (int off = 1; off < 32; off <<= 1) p += __shfl_xor(p, off);
    if (m32 == 0) psum[rl][ng] = p;
  }
  __syncthreads();
  float mean[16];
  #pragma unroll
  for (int r = 0; r < 16; ++r) {
    int rl = rowb + (r & 3) + 8 * (r >> 2);
    mean[r] = (psum[rl][0] + psum[rl][1]) * (1.f / (float)D_);
  }
  #pragma unroll
  for (int r = 0; r < 16; ++r) {
    int rl = rowb + (r & 3) + 8 * (r >> 2);
    float s = 0.f;
    #pragma unroll
    for (int j = 0; j < 3; ++j) { float dd = acc2[j][r] - mean[r]; s += dd * dd; }
    #pragma unroll
    for (int off = 1; off < 32; off <<= 1) s += __shfl_xor(s, off);
    if (m32 == 0) psq[rl][ng] = s;
  }
  __syncthreads();
  #pragma unroll
  for (int r = 0; r < 16; ++r) {
    int rl = rowb + (r & 3) + 8 * (r >> 2);
    int row = bm + rl;
    float inv = rsqrtf((psq[rl][0] + psq[rl][1]) * (1.f / (float)D_) + 1e-5f);
    #pragma unroll
    for (int j = 0; j < 3; ++j) {
      int col = (ng * 3 + j) * 32 + m32;
      float ovv = (acc2[j][r] - mean[r]) * inv * g2[col] + b2v[col];
      x[(size_t)row * D_ + col] = ovv;
      xb[(size_t)row * D_ + col] = __float2bfloat16(ovv);
    }
  }
}

// ---------------------------------------------------------------------------
// Head v3 (R26-validated): grid 640 = b x 5 window-groups of 4.
// ---------------------------------------------------------------------------
__global__ __launch_bounds__(256)
void head3_kernel(const float* __restrict__ x, const float* __restrict__ noise,
                  const float* __restrict__ pw1, const float* __restrict__ pb1,
                  const float* __restrict__ pw2, const float* __restrict__ pb2,
                  const float* __restrict__ ew1, const float* __restrict__ eb1,
                  const float* __restrict__ ew2, const float* __restrict__ eb2,
                  float* __restrict__ out)
{
  __shared__ float slotS[4][192];    // 3072
  __shared__ float phS[4][256];      // 4096
  __shared__ float ehS[4][128];      // 2048
  int blk = blockIdx.x;
  int b = blk / 5, g = blk - b * 5;  // windows g*4 .. g*4+3
  int tid = threadIdx.x;

  const float* lastrow = x + ((size_t)b * S_ + (S_ - 1)) * D_;
  for (int e = tid; e < 4 * 192; e += 256) {
    int wl = e / 192, c = e - wl * 192;
    int wg = g * 4 + wl;
    slotS[wl][c] = lastrow[c] + noise[((size_t)wg * B_ + b) * D_ + c] * 0.1f;
  }
  __syncthreads();

  bool doe = (tid < 128);
  float accp[4], acce[4];
  {
    float bp = pb1[tid];
    float be = doe ? eb1[tid] : 0.f;
    #pragma unroll
    for (int wl = 0; wl < 4; ++wl) { accp[wl] = bp; acce[wl] = be; }
  }
  {
    const float4* wr = (const float4*)(pw1 + (size_t)tid * D_);
    const float4* we = (const float4*)(ew1 + (size_t)(doe ? tid : 0) * D_);
    for (int k4 = 0; k4 < 48; ++k4) {
      float4 wv = wr[k4];
      float4 ev = we[k4];
      #pragma unroll
      for (int wl = 0; wl < 4; ++wl) {
        float4 sv = *(const float4*)&slotS[wl][k4 * 4];
        accp[wl] += wv.x*sv.x + wv.y*sv.y + wv.z*sv.z + wv.w*sv.w;
        if (doe) acce[wl] += ev.x*sv.x + ev.y*sv.y + ev.z*sv.z + ev.w*sv.w;
      }
    }
  }
  #pragma unroll
  for (int wl = 0; wl < 4; ++wl) {
    phS[wl][tid] = fmaxf(accp[wl], 0.f);
    if (doe) ehS[wl][tid] = fmaxf(acce[wl], 0.f);
  }
  __syncthreads();

  if (tid < 16) {
    int wl = tid >> 2, c = tid & 3;
    float a = pb2[c];
    const float4* wr = (const float4*)(pw2 + c * 256);
    const float4* pp = (const float4*)&phS[wl][0];
    for (int k = 0; k < 64; ++k) {
      float4 wv = wr[k], pv = pp[k];
      a += wv.x*pv.x + wv.y*pv.y + wv.z*pv.z + wv.w*pv.w;
    }
    out[((size_t)b * W_ + g * 4 + wl) * 4 + c] = a;
  } else if (tid >= 64 && tid < 68) {
    int wl = tid - 64;
    float a = eb2[0];
    const float4* wr = (const float4*)ew2;
    const float4* pp = (const float4*)&ehS[wl][0];
    for (int k = 0; k < 32; ++k) {
      float4 wv = wr[k], pv = pp[k];
      a += wv.x*pv.x + wv.y*pv.y + wv.z*pv.z + wv.w*pv.w;
    }
    out[(size_t)B_ * W_ * 4 + (size_t)b * W_ + g * 4 + wl] = 1.f / (1.f + expf(-a));
  }
}

// ---------------------------------------------------------------------------
extern "C" void kernel_launch(void* const* d_in, const int* in_sizes, int n_in,
                              void* d_out, int out_size, void* d_ws, size_t ws_size,
                              hipStream_t stream)
{
  const int*   title_idx       = (const int*)  d_in[0];
  const int*   class_idx       = (const int*)  d_in[1];
  const int*   process_idx     = (const int*)  d_in[2];
  const int*   activity_type   = (const int*)  d_in[3];
  const float* mouse_pos       = (const float*)d_in[4];
  const float* rect            = (const float*)d_in[5];
  const float* flags           = (const float*)d_in[6];
  const float* keyboard_active = (const float*)d_in[7];
  const float* window_mask     = (const float*)d_in[8];
  const float* noise           = (const float*)d_in[9];
  const float* title_emb       = (const float*)d_in[10];
  const float* class_emb       = (const float*)d_in[11];
  const float* process_emb     = (const float*)d_in[12];
  const float* spatial_w1      = (const float*)d_in[13];
  const float* spatial_b1      = (const float*)d_in[14];
  const float* spatial_w2      = (const float*)d_in[15];
  const float* spatial_b2      = (const float*)d_in[16];
  const float* wfuse_w         = (const float*)d_in[17];
  const float* wfuse_b         = (const float*)d_in[18];
  const float* mouse_w1        = (const float*)d_in[19];
  const float* mouse_b1        = (const float*)d_in[20];
  const float* mouse_w2        = (const float*)d_in[21];
  const float* mouse_b2        = (const float*)d_in[22];
  const float* act_emb         = (const float*)d_in[23];
  const float* kbd_w           = (const float*)d_in[24];
  const float* kbd_b           = (const float*)d_in[25];
  const float* afuse_w         = (const float*)d_in[26];
  const float* afuse_b         = (const float*)d_in[27];
  const float* qkv_w           = (const float*)d_in[28];
  const float* qkv_b           = (const float*)d_in[29];
  const float* out_w           = (const float*)d_in[30];
  const float* out_b           = (const float*)d_in[31];
  const float* ff1_w           = (const float*)d_in[32];
  const float* ff1_b           = (const float*)d_in[33];
  const float* ff2_w           = (const float*)d_in[34];
  const float* ff2_b           = (const float*)d_in[35];
  const float* ln1_g           = (const float*)d_in[36];
  const float* ln1_b           = (const float*)d_in[37];
  const float* ln2_g           = (const float*)d_in[38];
  const float* ln2_b           = (const float*)d_in[39];
  const float* proj_w1         = (const float*)d_in[40];
  const float* proj_b1         = (const float*)d_in[41];
  const float* proj_w2         = (const float*)d_in[42];
  const float* proj_b2         = (const float*)d_in[43];
  const float* ex_w1           = (const float*)d_in[44];
  const float* ex_b1           = (const float*)d_in[45];
  const float* ex_w2           = (const float*)d_in[46];
  const float* ex_b2           = (const float*)d_in[47];

  float* out = (float*)d_out;

  // workspace layout
  float* x = (float*)d_ws;                                      // BS*192 f32
  __hip_bfloat16* xb   = (__hip_bfloat16*)(x + (size_t)BS_ * D_);
  __hip_bfloat16* attb = xb   + (size_t)BS_ * D_;
  __hip_bfloat16* wqb  = attb + (size_t)BS_ * D_;
  __hip_bfloat16* wob  = wqb  + (size_t)L_ * THREED_ * D_;
  __hip_bfloat16* wf1b = wob  + (size_t)L_ * D_ * D_;
  __hip_bfloat16* wf2b = wf1b + (size_t)L_ * DFF_ * D_;
  float* TE2  = (float*)(wf2b + (size_t)L_ * D_ * DFF_);        // 1000*128 (permuted cols)
  float* CE2  = TE2  + 1000 * 128;                              // 500*128
  float* PE2  = CE2  + 500 * 128;                               // 1000*128
  __hip_bfloat16* WSPb = (__hip_bfloat16*)(PE2 + 1000 * 128);   // 128*64 bf16
  float* PEtab = (float*)(WSPb + 128 * 64);                     // 100*192 f32
  (void)ws_size; (void)n_in; (void)in_sizes; (void)out_size;

  convertprep_kernel<<<2077, 256, 0, stream>>>(
      qkv_w, wqb, out_w, wob, ff1_w, wf1b, ff2_w, wf2b,
      title_emb, class_emb, process_emb, wfuse_w, wfuse_b,
      spatial_w2, spatial_b2, TE2, CE2, PE2, WSPb, PEtab);

  encode8_kernel<<<BS_ / 8, 512, 0, stream>>>(
      title_idx, class_idx, process_idx, activity_type, mouse_pos, rect, flags,
      keyboard_active, window_mask, spatial_w1, spatial_b1,
      TE2, CE2, PE2, WSPb, PEtab,
      mouse_w1, mouse_b1, mouse_w2, mouse_b2, act_emb, kbd_w, kbd_b,
      afuse_w, afuse_b, x, xb);

  for (int l = 0; l < L_; ++l) {
    qkvattn_kernel<<<B_ * H_, 256, 0, stream>>>(
        xb, wqb + (size_t)l * THREED_ * D_, qkv_b + (size_t)l * THREED_, attb);
    outffln_kernel<<<BS_ / 64, 256, 0, stream>>>(
        attb, wob + (size_t)l * D_ * D_, out_b + (size_t)l * D_,
        ln1_g + (size_t)l * D_, ln1_b + (size_t)l * D_,
        wf1b + (size_t)l * DFF_ * D_, ff1_b + (size_t)l * DFF_,
        wf2b + (size_t)l * D_ * DFF_, ff2_b + (size_t)l * D_,
        ln2_g + (size_t)l * D_, ln2_b + (size_t)l * D_, x, xb);
  }

  head3_kernel<<<B_ * 5, 256, 0, stream>>>(
      x, noise, proj_w1, proj_b1, proj_w2, proj_b2,
      ex_w1, ex_b1, ex_w2, ex_b2, out);
}